// Round 3
// baseline (6557.941 us; speedup 1.0000x reference)
//
#include <hip/hip_runtime.h>
#include <hip/hip_bf16.h>
#include <math.h>

using bf16 = __hip_bfloat16;

static constexpr int kNA  = 20000;
static constexpr int kNP  = 40000;
static constexpr int kEWB = 150000;
static constexpr int kEW  = 150000;
static constexpr int kEC  = 300000;

// ---- canonical bf16 input region: segment sizes & offsets (element counts) ----
static constexpr int kNSeg = 21;
static constexpr int kSegN[kNSeg] = {
  150000, 150000, 300000,           // ew_wb, ew_w, ew_c
  131072, 512,                      // adW, adb
  262144, 1024,                     // kW, kb
  262144, 1024,                     // qW, qb
  262144, 1024,                     // mW, mb
  262144, 1024,                     // aW, ab
  24,                               // wpri
  98304, 98304,                     // watt, wmsg
  6, 1024, 1024,                    // skip, lng, lnb
  16384, 64                         // outW, outb
};
// cumulative offsets
static constexpr size_t kOff(int s) {
  size_t o = 0;
  for (int i = 0; i < s; ++i) o += (size_t)kSegN[i];
  return o;
}
static constexpr size_t kCanonTotal = kOff(kNSeg);

struct CanonArgs {
  const void* src[kNSeg];
  int n[kNSeg];
  unsigned dstOff[kNSeg];
};

__device__ __forceinline__ float toF(float x) { return x; }
__device__ __forceinline__ float toF(bf16 x)  { return __bfloat162float(x); }
__device__ __forceinline__ float bits2f(unsigned short b) {
  unsigned int u = ((unsigned int)b) << 16;
  return __uint_as_float(u);
}
__device__ __forceinline__ void storeOut(float* p, float v) { *p = v; }
__device__ __forceinline__ void storeOut(bf16* p, float v)  { *p = __float2bfloat16(v); }
__device__ __forceinline__ float sigmoidf_(float x) { return 1.0f / (1.0f + expf(-x)); }
__device__ __forceinline__ float gelu_exact(float x) {
  return 0.5f * x * (1.0f + erff(x * 0.70710678118654752f));
}

// -------------------------------------------------------------------------
// Input-dtype sniffer: if d_in arrays are bf16, the LOW 16 bits of each
// 32-bit word are a bf16 value of ~N(0,1) -> exponent field in [110,140]
// essentially always. If fp32, low 16 bits are random mantissa bits ->
// exponent lands there only ~12% of the time. flags: [0]=isBf16 [1]=1 [2]=0
// -------------------------------------------------------------------------
__global__ __launch_bounds__(256) void detect_dtype(
    const unsigned* __restrict__ x, unsigned* __restrict__ flags)
{
  __shared__ int cnt;
  if (threadIdx.x == 0) cnt = 0;
  __syncthreads();
  unsigned w = x[threadIdx.x];
  unsigned e = (w >> 7) & 0xFFu;
  if (e >= 110u && e <= 140u) atomicAdd(&cnt, 1);
  __syncthreads();
  if (threadIdx.x == 0) {
    flags[0] = (cnt >= 128) ? 1u : 0u;
    flags[1] = 1u;
    flags[2] = 0u;
  }
}

// -------------------------------------------------------------------------
// Canonicalize all small input arrays into bf16 workspace copies.
// grid: (maxN/256, kNSeg)
// -------------------------------------------------------------------------
__global__ __launch_bounds__(256) void canon_kernel(
    CanonArgs a, bf16* __restrict__ dst, const unsigned* __restrict__ flags)
{
  const int s = blockIdx.y;
  const int i = blockIdx.x * 256 + threadIdx.x;
  if (i >= a.n[s]) return;
  bf16 v;
  if (flags[0]) v = ((const bf16*)a.src[s])[i];
  else          v = __float2bfloat16(((const float*)a.src[s])[i]);
  dst[a.dstOff[s] + i] = v;
}

// -------------------------------------------------------------------------
// Fold per-head w_att/w_msg (64x64 per head) into the K/M projection.
// grid = L*ET*H = 24 blocks, 256 threads. All srcs are canonical bf16.
// -------------------------------------------------------------------------
__global__ __launch_bounds__(256) void combine_weights(
    const bf16* __restrict__ Wbig, const bf16* __restrict__ bbig,
    const bf16* __restrict__ wsm, float* __restrict__ Eff, float* __restrict__ beff)
{
  const int blk = blockIdx.x;
  const int h = blk & 3;
  const int le = blk >> 2;
  const int e = le % 3;
  const int l = le / 3;
  const int st = (e == 1) ? 0 : 1;  // cites/written-by: paper src; writes: author src

  const bf16* Wsrc = Wbig + (size_t)(l * 2 + st) * 65536;
  const bf16* bsrc = bbig + (size_t)(l * 2 + st) * 256;
  const bf16* wm   = wsm  + ((size_t)(l * 3 + e) * 4 + h) * 4096;
  float* outW = Eff  + (size_t)(l * 3 + e) * 65536;
  float* outb = beff + (size_t)(l * 3 + e) * 256;

  __shared__ float w[64][64];
  const int tid = threadIdx.x;
  for (int i = tid; i < 4096; i += 256) w[i >> 6][i & 63] = toF(wm[i]);
  __syncthreads();

  const int j  = tid & 63;
  const int i0 = tid >> 6;
  for (int i = i0; i < 256; i += 4) {
    float acc = 0.f;
    #pragma unroll 8
    for (int d = 0; d < 64; ++d) acc += toF(Wsrc[(size_t)i * 256 + h * 64 + d]) * w[d][j];
    outW[(size_t)i * 256 + h * 64 + j] = acc;
  }
  if (tid < 64) {
    float acc = 0.f;
    #pragma unroll 8
    for (int d = 0; d < 64; ++d) acc += toF(bsrc[h * 64 + d]) * w[d][tid];
    outb[h * 64 + tid] = acc;
  }
}

// -------------------------------------------------------------------------
// C[M,256] = act( (ascale * A[M,256]) @ W[256,256] + bias[256] )
// A dtype selected at runtime by *aflag (1 = bf16, 0 = fp32).
// -------------------------------------------------------------------------
template <typename WT, typename OT>
__global__ __launch_bounds__(256) void gemm_k256(
    const void* __restrict__ A, const unsigned* __restrict__ aflag,
    const WT* __restrict__ W, const WT* __restrict__ bias,
    OT* __restrict__ C, int M, int act, float ascale)
{
  __shared__ float As[16][65];
  __shared__ float Ws[16][65];
  const bool abf = (*aflag != 0u);
  const int tid = threadIdx.x;
  const int bm = blockIdx.x * 64;
  const int bn = blockIdx.y * 64;
  const int tx = tid & 15, ty = tid >> 4;
  const int lr = tid >> 2;
  const int lk = (tid & 3) * 4;
  const int wk = tid >> 4;
  const int wn = (tid & 15) * 4;
  float acc[4][4] = {};

  for (int k0 = 0; k0 < 256; k0 += 16) {
    const int row = bm + lr;
    float a0 = 0.f, a1 = 0.f, a2 = 0.f, a3 = 0.f;
    if (row < M) {
      const size_t off = (size_t)row * 256 + k0 + lk;
      if (abf) {
        const bf16* ap = (const bf16*)A + off;
        a0 = toF(ap[0]); a1 = toF(ap[1]); a2 = toF(ap[2]); a3 = toF(ap[3]);
      } else {
        const float* ap = (const float*)A + off;
        a0 = ap[0]; a1 = ap[1]; a2 = ap[2]; a3 = ap[3];
      }
      a0 *= ascale; a1 *= ascale; a2 *= ascale; a3 *= ascale;
    }
    As[lk + 0][lr] = a0; As[lk + 1][lr] = a1;
    As[lk + 2][lr] = a2; As[lk + 3][lr] = a3;
    const WT* wp = W + (size_t)(k0 + wk) * 256 + bn + wn;
    Ws[wk][wn + 0] = toF(wp[0]); Ws[wk][wn + 1] = toF(wp[1]);
    Ws[wk][wn + 2] = toF(wp[2]); Ws[wk][wn + 3] = toF(wp[3]);
    __syncthreads();
    #pragma unroll
    for (int k = 0; k < 16; ++k) {
      float av[4], bv[4];
      #pragma unroll
      for (int i = 0; i < 4; ++i) av[i] = As[k][ty * 4 + i];
      #pragma unroll
      for (int j = 0; j < 4; ++j) bv[j] = Ws[k][tx * 4 + j];
      #pragma unroll
      for (int i = 0; i < 4; ++i)
        #pragma unroll
        for (int j = 0; j < 4; ++j) acc[i][j] += av[i] * bv[j];
    }
    __syncthreads();
  }

  #pragma unroll
  for (int i = 0; i < 4; ++i) {
    const int row = bm + ty * 4 + i;
    if (row >= M) continue;
    #pragma unroll
    for (int j = 0; j < 4; ++j) {
      const int col = bn + tx * 4 + j;
      float v = acc[i][j] + toF(bias[col]);
      if (act == 1) v = gelu_exact(v);
      storeOut(&C[(size_t)row * 256 + col], v);
    }
  }
}

// -------------------------------------------------------------------------
// Per-edge attention + message scatter. One wave per edge; lane covers
// elements 4*lane..4*lane+3 (head = lane>>4). All tensor srcs bf16.
// -------------------------------------------------------------------------
__global__ __launch_bounds__(256) void edge_kernel(
    const bf16* __restrict__ q, const bf16* __restrict__ kt, const bf16* __restrict__ mt,
    const int* __restrict__ src, const int* __restrict__ dst, const bf16* __restrict__ ew,
    const bf16* __restrict__ pri, float* __restrict__ agg, int E)
{
  const int lane = threadIdx.x & 63;
  const int wid  = threadIdx.x >> 6;
  const int e = blockIdx.x * 4 + wid;
  if (e >= E) return;
  const int s = src[e];
  const int d = dst[e];

  union B4 { uint2 u; unsigned short s[4]; };
  B4 qb, kb, mb;
  qb.u = ((const uint2*)(q  + (size_t)d * 256))[lane];
  kb.u = ((const uint2*)(kt + (size_t)s * 256))[lane];
  mb.u = ((const uint2*)(mt + (size_t)s * 256))[lane];

  float dot = 0.f;
  #pragma unroll
  for (int j = 0; j < 4; ++j) dot += bits2f(qb.s[j]) * bits2f(kb.s[j]);
  #pragma unroll
  for (int off = 1; off < 16; off <<= 1) dot += __shfl_xor(dot, off);

  const int head = lane >> 4;
  const float a = toF(ew[e]) * sigmoidf_(dot * toF(pri[head]) * 0.125f);

  float* ar = agg + (size_t)d * 256 + lane * 4;
  #pragma unroll
  for (int j = 0; j < 4; ++j) atomicAdd(&ar[j], bits2f(mb.s[j]) * a);
}

// -------------------------------------------------------------------------
// o = tr*alpha + feat*(1-alpha); feat = bf16(LN(o)*g + b). One wave per node.
// -------------------------------------------------------------------------
__global__ __launch_bounds__(256) void skip_ln(
    const float* __restrict__ tr, bf16* __restrict__ feat,
    const bf16* __restrict__ skipv, const bf16* __restrict__ g,
    const bf16* __restrict__ b, int N)
{
  const int lane = threadIdx.x & 63;
  const int wid  = threadIdx.x >> 6;
  const int node = blockIdx.x * 4 + wid;
  if (node >= N) return;
  const float alpha = sigmoidf_(toF(*skipv));
  const float4 t = ((const float4*)(tr + (size_t)node * 256))[lane];
  union B4 { uint2 u; unsigned short s[4]; };
  B4 fb;
  fb.u = ((const uint2*)(feat + (size_t)node * 256))[lane];
  float o[4];
  o[0] = t.x * alpha + bits2f(fb.s[0]) * (1.f - alpha);
  o[1] = t.y * alpha + bits2f(fb.s[1]) * (1.f - alpha);
  o[2] = t.z * alpha + bits2f(fb.s[2]) * (1.f - alpha);
  o[3] = t.w * alpha + bits2f(fb.s[3]) * (1.f - alpha);

  float sum = o[0] + o[1] + o[2] + o[3];
  #pragma unroll
  for (int off = 32; off; off >>= 1) sum += __shfl_xor(sum, off);
  const float mu = sum * (1.f / 256.f);

  float dd[4], sq = 0.f;
  #pragma unroll
  for (int j = 0; j < 4; ++j) { dd[j] = o[j] - mu; sq += dd[j] * dd[j]; }
  #pragma unroll
  for (int off = 32; off; off >>= 1) sq += __shfl_xor(sq, off);
  const float rs = rsqrtf(sq * (1.f / 256.f) + 1e-5f);

  bf16* fout = feat + (size_t)node * 256 + lane * 4;
  #pragma unroll
  for (int j = 0; j < 4; ++j) {
    float r = dd[j] * rs * toF(g[lane * 4 + j]) + toF(b[lane * 4 + j]);
    fout[j] = __float2bfloat16(r);
  }
}

// -------------------------------------------------------------------------
// out[M,64] = A[M,256] @ W[256,64] + b[64]; output dtype per *flag.
// -------------------------------------------------------------------------
__global__ __launch_bounds__(256) void out_gemm(
    const bf16* __restrict__ A, const bf16* __restrict__ W,
    const bf16* __restrict__ bias, void* __restrict__ out,
    const unsigned* __restrict__ flag, int M)
{
  __shared__ float Ws[64][64];
  const bool obf = (*flag != 0u);
  const int tid = threadIdx.x;
  const int row = blockIdx.x * 64 + (tid >> 2);
  const int c0 = (tid & 3) * 16;
  const int arow = (row < M) ? row : 0;
  const bf16* a = A + (size_t)arow * 256;
  float acc[16] = {};
  for (int k0 = 0; k0 < 256; k0 += 64) {
    for (int i = tid; i < 4096; i += 256)
      Ws[i >> 6][i & 63] = toF(W[(size_t)(k0 + (i >> 6)) * 64 + (i & 63)]);
    __syncthreads();
    for (int k = 0; k < 64; ++k) {
      const float av = toF(a[k0 + k]);
      #pragma unroll
      for (int j = 0; j < 16; ++j) acc[j] += av * Ws[k][c0 + j];
    }
    __syncthreads();
  }
  if (row < M) {
    #pragma unroll
    for (int j = 0; j < 16; ++j) {
      const float v = acc[j] + toF(bias[c0 + j]);
      const size_t idx = (size_t)row * 64 + c0 + j;
      if (obf) ((bf16*)out)[idx] = __float2bfloat16(v);
      else     ((float*)out)[idx] = v;
    }
  }
}

// -------------------------------------------------------------------------
extern "C" void kernel_launch(void* const* d_in, const int* in_sizes, int n_in,
                              void* d_out, int out_size, void* d_ws, size_t ws_size,
                              hipStream_t stream) {
  const int* src_wb  = (const int*)d_in[23];
  const int* dst_wb  = (const int*)d_in[24];
  const int* src_w   = (const int*)d_in[25];
  const int* dst_w   = (const int*)d_in[26];
  const int* src_c   = (const int*)d_in[27];
  const int* dst_c   = (const int*)d_in[28];

  // ---- workspace carve (~171 MB total) ----
  char* base = (char*)d_ws;
  unsigned* flags = (unsigned*)base;          // [0]=isBf16 [1]=1 [2]=0
  bf16* canon = (bf16*)(base + 256);
  char* p = base + 256 + (((size_t)kCanonTotal * 2 + 511) & ~(size_t)511);
  bf16* fa  = (bf16*)p;                       // [NA,256]
  bf16* fp_ = fa + (size_t)kNA * 256;         // [NP,256]
  char* R   = (char*)(fp_ + (size_t)kNP * 256);
  bf16* qa = (bf16*)R;                        // [NA,256]
  bf16* qp = qa + (size_t)kNA * 256;          // [NP,256]
  bf16* kt = qp + (size_t)kNP * 256;          // [NP,256]
  bf16* mt = kt + (size_t)kNP * 256;          // [NP,256]
  float* tr_a = (float*)R;                    // fp32 view, disjoint lifetime
  float* tr_p = tr_a + (size_t)kNA * 256;
  char* afterR = R + (size_t)(kNA + 3 * kNP) * 256 * sizeof(bf16);
  float* agg_a = (float*)afterR;              // [NA,256]
  float* agg_p = agg_a + (size_t)kNA * 256;   // [NP,256]
  float* Keff  = agg_p + (size_t)kNP * 256;   // [L,ET,256,256]
  float* Meff  = Keff + (size_t)6 * 65536;
  float* kbe   = Meff + (size_t)6 * 65536;
  float* mbe   = kbe + (size_t)6 * 256;

  // canonical bf16 input pointers
  const bf16* c_ew_wb = canon + kOff(0);
  const bf16* c_ew_w  = canon + kOff(1);
  const bf16* c_ew_c  = canon + kOff(2);
  const bf16* c_adW   = canon + kOff(3);
  const bf16* c_adb   = canon + kOff(4);
  const bf16* c_kW    = canon + kOff(5);
  const bf16* c_kb    = canon + kOff(6);
  const bf16* c_qW    = canon + kOff(7);
  const bf16* c_qb    = canon + kOff(8);
  const bf16* c_mW    = canon + kOff(9);
  const bf16* c_mb    = canon + kOff(10);
  const bf16* c_aW    = canon + kOff(11);
  const bf16* c_ab    = canon + kOff(12);
  const bf16* c_wpri  = canon + kOff(13);
  const bf16* c_watt  = canon + kOff(14);
  const bf16* c_wmsg  = canon + kOff(15);
  const bf16* c_skip  = canon + kOff(16);
  const bf16* c_lng   = canon + kOff(17);
  const bf16* c_lnb   = canon + kOff(18);
  const bf16* c_outW  = canon + kOff(19);
  const bf16* c_outb  = canon + kOff(20);

  const unsigned* fIn  = flags + 0;  // input dtype flag
  const unsigned* f1   = flags + 1;  // constant 1 (A is bf16)
  const unsigned* f0   = flags + 2;  // constant 0 (A is fp32)

  detect_dtype<<<1, 256, 0, stream>>>((const unsigned*)d_in[0], flags);

  CanonArgs ca;
  for (int s = 0; s < kNSeg; ++s) { ca.n[s] = kSegN[s]; ca.dstOff[s] = (unsigned)kOff(s); }
  const int srcIdx[kNSeg] = {2,3,4, 5,6, 7,8, 9,10, 11,12, 13,14, 15, 16,17, 18,19,20, 21,22};
  for (int s = 0; s < kNSeg; ++s) ca.src[s] = d_in[srcIdx[s]];
  canon_kernel<<<dim3(1172, kNSeg), 256, 0, stream>>>(ca, canon, flags);

  auto gA = [](int m) { return dim3((unsigned)((m + 63) / 64), 4); };

  combine_weights<<<24, 256, 0, stream>>>(c_kW, c_kb, c_watt, Keff, kbe);
  combine_weights<<<24, 256, 0, stream>>>(c_mW, c_mb, c_wmsg, Meff, mbe);

  // adapt: feats = gelu(x @ adapt_W + adapt_b); x read dual-dtype
  gemm_k256<bf16, bf16><<<gA(kNA), 256, 0, stream>>>(d_in[0], fIn, c_adW,        c_adb,       fa,  kNA, 1, 1.f);
  gemm_k256<bf16, bf16><<<gA(kNP), 256, 0, stream>>>(d_in[1], fIn, c_adW + 65536, c_adb + 256, fp_, kNP, 1, 1.f);

  for (int l = 0; l < 2; ++l) {
    gemm_k256<bf16, bf16><<<gA(kNA), 256, 0, stream>>>(
        fa,  f1, c_qW + (size_t)(l * 2 + 0) * 65536, c_qb + (l * 2 + 0) * 256, qa, kNA, 0, 1.f);
    gemm_k256<bf16, bf16><<<gA(kNP), 256, 0, stream>>>(
        fp_, f1, c_qW + (size_t)(l * 2 + 1) * 65536, c_qb + (l * 2 + 1) * 256, qp, kNP, 0, 1.f);

    hipMemsetAsync(agg_a, 0, (size_t)kNA * 256 * 4, stream);
    hipMemsetAsync(agg_p, 0, (size_t)kNP * 256 * 4, stream);

    // WRITTEN_BY (e=2): paper -> author
    gemm_k256<float, bf16><<<gA(kNP), 256, 0, stream>>>(
        fp_, f1, Keff + (size_t)(l * 3 + 2) * 65536, kbe + (l * 3 + 2) * 256, kt, kNP, 0, 1.f);
    gemm_k256<float, bf16><<<gA(kNP), 256, 0, stream>>>(
        fp_, f1, Meff + (size_t)(l * 3 + 2) * 65536, mbe + (l * 3 + 2) * 256, mt, kNP, 0, 1.f);
    edge_kernel<<<kEWB / 4, 256, 0, stream>>>(
        qa, kt, mt, src_wb, dst_wb, c_ew_wb, c_wpri + (l * 3 + 2) * 4, agg_a, kEWB);

    // WRITES (e=1): author -> paper
    gemm_k256<float, bf16><<<gA(kNA), 256, 0, stream>>>(
        fa, f1, Keff + (size_t)(l * 3 + 1) * 65536, kbe + (l * 3 + 1) * 256, kt, kNA, 0, 1.f);
    gemm_k256<float, bf16><<<gA(kNA), 256, 0, stream>>>(
        fa, f1, Meff + (size_t)(l * 3 + 1) * 65536, mbe + (l * 3 + 1) * 256, mt, kNA, 0, 1.f);
    edge_kernel<<<kEW / 4, 256, 0, stream>>>(
        qp, kt, mt, src_w, dst_w, c_ew_w, c_wpri + (l * 3 + 1) * 4, agg_p, kEW);

    // CITES (e=0): paper -> paper
    gemm_k256<float, bf16><<<gA(kNP), 256, 0, stream>>>(
        fp_, f1, Keff + (size_t)(l * 3 + 0) * 65536, kbe + (l * 3 + 0) * 256, kt, kNP, 0, 1.f);
    gemm_k256<float, bf16><<<gA(kNP), 256, 0, stream>>>(
        fp_, f1, Meff + (size_t)(l * 3 + 0) * 65536, mbe + (l * 3 + 0) * 256, mt, kNP, 0, 1.f);
    edge_kernel<<<kEC / 4, 256, 0, stream>>>(
        qp, kt, mt, src_c, dst_c, c_ew_c, c_wpri + (l * 3 + 0) * 4, agg_p, kEC);

    // A-projection (paper agg scaled 0.5 for cross-relation mean)
    gemm_k256<bf16, float><<<gA(kNA), 256, 0, stream>>>(
        agg_a, f0, c_aW + (size_t)(l * 2 + 0) * 65536, c_ab + (l * 2 + 0) * 256, tr_a, kNA, 0, 1.f);
    gemm_k256<bf16, float><<<gA(kNP), 256, 0, stream>>>(
        agg_p, f0, c_aW + (size_t)(l * 2 + 1) * 65536, c_ab + (l * 2 + 1) * 256, tr_p, kNP, 0, 0.5f);

    skip_ln<<<kNA / 4, 256, 0, stream>>>(
        tr_a, fa,  c_skip + l * 3 + 0, c_lng + (l * 2 + 0) * 256, c_lnb + (l * 2 + 0) * 256, kNA);
    skip_ln<<<kNP / 4, 256, 0, stream>>>(
        tr_p, fp_, c_skip + l * 3 + 1, c_lng + (l * 2 + 1) * 256, c_lnb + (l * 2 + 1) * 256, kNP);
  }

  out_gemm<<<kNP / 64, 256, 0, stream>>>(fp_, c_outW, c_outb, d_out, fIn, kNP);
}

// Round 4
// 2947.942 us; speedup vs baseline: 2.2246x; 2.2246x over previous
//
#include <hip/hip_runtime.h>
#include <hip/hip_bf16.h>
#include <math.h>

using bf16 = __hip_bfloat16;

static constexpr int kNA  = 20000;
static constexpr int kNP  = 40000;
static constexpr int kEWB = 150000;
static constexpr int kEW  = 150000;
static constexpr int kEC  = 300000;

// ---- canonical bf16 input region: segment sizes & offsets (element counts) ----
static constexpr int kNSeg = 21;
static constexpr int kSegN[kNSeg] = {
  150000, 150000, 300000,           // ew_wb, ew_w, ew_c
  131072, 512,                      // adW, adb
  262144, 1024,                     // kW, kb
  262144, 1024,                     // qW, qb
  262144, 1024,                     // mW, mb
  262144, 1024,                     // aW, ab
  24,                               // wpri
  98304, 98304,                     // watt, wmsg
  6, 1024, 1024,                    // skip, lng, lnb
  16384, 64                         // outW, outb
};
static constexpr size_t kOff(int s) {
  size_t o = 0;
  for (int i = 0; i < s; ++i) o += (size_t)kSegN[i];
  return o;
}
static constexpr size_t kCanonTotal = kOff(kNSeg);

struct CanonArgs {
  const void* src[kNSeg];
  int n[kNSeg];
  unsigned dstOff[kNSeg];
};

__device__ __forceinline__ float toF(float x) { return x; }
__device__ __forceinline__ float toF(bf16 x)  { return __bfloat162float(x); }
__device__ __forceinline__ float bits2f(unsigned short b) {
  unsigned int u = ((unsigned int)b) << 16;
  return __uint_as_float(u);
}
__device__ __forceinline__ void storeOut(float* p, float v) { *p = v; }
__device__ __forceinline__ void storeOut(bf16* p, float v)  { *p = __float2bfloat16(v); }
__device__ __forceinline__ float sigmoidf_(float x) { return 1.0f / (1.0f + expf(-x)); }
__device__ __forceinline__ float gelu_exact(float x) {
  return 0.5f * x * (1.0f + erff(x * 0.70710678118654752f));
}

// -------------------------------------------------------------------------
// Input-dtype sniffer (see round-2 notes). flags: [0]=isBf16 [1]=1 [2]=0
// -------------------------------------------------------------------------
__global__ __launch_bounds__(256) void detect_dtype(
    const unsigned* __restrict__ x, unsigned* __restrict__ flags)
{
  __shared__ int cnt;
  if (threadIdx.x == 0) cnt = 0;
  __syncthreads();
  unsigned w = x[threadIdx.x];
  unsigned e = (w >> 7) & 0xFFu;
  if (e >= 110u && e <= 140u) atomicAdd(&cnt, 1);
  __syncthreads();
  if (threadIdx.x == 0) {
    flags[0] = (cnt >= 128) ? 1u : 0u;
    flags[1] = 1u;
    flags[2] = 0u;
  }
}

__global__ __launch_bounds__(256) void canon_kernel(
    CanonArgs a, bf16* __restrict__ dst, const unsigned* __restrict__ flags)
{
  const int s = blockIdx.y;
  const int i = blockIdx.x * 256 + threadIdx.x;
  if (i >= a.n[s]) return;
  bf16 v;
  if (flags[0]) v = ((const bf16*)a.src[s])[i];
  else          v = __float2bfloat16(((const float*)a.src[s])[i]);
  dst[a.dstOff[s] + i] = v;
}

// -------------------------------------------------------------------------
// CSR build: histogram -> exclusive scan (single block) -> scatter.
// -------------------------------------------------------------------------
__global__ __launch_bounds__(256) void csr_hist(
    const int* __restrict__ dst, int E, int* __restrict__ cnt)
{
  const int i = blockIdx.x * 256 + threadIdx.x;
  if (i < E) atomicAdd(&cnt[dst[i]], 1);
}

// cur holds degrees on entry; on exit offs[0..N] = exclusive scan (offs[N]=E)
// and cur[i] = offs[i] (cursor copy for scatter).
__global__ __launch_bounds__(1024) void csr_scan(
    int* __restrict__ cur, int* __restrict__ offs, int N)
{
  __shared__ int buf[1024];
  __shared__ int carry;
  const int tid = threadIdx.x;
  if (tid == 0) carry = 0;
  __syncthreads();
  for (int base = 0; base < N; base += 1024) {
    const int idx = base + tid;
    const int v = (idx < N) ? cur[idx] : 0;
    buf[tid] = v;
    __syncthreads();
    for (int off = 1; off < 1024; off <<= 1) {
      int t = (tid >= off) ? buf[tid - off] : 0;
      __syncthreads();
      buf[tid] += t;
      __syncthreads();
    }
    const int excl = buf[tid] - v;
    const int total = buf[1023];
    if (idx < N) {
      const int o = carry + excl;
      offs[idx] = o;
      cur[idx] = o;
    }
    __syncthreads();
    if (tid == 0) carry += total;
    __syncthreads();
  }
  if (tid == 0) offs[N] = carry;
}

__global__ __launch_bounds__(256) void csr_scatter(
    const int* __restrict__ dst, int E, int* __restrict__ cur, int* __restrict__ sorted)
{
  const int i = blockIdx.x * 256 + threadIdx.x;
  if (i >= E) return;
  const int p = atomicAdd(&cur[dst[i]], 1);
  sorted[p] = i;
}

// -------------------------------------------------------------------------
// Fold per-head w_att/w_msg into the K/M projections. 24 blocks.
// -------------------------------------------------------------------------
__global__ __launch_bounds__(256) void combine_weights(
    const bf16* __restrict__ Wbig, const bf16* __restrict__ bbig,
    const bf16* __restrict__ wsm, float* __restrict__ Eff, float* __restrict__ beff)
{
  const int blk = blockIdx.x;
  const int h = blk & 3;
  const int le = blk >> 2;
  const int e = le % 3;
  const int l = le / 3;
  const int st = (e == 1) ? 0 : 1;

  const bf16* Wsrc = Wbig + (size_t)(l * 2 + st) * 65536;
  const bf16* bsrc = bbig + (size_t)(l * 2 + st) * 256;
  const bf16* wm   = wsm  + ((size_t)(l * 3 + e) * 4 + h) * 4096;
  float* outW = Eff  + (size_t)(l * 3 + e) * 65536;
  float* outb = beff + (size_t)(l * 3 + e) * 256;

  __shared__ float w[64][64];
  const int tid = threadIdx.x;
  for (int i = tid; i < 4096; i += 256) w[i >> 6][i & 63] = toF(wm[i]);
  __syncthreads();

  const int j  = tid & 63;
  const int i0 = tid >> 6;
  for (int i = i0; i < 256; i += 4) {
    float acc = 0.f;
    #pragma unroll 8
    for (int d = 0; d < 64; ++d) acc += toF(Wsrc[(size_t)i * 256 + h * 64 + d]) * w[d][j];
    outW[(size_t)i * 256 + h * 64 + j] = acc;
  }
  if (tid < 64) {
    float acc = 0.f;
    #pragma unroll 8
    for (int d = 0; d < 64; ++d) acc += toF(bsrc[h * 64 + d]) * w[d][tid];
    outb[h * 64 + tid] = acc;
  }
}

// -------------------------------------------------------------------------
// C[M,256] = act( (ascale*A[M,256]) @ W[256,256] + bias ), runtime A dtype.
// -------------------------------------------------------------------------
template <typename WT, typename OT>
__global__ __launch_bounds__(256) void gemm_k256(
    const void* __restrict__ A, const unsigned* __restrict__ aflag,
    const WT* __restrict__ W, const WT* __restrict__ bias,
    OT* __restrict__ C, int M, int act, float ascale)
{
  __shared__ float As[16][65];
  __shared__ float Ws[16][65];
  const bool abf = (*aflag != 0u);
  const int tid = threadIdx.x;
  const int bm = blockIdx.x * 64;
  const int bn = blockIdx.y * 64;
  const int tx = tid & 15, ty = tid >> 4;
  const int lr = tid >> 2;
  const int lk = (tid & 3) * 4;
  const int wk = tid >> 4;
  const int wn = (tid & 15) * 4;
  float acc[4][4] = {};

  for (int k0 = 0; k0 < 256; k0 += 16) {
    const int row = bm + lr;
    float a0 = 0.f, a1 = 0.f, a2 = 0.f, a3 = 0.f;
    if (row < M) {
      const size_t off = (size_t)row * 256 + k0 + lk;
      if (abf) {
        const bf16* ap = (const bf16*)A + off;
        a0 = toF(ap[0]); a1 = toF(ap[1]); a2 = toF(ap[2]); a3 = toF(ap[3]);
      } else {
        const float* ap = (const float*)A + off;
        a0 = ap[0]; a1 = ap[1]; a2 = ap[2]; a3 = ap[3];
      }
      a0 *= ascale; a1 *= ascale; a2 *= ascale; a3 *= ascale;
    }
    As[lk + 0][lr] = a0; As[lk + 1][lr] = a1;
    As[lk + 2][lr] = a2; As[lk + 3][lr] = a3;
    const WT* wp = W + (size_t)(k0 + wk) * 256 + bn + wn;
    Ws[wk][wn + 0] = toF(wp[0]); Ws[wk][wn + 1] = toF(wp[1]);
    Ws[wk][wn + 2] = toF(wp[2]); Ws[wk][wn + 3] = toF(wp[3]);
    __syncthreads();
    #pragma unroll
    for (int k = 0; k < 16; ++k) {
      float av[4], bv[4];
      #pragma unroll
      for (int i = 0; i < 4; ++i) av[i] = As[k][ty * 4 + i];
      #pragma unroll
      for (int j = 0; j < 4; ++j) bv[j] = Ws[k][tx * 4 + j];
      #pragma unroll
      for (int i = 0; i < 4; ++i)
        #pragma unroll
        for (int j = 0; j < 4; ++j) acc[i][j] += av[i] * bv[j];
    }
    __syncthreads();
  }

  #pragma unroll
  for (int i = 0; i < 4; ++i) {
    const int row = bm + ty * 4 + i;
    if (row >= M) continue;
    #pragma unroll
    for (int j = 0; j < 4; ++j) {
      const int col = bn + tx * 4 + j;
      float v = acc[i][j] + toF(bias[col]);
      if (act == 1) v = gelu_exact(v);
      storeOut(&C[(size_t)row * 256 + col], v);
    }
  }
}

// -------------------------------------------------------------------------
// CSR gather: one wave per dst node, fp32 register accumulation, ONE
// non-atomic bf16 write per node. addPrev chains two relations; finalScale
// applies the cross-relation mean.
// -------------------------------------------------------------------------
__global__ __launch_bounds__(256) void gather_kernel(
    const bf16* __restrict__ q, const bf16* __restrict__ kt, const bf16* __restrict__ mt,
    const int* __restrict__ src, const int* __restrict__ sorted, const int* __restrict__ offs,
    const bf16* __restrict__ ew, const bf16* __restrict__ pri,
    bf16* __restrict__ agg, int Nd, int addPrev, float finalScale)
{
  const int lane = threadIdx.x & 63;
  const int wid  = threadIdx.x >> 6;
  const int node = blockIdx.x * 4 + wid;
  if (node >= Nd) return;

  union B4 { uint2 u; unsigned short s[4]; };
  B4 qv;
  qv.u = ((const uint2*)(q + (size_t)node * 256))[lane];
  float qf[4];
  #pragma unroll
  for (int j = 0; j < 4; ++j) qf[j] = bits2f(qv.s[j]);
  const float prih = toF(pri[lane >> 4]);

  float acc[4] = {0.f, 0.f, 0.f, 0.f};
  const int beg = offs[node], end = offs[node + 1];
  for (int idx = beg; idx < end; ++idx) {
    const int e = sorted[idx];
    const int s = src[e];
    B4 kb;
    kb.u = ((const uint2*)(kt + (size_t)s * 256))[lane];
    float dot = 0.f;
    #pragma unroll
    for (int j = 0; j < 4; ++j) dot += qf[j] * bits2f(kb.s[j]);
    #pragma unroll
    for (int off = 1; off < 16; off <<= 1) dot += __shfl_xor(dot, off);
    const float a = toF(ew[e]) * sigmoidf_(dot * prih * 0.125f);
    B4 mb;
    mb.u = ((const uint2*)(mt + (size_t)s * 256))[lane];
    #pragma unroll
    for (int j = 0; j < 4; ++j) acc[j] += bits2f(mb.s[j]) * a;
  }

  if (addPrev) {
    B4 pb;
    pb.u = ((const uint2*)(agg + (size_t)node * 256))[lane];
    #pragma unroll
    for (int j = 0; j < 4; ++j) acc[j] += bits2f(pb.s[j]);
  }
  bf16* out = agg + (size_t)node * 256 + lane * 4;
  #pragma unroll
  for (int j = 0; j < 4; ++j) out[j] = __float2bfloat16(acc[j] * finalScale);
}

// -------------------------------------------------------------------------
// o = tr*alpha + feat*(1-alpha); feat = bf16(LN(o)*g + b). One wave per node.
// -------------------------------------------------------------------------
__global__ __launch_bounds__(256) void skip_ln(
    const float* __restrict__ tr, bf16* __restrict__ feat,
    const bf16* __restrict__ skipv, const bf16* __restrict__ g,
    const bf16* __restrict__ b, int N)
{
  const int lane = threadIdx.x & 63;
  const int wid  = threadIdx.x >> 6;
  const int node = blockIdx.x * 4 + wid;
  if (node >= N) return;
  const float alpha = sigmoidf_(toF(*skipv));
  const float4 t = ((const float4*)(tr + (size_t)node * 256))[lane];
  union B4 { uint2 u; unsigned short s[4]; };
  B4 fb;
  fb.u = ((const uint2*)(feat + (size_t)node * 256))[lane];
  float o[4];
  o[0] = t.x * alpha + bits2f(fb.s[0]) * (1.f - alpha);
  o[1] = t.y * alpha + bits2f(fb.s[1]) * (1.f - alpha);
  o[2] = t.z * alpha + bits2f(fb.s[2]) * (1.f - alpha);
  o[3] = t.w * alpha + bits2f(fb.s[3]) * (1.f - alpha);

  float sum = o[0] + o[1] + o[2] + o[3];
  #pragma unroll
  for (int off = 32; off; off >>= 1) sum += __shfl_xor(sum, off);
  const float mu = sum * (1.f / 256.f);

  float dd[4], sq = 0.f;
  #pragma unroll
  for (int j = 0; j < 4; ++j) { dd[j] = o[j] - mu; sq += dd[j] * dd[j]; }
  #pragma unroll
  for (int off = 32; off; off >>= 1) sq += __shfl_xor(sq, off);
  const float rs = rsqrtf(sq * (1.f / 256.f) + 1e-5f);

  bf16* fout = feat + (size_t)node * 256 + lane * 4;
  #pragma unroll
  for (int j = 0; j < 4; ++j) {
    float r = dd[j] * rs * toF(g[lane * 4 + j]) + toF(b[lane * 4 + j]);
    fout[j] = __float2bfloat16(r);
  }
}

// -------------------------------------------------------------------------
// out[M,64] = A[M,256] @ W[256,64] + b[64]; output dtype per *flag.
// -------------------------------------------------------------------------
__global__ __launch_bounds__(256) void out_gemm(
    const bf16* __restrict__ A, const bf16* __restrict__ W,
    const bf16* __restrict__ bias, void* __restrict__ out,
    const unsigned* __restrict__ flag, int M)
{
  __shared__ float Ws[64][64];
  const bool obf = (*flag != 0u);
  const int tid = threadIdx.x;
  const int row = blockIdx.x * 64 + (tid >> 2);
  const int c0 = (tid & 3) * 16;
  const int arow = (row < M) ? row : 0;
  const bf16* a = A + (size_t)arow * 256;
  float acc[16] = {};
  for (int k0 = 0; k0 < 256; k0 += 64) {
    for (int i = tid; i < 4096; i += 256)
      Ws[i >> 6][i & 63] = toF(W[(size_t)(k0 + (i >> 6)) * 64 + (i & 63)]);
    __syncthreads();
    for (int k = 0; k < 64; ++k) {
      const float av = toF(a[k0 + k]);
      #pragma unroll
      for (int j = 0; j < 16; ++j) acc[j] += av * Ws[k][c0 + j];
    }
    __syncthreads();
  }
  if (row < M) {
    #pragma unroll
    for (int j = 0; j < 16; ++j) {
      const float v = acc[j] + toF(bias[c0 + j]);
      const size_t idx = (size_t)row * 64 + c0 + j;
      if (obf) ((bf16*)out)[idx] = __float2bfloat16(v);
      else     ((float*)out)[idx] = v;
    }
  }
}

// -------------------------------------------------------------------------
extern "C" void kernel_launch(void* const* d_in, const int* in_sizes, int n_in,
                              void* d_out, int out_size, void* d_ws, size_t ws_size,
                              hipStream_t stream) {
  const int* src_wb  = (const int*)d_in[23];
  const int* dst_wb  = (const int*)d_in[24];
  const int* src_w   = (const int*)d_in[25];
  const int* dst_w   = (const int*)d_in[26];
  const int* src_c   = (const int*)d_in[27];
  const int* dst_c   = (const int*)d_in[28];

  // ---- workspace carve (~144 MB total) ----
  char* base = (char*)d_ws;
  unsigned* flags = (unsigned*)base;                       // 256 B
  bf16* canon = (bf16*)(base + 256);
  char* p = base + 256 + (((size_t)kCanonTotal * 2 + 511) & ~(size_t)511);
  // CSR region
  int* cur_wb  = (int*)p;                 // NA+1 (degree -> cursor)
  int* cur_w   = cur_wb + (kNA + 1);      // NP+1
  int* cur_c   = cur_w + (kNP + 1);       // NP+1
  int* offs_wb = cur_c + (kNP + 1);       // NA+1
  int* offs_w  = offs_wb + (kNA + 1);     // NP+1
  int* offs_c  = offs_w + (kNP + 1);      // NP+1
  int* sort_wb = offs_c + (kNP + 1);      // E_WB
  int* sort_w  = sort_wb + kEWB;          // E_W
  int* sort_c  = sort_w + kEW;            // E_C
  char* p2 = (char*)(((size_t)(sort_c + kEC) + 511) & ~(size_t)511);
  bf16* fa  = (bf16*)p2;                  // [NA,256]
  bf16* fp_ = fa + (size_t)kNA * 256;     // [NP,256]
  char* R   = (char*)(fp_ + (size_t)kNP * 256);
  bf16* qa = (bf16*)R;                    // [NA,256]
  bf16* qp = qa + (size_t)kNA * 256;      // [NP,256]
  bf16* kt = qp + (size_t)kNP * 256;      // [NP,256] (sized for max rows)
  bf16* mt = kt + (size_t)kNP * 256;      // [NP,256]
  float* tr_a = (float*)R;                // fp32 view of R, disjoint lifetime
  float* tr_p = tr_a + (size_t)kNA * 256;
  char* afterR = R + (size_t)(kNA + 3 * kNP) * 256 * sizeof(bf16);
  bf16* agg_a = (bf16*)afterR;            // [NA,256]
  bf16* agg_p = agg_a + (size_t)kNA * 256;// [NP,256]
  float* Keff = (float*)(agg_p + (size_t)kNP * 256);
  float* Meff = Keff + (size_t)6 * 65536;
  float* kbe  = Meff + (size_t)6 * 65536;
  float* mbe  = kbe + (size_t)6 * 256;

  const bf16* c_ew_wb = canon + kOff(0);
  const bf16* c_ew_w  = canon + kOff(1);
  const bf16* c_ew_c  = canon + kOff(2);
  const bf16* c_adW   = canon + kOff(3);
  const bf16* c_adb   = canon + kOff(4);
  const bf16* c_kW    = canon + kOff(5);
  const bf16* c_kb    = canon + kOff(6);
  const bf16* c_qW    = canon + kOff(7);
  const bf16* c_qb    = canon + kOff(8);
  const bf16* c_mW    = canon + kOff(9);
  const bf16* c_mb    = canon + kOff(10);
  const bf16* c_aW    = canon + kOff(11);
  const bf16* c_ab    = canon + kOff(12);
  const bf16* c_wpri  = canon + kOff(13);
  const bf16* c_watt  = canon + kOff(14);
  const bf16* c_wmsg  = canon + kOff(15);
  const bf16* c_skip  = canon + kOff(16);
  const bf16* c_lng   = canon + kOff(17);
  const bf16* c_lnb   = canon + kOff(18);
  const bf16* c_outW  = canon + kOff(19);
  const bf16* c_outb  = canon + kOff(20);

  const unsigned* fIn = flags + 0;
  const unsigned* f1  = flags + 1;

  detect_dtype<<<1, 256, 0, stream>>>((const unsigned*)d_in[0], flags);

  CanonArgs ca;
  for (int s = 0; s < kNSeg; ++s) { ca.n[s] = kSegN[s]; ca.dstOff[s] = (unsigned)kOff(s); }
  const int srcIdx[kNSeg] = {2,3,4, 5,6, 7,8, 9,10, 11,12, 13,14, 15, 16,17, 18,19,20, 21,22};
  for (int s = 0; s < kNSeg; ++s) ca.src[s] = d_in[srcIdx[s]];
  canon_kernel<<<dim3(1172, kNSeg), 256, 0, stream>>>(ca, canon, flags);

  // ---- CSR build (edges static across layers: build once per launch) ----
  hipMemsetAsync(cur_wb, 0, (size_t)((kNA + 1) + 2 * (kNP + 1)) * 4, stream);
  csr_hist<<<(kEWB + 255) / 256, 256, 0, stream>>>(dst_wb, kEWB, cur_wb);
  csr_hist<<<(kEW  + 255) / 256, 256, 0, stream>>>(dst_w,  kEW,  cur_w);
  csr_hist<<<(kEC  + 255) / 256, 256, 0, stream>>>(dst_c,  kEC,  cur_c);
  csr_scan<<<1, 1024, 0, stream>>>(cur_wb, offs_wb, kNA);
  csr_scan<<<1, 1024, 0, stream>>>(cur_w,  offs_w,  kNP);
  csr_scan<<<1, 1024, 0, stream>>>(cur_c,  offs_c,  kNP);
  csr_scatter<<<(kEWB + 255) / 256, 256, 0, stream>>>(dst_wb, kEWB, cur_wb, sort_wb);
  csr_scatter<<<(kEW  + 255) / 256, 256, 0, stream>>>(dst_w,  kEW,  cur_w,  sort_w);
  csr_scatter<<<(kEC  + 255) / 256, 256, 0, stream>>>(dst_c,  kEC,  cur_c,  sort_c);

  auto gA = [](int m) { return dim3((unsigned)((m + 63) / 64), 4); };

  combine_weights<<<24, 256, 0, stream>>>(c_kW, c_kb, c_watt, Keff, kbe);
  combine_weights<<<24, 256, 0, stream>>>(c_mW, c_mb, c_wmsg, Meff, mbe);

  // adapt: feats = gelu(x @ adapt_W + adapt_b); x read dual-dtype
  gemm_k256<bf16, bf16><<<gA(kNA), 256, 0, stream>>>(d_in[0], fIn, c_adW,         c_adb,       fa,  kNA, 1, 1.f);
  gemm_k256<bf16, bf16><<<gA(kNP), 256, 0, stream>>>(d_in[1], fIn, c_adW + 65536, c_adb + 256, fp_, kNP, 1, 1.f);

  for (int l = 0; l < 2; ++l) {
    gemm_k256<bf16, bf16><<<gA(kNA), 256, 0, stream>>>(
        fa,  f1, c_qW + (size_t)(l * 2 + 0) * 65536, c_qb + (l * 2 + 0) * 256, qa, kNA, 0, 1.f);
    gemm_k256<bf16, bf16><<<gA(kNP), 256, 0, stream>>>(
        fp_, f1, c_qW + (size_t)(l * 2 + 1) * 65536, c_qb + (l * 2 + 1) * 256, qp, kNP, 0, 1.f);

    // WRITTEN_BY (e=2): paper -> author
    gemm_k256<float, bf16><<<gA(kNP), 256, 0, stream>>>(
        fp_, f1, Keff + (size_t)(l * 3 + 2) * 65536, kbe + (l * 3 + 2) * 256, kt, kNP, 0, 1.f);
    gemm_k256<float, bf16><<<gA(kNP), 256, 0, stream>>>(
        fp_, f1, Meff + (size_t)(l * 3 + 2) * 65536, mbe + (l * 3 + 2) * 256, mt, kNP, 0, 1.f);
    gather_kernel<<<(kNA + 3) / 4, 256, 0, stream>>>(
        qa, kt, mt, src_wb, sort_wb, offs_wb, c_ew_wb, c_wpri + (l * 3 + 2) * 4,
        agg_a, kNA, 0, 1.f);

    // WRITES (e=1): author -> paper
    gemm_k256<float, bf16><<<gA(kNA), 256, 0, stream>>>(
        fa, f1, Keff + (size_t)(l * 3 + 1) * 65536, kbe + (l * 3 + 1) * 256, kt, kNA, 0, 1.f);
    gemm_k256<float, bf16><<<gA(kNA), 256, 0, stream>>>(
        fa, f1, Meff + (size_t)(l * 3 + 1) * 65536, mbe + (l * 3 + 1) * 256, mt, kNA, 0, 1.f);
    gather_kernel<<<(kNP + 3) / 4, 256, 0, stream>>>(
        qp, kt, mt, src_w, sort_w, offs_w, c_ew_w, c_wpri + (l * 3 + 1) * 4,
        agg_p, kNP, 0, 1.f);

    // CITES (e=0): paper -> paper, chained add + 0.5 mean
    gemm_k256<float, bf16><<<gA(kNP), 256, 0, stream>>>(
        fp_, f1, Keff + (size_t)(l * 3 + 0) * 65536, kbe + (l * 3 + 0) * 256, kt, kNP, 0, 1.f);
    gemm_k256<float, bf16><<<gA(kNP), 256, 0, stream>>>(
        fp_, f1, Meff + (size_t)(l * 3 + 0) * 65536, mbe + (l * 3 + 0) * 256, mt, kNP, 0, 1.f);
    gather_kernel<<<(kNP + 3) / 4, 256, 0, stream>>>(
        qp, kt, mt, src_c, sort_c, offs_c, c_ew_c, c_wpri + (l * 3 + 0) * 4,
        agg_p, kNP, 1, 0.5f);

    // A-projection of aggregates (mean already applied in gather)
    gemm_k256<bf16, float><<<gA(kNA), 256, 0, stream>>>(
        agg_a, f1, c_aW + (size_t)(l * 2 + 0) * 65536, c_ab + (l * 2 + 0) * 256, tr_a, kNA, 0, 1.f);
    gemm_k256<bf16, float><<<gA(kNP), 256, 0, stream>>>(
        agg_p, f1, c_aW + (size_t)(l * 2 + 1) * 65536, c_ab + (l * 2 + 1) * 256, tr_p, kNP, 0, 1.f);

    skip_ln<<<kNA / 4, 256, 0, stream>>>(
        tr_a, fa,  c_skip + l * 3 + 0, c_lng + (l * 2 + 0) * 256, c_lnb + (l * 2 + 0) * 256, kNA);
    skip_ln<<<kNP / 4, 256, 0, stream>>>(
        tr_p, fp_, c_skip + l * 3 + 1, c_lng + (l * 2 + 1) * 256, c_lnb + (l * 2 + 1) * 256, kNP);
  }

  out_gemm<<<kNP / 64, 256, 0, stream>>>(fp_, c_outW, c_outb, d_out, fIn, kNP);
}

// Round 5
// 1700.013 us; speedup vs baseline: 3.8576x; 1.7341x over previous
//
#include <hip/hip_runtime.h>
#include <hip/hip_bf16.h>
#include <math.h>

using bf16 = __hip_bfloat16;

typedef __attribute__((ext_vector_type(8))) short short8;   // 8 bf16 (4 VGPRs)
typedef __attribute__((ext_vector_type(4))) float float4v;  // MFMA acc

static constexpr int kNA  = 20000;
static constexpr int kNP  = 40000;
static constexpr int kEWB = 150000;
static constexpr int kEW  = 150000;
static constexpr int kEC  = 300000;

// ---- canonical bf16 input region: segment sizes & offsets (element counts) ----
static constexpr int kNSeg = 21;
static constexpr int kSegN[kNSeg] = {
  150000, 150000, 300000,           // ew_wb, ew_w, ew_c
  131072, 512,                      // adW, adb
  262144, 1024,                     // kW, kb
  262144, 1024,                     // qW, qb
  262144, 1024,                     // mW, mb
  262144, 1024,                     // aW, ab
  24,                               // wpri
  98304, 98304,                     // watt, wmsg
  6, 1024, 1024,                    // skip, lng, lnb
  16384, 64                         // outW, outb
};
static constexpr size_t kOff(int s) {
  size_t o = 0;
  for (int i = 0; i < s; ++i) o += (size_t)kSegN[i];
  return o;
}
static constexpr size_t kCanonTotal = kOff(kNSeg);

struct CanonArgs {
  const void* src[kNSeg];
  int n[kNSeg];
  unsigned dstOff[kNSeg];
};
struct TransArgs {
  const bf16* src[10];
  bf16* dst[10];
};

__device__ __forceinline__ float toF(float x) { return x; }
__device__ __forceinline__ float toF(bf16 x)  { return __bfloat162float(x); }
__device__ __forceinline__ float bits2f(unsigned short b) {
  unsigned int u = ((unsigned int)b) << 16;
  return __uint_as_float(u);
}
__device__ __forceinline__ void storeOut(float* p, float v) { *p = v; }
__device__ __forceinline__ void storeOut(bf16* p, float v)  { *p = __float2bfloat16(v); }
__device__ __forceinline__ float sigmoidf_(float x) { return 1.0f / (1.0f + expf(-x)); }
__device__ __forceinline__ float gelu_exact(float x) {
  return 0.5f * x * (1.0f + erff(x * 0.70710678118654752f));
}

// -------------------------------------------------------------------------
// Input-dtype sniffer. flags: [0]=isBf16 [1]=1
// -------------------------------------------------------------------------
__global__ __launch_bounds__(256) void detect_dtype(
    const unsigned* __restrict__ x, unsigned* __restrict__ flags)
{
  __shared__ int cnt;
  if (threadIdx.x == 0) cnt = 0;
  __syncthreads();
  unsigned w = x[threadIdx.x];
  unsigned e = (w >> 7) & 0xFFu;
  if (e >= 110u && e <= 140u) atomicAdd(&cnt, 1);
  __syncthreads();
  if (threadIdx.x == 0) {
    flags[0] = (cnt >= 128) ? 1u : 0u;
    flags[1] = 1u;
  }
}

__global__ __launch_bounds__(256) void canon_kernel(
    CanonArgs a, bf16* __restrict__ dst, const unsigned* __restrict__ flags)
{
  const int s = blockIdx.y;
  const int i = blockIdx.x * 256 + threadIdx.x;
  if (i >= a.n[s]) return;
  bf16 v;
  if (flags[0]) v = ((const bf16*)a.src[s])[i];
  else          v = __float2bfloat16(((const float*)a.src[s])[i]);
  dst[a.dstOff[s] + i] = v;
}

// -------------------------------------------------------------------------
// Batched 256x256 weight transpose: dst[n][k] = src[k][n]. grid (4,4,10).
// -------------------------------------------------------------------------
__global__ __launch_bounds__(256) void transpose_w(TransArgs ta)
{
  const int m = blockIdx.z;
  const short* src = (const short*)ta.src[m];
  short* dst = (short*)ta.dst[m];
  const int k0 = blockIdx.x * 64, n0 = blockIdx.y * 64;
  __shared__ short tile[64][65];
  const int tx = threadIdx.x & 63, ty = threadIdx.x >> 6;
  for (int i = ty; i < 64; i += 4)
    tile[i][tx] = src[(size_t)(k0 + i) * 256 + n0 + tx];
  __syncthreads();
  for (int i = ty; i < 64; i += 4)
    dst[(size_t)(n0 + i) * 256 + k0 + tx] = tile[tx][i];
}

// -------------------------------------------------------------------------
// CSR build: histogram -> exclusive scan (single block) -> scatter.
// -------------------------------------------------------------------------
__global__ __launch_bounds__(256) void csr_hist(
    const int* __restrict__ dst, int E, int* __restrict__ cnt)
{
  const int i = blockIdx.x * 256 + threadIdx.x;
  if (i < E) atomicAdd(&cnt[dst[i]], 1);
}

__global__ __launch_bounds__(1024) void csr_scan(
    int* __restrict__ cur, int* __restrict__ offs, int N)
{
  __shared__ int buf[1024];
  __shared__ int carry;
  const int tid = threadIdx.x;
  if (tid == 0) carry = 0;
  __syncthreads();
  for (int base = 0; base < N; base += 1024) {
    const int idx = base + tid;
    const int v = (idx < N) ? cur[idx] : 0;
    buf[tid] = v;
    __syncthreads();
    for (int off = 1; off < 1024; off <<= 1) {
      int t = (tid >= off) ? buf[tid - off] : 0;
      __syncthreads();
      buf[tid] += t;
      __syncthreads();
    }
    const int excl = buf[tid] - v;
    const int total = buf[1023];
    if (idx < N) {
      const int o = carry + excl;
      offs[idx] = o;
      cur[idx] = o;
    }
    __syncthreads();
    if (tid == 0) carry += total;
    __syncthreads();
  }
  if (tid == 0) offs[N] = carry;
}

__global__ __launch_bounds__(256) void csr_scatter(
    const int* __restrict__ dst, int E, int* __restrict__ cur, int* __restrict__ sorted)
{
  const int i = blockIdx.x * 256 + threadIdx.x;
  if (i >= E) return;
  const int p = atomicAdd(&cur[dst[i]], 1);
  sorted[p] = i;
}

// -------------------------------------------------------------------------
// Fold per-head w_att/w_msg into K/M projections; emit bf16 TRANSPOSED
// EffT[n][k] plus bf16 bias. 24 blocks.
// -------------------------------------------------------------------------
__global__ __launch_bounds__(256) void combine_weights(
    const bf16* __restrict__ Wbig, const bf16* __restrict__ bbig,
    const bf16* __restrict__ wsm, bf16* __restrict__ EffT, bf16* __restrict__ beff)
{
  const int blk = blockIdx.x;
  const int h = blk & 3;
  const int le = blk >> 2;
  const int e = le % 3;
  const int l = le / 3;
  const int st = (e == 1) ? 0 : 1;

  const bf16* Wsrc = Wbig + (size_t)(l * 2 + st) * 65536;
  const bf16* bsrc = bbig + (size_t)(l * 2 + st) * 256;
  const bf16* wm   = wsm  + ((size_t)(l * 3 + e) * 4 + h) * 4096;
  bf16* outWT = EffT + (size_t)(l * 3 + e) * 65536;
  bf16* outb  = beff + (size_t)(l * 3 + e) * 256;

  __shared__ float w[64][64];
  const int tid = threadIdx.x;
  for (int i = tid; i < 4096; i += 256) w[i >> 6][i & 63] = toF(wm[i]);
  __syncthreads();

  const int j  = tid & 63;
  const int i0 = tid >> 6;
  for (int i = i0; i < 256; i += 4) {
    float acc = 0.f;
    #pragma unroll 8
    for (int d = 0; d < 64; ++d) acc += toF(Wsrc[(size_t)i * 256 + h * 64 + d]) * w[d][j];
    outWT[(size_t)(h * 64 + j) * 256 + i] = __float2bfloat16(acc);  // transposed [n][k]
  }
  if (tid < 64) {
    float acc = 0.f;
    #pragma unroll 8
    for (int d = 0; d < 64; ++d) acc += toF(bsrc[h * 64 + d]) * w[d][tid];
    outb[h * 64 + tid] = __float2bfloat16(acc);
  }
}

// -------------------------------------------------------------------------
// MFMA GEMM: C[M,256] = act( A[M,256] @ W + bias ), W given transposed
// WT[n][k] bf16. Block = 256 thr (4 waves), tile 128(M) x 256(N), BK=64.
// Wave w owns cols w*64..w*64+63: 8 m-tiles x 4 n-tiles of 16x16x32 MFMA.
// A dtype runtime-selected (*aflag: 1=bf16, 0=fp32->converted in staging).
// -------------------------------------------------------------------------
template <typename OT>
__global__ __launch_bounds__(256) void mfma_gemm(
    const void* __restrict__ A, const unsigned* __restrict__ aflag,
    const bf16* __restrict__ WT, const bf16* __restrict__ bias,
    OT* __restrict__ C, int M, int act)
{
  __shared__ short As[128][72];
  __shared__ short Bs[256][72];
  const bool abf = (*aflag != 0u);
  const int t = threadIdx.x;
  const int bm = blockIdx.x * 128;
  const int lane = t & 63;
  const int wid  = t >> 6;
  const int n0 = wid * 64;
  const int col16 = lane & 15;
  const int quad  = lane >> 4;
  const int rr = t >> 3;        // staging row 0..31
  const int kk = (t & 7) * 8;   // staging k-offset

  float4v acc[8][4];
  #pragma unroll
  for (int mi = 0; mi < 8; ++mi)
    #pragma unroll
    for (int ni = 0; ni < 4; ++ni) acc[mi][ni] = (float4v){0.f, 0.f, 0.f, 0.f};

  for (int k0 = 0; k0 < 256; k0 += 64) {
    // stage A (128 x 64)
    #pragma unroll
    for (int it = 0; it < 4; ++it) {
      const int row = it * 32 + rr;
      const int grow = bm + row;
      short8 v = (short8){0, 0, 0, 0, 0, 0, 0, 0};
      if (grow < M) {
        if (abf) {
          v = *(const short8*)((const short*)A + (size_t)grow * 256 + k0 + kk);
        } else {
          const float* ap = (const float*)A + (size_t)grow * 256 + k0 + kk;
          #pragma unroll
          for (int j = 0; j < 8; ++j) {
            union { bf16 h; short s; } cv;
            cv.h = __float2bfloat16(ap[j]);
            v[j] = cv.s;
          }
        }
      }
      *(short8*)&As[row][kk] = v;
    }
    // stage B (256 x 64) from WT[n][k]
    #pragma unroll
    for (int it = 0; it < 8; ++it) {
      const int n = it * 32 + rr;
      *(short8*)&Bs[n][kk] = *(const short8*)((const short*)WT + (size_t)n * 256 + k0 + kk);
    }
    __syncthreads();

    #pragma unroll
    for (int ks = 0; ks < 64; ks += 32) {
      short8 bfr[4];
      #pragma unroll
      for (int ni = 0; ni < 4; ++ni)
        bfr[ni] = *(const short8*)&Bs[n0 + ni * 16 + col16][ks + quad * 8];
      #pragma unroll
      for (int mi = 0; mi < 8; ++mi) {
        const short8 afr = *(const short8*)&As[mi * 16 + col16][ks + quad * 8];
        #pragma unroll
        for (int ni = 0; ni < 4; ++ni)
          acc[mi][ni] = __builtin_amdgcn_mfma_f32_16x16x32_bf16(afr, bfr[ni], acc[mi][ni], 0, 0, 0);
      }
    }
    __syncthreads();
  }

  // epilogue: D row = quad*4 + r (within 16-tile), col = col16
  #pragma unroll
  for (int ni = 0; ni < 4; ++ni) {
    const int col = n0 + ni * 16 + col16;
    const float bc = toF(bias[col]);
    #pragma unroll
    for (int mi = 0; mi < 8; ++mi) {
      #pragma unroll
      for (int r = 0; r < 4; ++r) {
        const int row = bm + mi * 16 + quad * 4 + r;
        if (row < M) {
          float v = acc[mi][ni][r] + bc;
          if (act == 1) v = gelu_exact(v);
          storeOut(&C[(size_t)row * 256 + col], v);
        }
      }
    }
  }
}

// -------------------------------------------------------------------------
// CSR gather: one wave per dst node, fp32 register accumulation, one
// non-atomic bf16 write per node.
// -------------------------------------------------------------------------
__global__ __launch_bounds__(256) void gather_kernel(
    const bf16* __restrict__ q, const bf16* __restrict__ kt, const bf16* __restrict__ mt,
    const int* __restrict__ src, const int* __restrict__ sorted, const int* __restrict__ offs,
    const bf16* __restrict__ ew, const bf16* __restrict__ pri,
    bf16* __restrict__ agg, int Nd, int addPrev, float finalScale)
{
  const int lane = threadIdx.x & 63;
  const int wid  = threadIdx.x >> 6;
  const int node = blockIdx.x * 4 + wid;
  if (node >= Nd) return;

  union B4 { uint2 u; unsigned short s[4]; };
  B4 qv;
  qv.u = ((const uint2*)(q + (size_t)node * 256))[lane];
  float qf[4];
  #pragma unroll
  for (int j = 0; j < 4; ++j) qf[j] = bits2f(qv.s[j]);
  const float prih = toF(pri[lane >> 4]);

  float acc[4] = {0.f, 0.f, 0.f, 0.f};
  const int beg = offs[node], end = offs[node + 1];
  for (int idx = beg; idx < end; ++idx) {
    const int e = sorted[idx];
    const int s = src[e];
    B4 kb;
    kb.u = ((const uint2*)(kt + (size_t)s * 256))[lane];
    float dot = 0.f;
    #pragma unroll
    for (int j = 0; j < 4; ++j) dot += qf[j] * bits2f(kb.s[j]);
    #pragma unroll
    for (int off = 1; off < 16; off <<= 1) dot += __shfl_xor(dot, off);
    const float a = toF(ew[e]) * sigmoidf_(dot * prih * 0.125f);
    B4 mb;
    mb.u = ((const uint2*)(mt + (size_t)s * 256))[lane];
    #pragma unroll
    for (int j = 0; j < 4; ++j) acc[j] += bits2f(mb.s[j]) * a;
  }

  if (addPrev) {
    B4 pb;
    pb.u = ((const uint2*)(agg + (size_t)node * 256))[lane];
    #pragma unroll
    for (int j = 0; j < 4; ++j) acc[j] += bits2f(pb.s[j]);
  }
  bf16* out = agg + (size_t)node * 256 + lane * 4;
  #pragma unroll
  for (int j = 0; j < 4; ++j) out[j] = __float2bfloat16(acc[j] * finalScale);
}

// -------------------------------------------------------------------------
// o = tr*alpha + feat*(1-alpha); feat = bf16(LN(o)*g + b). One wave per node.
// -------------------------------------------------------------------------
__global__ __launch_bounds__(256) void skip_ln(
    const float* __restrict__ tr, bf16* __restrict__ feat,
    const bf16* __restrict__ skipv, const bf16* __restrict__ g,
    const bf16* __restrict__ b, int N)
{
  const int lane = threadIdx.x & 63;
  const int wid  = threadIdx.x >> 6;
  const int node = blockIdx.x * 4 + wid;
  if (node >= N) return;
  const float alpha = sigmoidf_(toF(*skipv));
  const float4 t = ((const float4*)(tr + (size_t)node * 256))[lane];
  union B4 { uint2 u; unsigned short s[4]; };
  B4 fb;
  fb.u = ((const uint2*)(feat + (size_t)node * 256))[lane];
  float o[4];
  o[0] = t.x * alpha + bits2f(fb.s[0]) * (1.f - alpha);
  o[1] = t.y * alpha + bits2f(fb.s[1]) * (1.f - alpha);
  o[2] = t.z * alpha + bits2f(fb.s[2]) * (1.f - alpha);
  o[3] = t.w * alpha + bits2f(fb.s[3]) * (1.f - alpha);

  float sum = o[0] + o[1] + o[2] + o[3];
  #pragma unroll
  for (int off = 32; off; off >>= 1) sum += __shfl_xor(sum, off);
  const float mu = sum * (1.f / 256.f);

  float dd[4], sq = 0.f;
  #pragma unroll
  for (int j = 0; j < 4; ++j) { dd[j] = o[j] - mu; sq += dd[j] * dd[j]; }
  #pragma unroll
  for (int off = 32; off; off >>= 1) sq += __shfl_xor(sq, off);
  const float rs = rsqrtf(sq * (1.f / 256.f) + 1e-5f);

  bf16* fout = feat + (size_t)node * 256 + lane * 4;
  #pragma unroll
  for (int j = 0; j < 4; ++j) {
    float r = dd[j] * rs * toF(g[lane * 4 + j]) + toF(b[lane * 4 + j]);
    fout[j] = __float2bfloat16(r);
  }
}

// -------------------------------------------------------------------------
// out[M,64] = A[M,256] @ W[256,64] + b[64]; output dtype per *flag.
// -------------------------------------------------------------------------
__global__ __launch_bounds__(256) void out_gemm(
    const bf16* __restrict__ A, const bf16* __restrict__ W,
    const bf16* __restrict__ bias, void* __restrict__ out,
    const unsigned* __restrict__ flag, int M)
{
  __shared__ float Ws[64][64];
  const bool obf = (*flag != 0u);
  const int tid = threadIdx.x;
  const int row = blockIdx.x * 64 + (tid >> 2);
  const int c0 = (tid & 3) * 16;
  const int arow = (row < M) ? row : 0;
  const bf16* a = A + (size_t)arow * 256;
  float acc[16] = {};
  for (int k0 = 0; k0 < 256; k0 += 64) {
    for (int i = tid; i < 4096; i += 256)
      Ws[i >> 6][i & 63] = toF(W[(size_t)(k0 + (i >> 6)) * 64 + (i & 63)]);
    __syncthreads();
    for (int k = 0; k < 64; ++k) {
      const float av = toF(a[k0 + k]);
      #pragma unroll
      for (int j = 0; j < 16; ++j) acc[j] += av * Ws[k][c0 + j];
    }
    __syncthreads();
  }
  if (row < M) {
    #pragma unroll
    for (int j = 0; j < 16; ++j) {
      const float v = acc[j] + toF(bias[c0 + j]);
      const size_t idx = (size_t)row * 64 + c0 + j;
      if (obf) ((bf16*)out)[idx] = __float2bfloat16(v);
      else     ((float*)out)[idx] = v;
    }
  }
}

// -------------------------------------------------------------------------
extern "C" void kernel_launch(void* const* d_in, const int* in_sizes, int n_in,
                              void* d_out, int out_size, void* d_ws, size_t ws_size,
                              hipStream_t stream) {
  const int* src_wb  = (const int*)d_in[23];
  const int* dst_wb  = (const int*)d_in[24];
  const int* src_w   = (const int*)d_in[25];
  const int* dst_w   = (const int*)d_in[26];
  const int* src_c   = (const int*)d_in[27];
  const int* dst_c   = (const int*)d_in[28];

  // ---- workspace carve (~144 MB total) ----
  char* base = (char*)d_ws;
  unsigned* flags = (unsigned*)base;                       // 256 B
  bf16* canon = (bf16*)(base + 256);
  char* p = base + 256 + (((size_t)kCanonTotal * 2 + 511) & ~(size_t)511);
  // transposed weights (bf16 [n][k])
  bf16* adWT = (bf16*)p;                  // 2 x 65536
  bf16* qWT  = adWT + (size_t)2 * 65536;  // 4 x 65536
  bf16* aWT  = qWT  + (size_t)4 * 65536;  // 4 x 65536
  bf16* KeffT = aWT + (size_t)4 * 65536;  // 6 x 65536
  bf16* MeffT = KeffT + (size_t)6 * 65536;
  bf16* kbeT  = MeffT + (size_t)6 * 65536; // 6 x 256
  bf16* mbeT  = kbeT + (size_t)6 * 256;
  char* pc = (char*)(((size_t)(mbeT + 6 * 256) + 511) & ~(size_t)511);
  // CSR region
  int* cur_wb  = (int*)pc;
  int* cur_w   = cur_wb + (kNA + 1);
  int* cur_c   = cur_w + (kNP + 1);
  int* offs_wb = cur_c + (kNP + 1);
  int* offs_w  = offs_wb + (kNA + 1);
  int* offs_c  = offs_w + (kNP + 1);
  int* sort_wb = offs_c + (kNP + 1);
  int* sort_w  = sort_wb + kEWB;
  int* sort_c  = sort_w + kEW;
  char* p2 = (char*)(((size_t)(sort_c + kEC) + 511) & ~(size_t)511);
  bf16* fa  = (bf16*)p2;                  // [NA,256]
  bf16* fp_ = fa + (size_t)kNA * 256;     // [NP,256]
  char* R   = (char*)(fp_ + (size_t)kNP * 256);
  bf16* qa = (bf16*)R;                    // [NA,256]
  bf16* qp = qa + (size_t)kNA * 256;      // [NP,256]
  bf16* kt = qp + (size_t)kNP * 256;      // [NP,256]
  bf16* mt = kt + (size_t)kNP * 256;      // [NP,256]
  float* tr_a = (float*)R;                // fp32 view, disjoint lifetime
  float* tr_p = tr_a + (size_t)kNA * 256;
  char* afterR = R + (size_t)(kNA + 3 * kNP) * 256 * sizeof(bf16);
  bf16* agg_a = (bf16*)afterR;            // [NA,256]
  bf16* agg_p = agg_a + (size_t)kNA * 256;// [NP,256]

  const bf16* c_ew_wb = canon + kOff(0);
  const bf16* c_ew_w  = canon + kOff(1);
  const bf16* c_ew_c  = canon + kOff(2);
  const bf16* c_adW   = canon + kOff(3);
  const bf16* c_adb   = canon + kOff(4);
  const bf16* c_kW    = canon + kOff(5);
  const bf16* c_kb    = canon + kOff(6);
  const bf16* c_qW    = canon + kOff(7);
  const bf16* c_qb    = canon + kOff(8);
  const bf16* c_mW    = canon + kOff(9);
  const bf16* c_mb    = canon + kOff(10);
  const bf16* c_aW    = canon + kOff(11);
  const bf16* c_ab    = canon + kOff(12);
  const bf16* c_wpri  = canon + kOff(13);
  const bf16* c_watt  = canon + kOff(14);
  const bf16* c_wmsg  = canon + kOff(15);
  const bf16* c_skip  = canon + kOff(16);
  const bf16* c_lng   = canon + kOff(17);
  const bf16* c_lnb   = canon + kOff(18);
  const bf16* c_outW  = canon + kOff(19);
  const bf16* c_outb  = canon + kOff(20);

  const unsigned* fIn = flags + 0;
  const unsigned* f1  = flags + 1;

  detect_dtype<<<1, 256, 0, stream>>>((const unsigned*)d_in[0], flags);

  CanonArgs ca;
  for (int s = 0; s < kNSeg; ++s) { ca.n[s] = kSegN[s]; ca.dstOff[s] = (unsigned)kOff(s); }
  const int srcIdx[kNSeg] = {2,3,4, 5,6, 7,8, 9,10, 11,12, 13,14, 15, 16,17, 18,19,20, 21,22};
  for (int s = 0; s < kNSeg; ++s) ca.src[s] = d_in[srcIdx[s]];
  canon_kernel<<<dim3(1172, kNSeg), 256, 0, stream>>>(ca, canon, flags);

  // ---- transpose the 10 dense 256x256 weights into [n][k] layout ----
  TransArgs ta;
  ta.src[0] = c_adW;              ta.dst[0] = adWT;
  ta.src[1] = c_adW + 65536;      ta.dst[1] = adWT + 65536;
  for (int m = 0; m < 4; ++m) { ta.src[2 + m] = c_qW + (size_t)m * 65536; ta.dst[2 + m] = qWT + (size_t)m * 65536; }
  for (int m = 0; m < 4; ++m) { ta.src[6 + m] = c_aW + (size_t)m * 65536; ta.dst[6 + m] = aWT + (size_t)m * 65536; }
  transpose_w<<<dim3(4, 4, 10), 256, 0, stream>>>(ta);

  // ---- CSR build (edges static: once per launch) ----
  hipMemsetAsync(cur_wb, 0, (size_t)((kNA + 1) + 2 * (kNP + 1)) * 4, stream);
  csr_hist<<<(kEWB + 255) / 256, 256, 0, stream>>>(dst_wb, kEWB, cur_wb);
  csr_hist<<<(kEW  + 255) / 256, 256, 0, stream>>>(dst_w,  kEW,  cur_w);
  csr_hist<<<(kEC  + 255) / 256, 256, 0, stream>>>(dst_c,  kEC,  cur_c);
  csr_scan<<<1, 1024, 0, stream>>>(cur_wb, offs_wb, kNA);
  csr_scan<<<1, 1024, 0, stream>>>(cur_w,  offs_w,  kNP);
  csr_scan<<<1, 1024, 0, stream>>>(cur_c,  offs_c,  kNP);
  csr_scatter<<<(kEWB + 255) / 256, 256, 0, stream>>>(dst_wb, kEWB, cur_wb, sort_wb);
  csr_scatter<<<(kEW  + 255) / 256, 256, 0, stream>>>(dst_w,  kEW,  cur_w,  sort_w);
  csr_scatter<<<(kEC  + 255) / 256, 256, 0, stream>>>(dst_c,  kEC,  cur_c,  sort_c);

  combine_weights<<<24, 256, 0, stream>>>(c_kW, c_kb, c_watt, KeffT, kbeT);
  combine_weights<<<24, 256, 0, stream>>>(c_mW, c_mb, c_wmsg, MeffT, mbeT);

  auto gM = [](int m) { return dim3((unsigned)((m + 127) / 128)); };

  // adapt: feats = gelu(x @ adapt_W + adapt_b); x read dual-dtype
  mfma_gemm<bf16><<<gM(kNA), 256, 0, stream>>>(d_in[0], fIn, adWT,         c_adb,       fa,  kNA, 1);
  mfma_gemm<bf16><<<gM(kNP), 256, 0, stream>>>(d_in[1], fIn, adWT + 65536, c_adb + 256, fp_, kNP, 1);

  for (int l = 0; l < 2; ++l) {
    mfma_gemm<bf16><<<gM(kNA), 256, 0, stream>>>(
        fa,  f1, qWT + (size_t)(l * 2 + 0) * 65536, c_qb + (l * 2 + 0) * 256, qa, kNA, 0);
    mfma_gemm<bf16><<<gM(kNP), 256, 0, stream>>>(
        fp_, f1, qWT + (size_t)(l * 2 + 1) * 65536, c_qb + (l * 2 + 1) * 256, qp, kNP, 0);

    // WRITTEN_BY (e=2): paper -> author
    mfma_gemm<bf16><<<gM(kNP), 256, 0, stream>>>(
        fp_, f1, KeffT + (size_t)(l * 3 + 2) * 65536, kbeT + (l * 3 + 2) * 256, kt, kNP, 0);
    mfma_gemm<bf16><<<gM(kNP), 256, 0, stream>>>(
        fp_, f1, MeffT + (size_t)(l * 3 + 2) * 65536, mbeT + (l * 3 + 2) * 256, mt, kNP, 0);
    gather_kernel<<<(kNA + 3) / 4, 256, 0, stream>>>(
        qa, kt, mt, src_wb, sort_wb, offs_wb, c_ew_wb, c_wpri + (l * 3 + 2) * 4,
        agg_a, kNA, 0, 1.f);

    // WRITES (e=1): author -> paper
    mfma_gemm<bf16><<<gM(kNA), 256, 0, stream>>>(
        fa, f1, KeffT + (size_t)(l * 3 + 1) * 65536, kbeT + (l * 3 + 1) * 256, kt, kNA, 0);
    mfma_gemm<bf16><<<gM(kNA), 256, 0, stream>>>(
        fa, f1, MeffT + (size_t)(l * 3 + 1) * 65536, mbeT + (l * 3 + 1) * 256, mt, kNA, 0);
    gather_kernel<<<(kNP + 3) / 4, 256, 0, stream>>>(
        qp, kt, mt, src_w, sort_w, offs_w, c_ew_w, c_wpri + (l * 3 + 1) * 4,
        agg_p, kNP, 0, 1.f);

    // CITES (e=0): paper -> paper, chained add + 0.5 mean
    mfma_gemm<bf16><<<gM(kNP), 256, 0, stream>>>(
        fp_, f1, KeffT + (size_t)(l * 3 + 0) * 65536, kbeT + (l * 3 + 0) * 256, kt, kNP, 0);
    mfma_gemm<bf16><<<gM(kNP), 256, 0, stream>>>(
        fp_, f1, MeffT + (size_t)(l * 3 + 0) * 65536, mbeT + (l * 3 + 0) * 256, mt, kNP, 0);
    gather_kernel<<<(kNP + 3) / 4, 256, 0, stream>>>(
        qp, kt, mt, src_c, sort_c, offs_c, c_ew_c, c_wpri + (l * 3 + 0) * 4,
        agg_p, kNP, 1, 0.5f);

    // A-projection of aggregates
    mfma_gemm<float><<<gM(kNA), 256, 0, stream>>>(
        agg_a, f1, aWT + (size_t)(l * 2 + 0) * 65536, c_ab + (l * 2 + 0) * 256, tr_a, kNA, 0);
    mfma_gemm<float><<<gM(kNP), 256, 0, stream>>>(
        agg_p, f1, aWT + (size_t)(l * 2 + 1) * 65536, c_ab + (l * 2 + 1) * 256, tr_p, kNP, 0);

    skip_ln<<<kNA / 4, 256, 0, stream>>>(
        tr_a, fa,  c_skip + l * 3 + 0, c_lng + (l * 2 + 0) * 256, c_lnb + (l * 2 + 0) * 256, kNA);
    skip_ln<<<kNP / 4, 256, 0, stream>>>(
        tr_p, fp_, c_skip + l * 3 + 1, c_lng + (l * 2 + 1) * 256, c_lnb + (l * 2 + 1) * 256, kNP);
  }

  out_gemm<<<kNP / 64, 256, 0, stream>>>(fp_, c_outW, c_outb, d_out, fIn, kNP);
}

// Round 6
// 1618.538 us; speedup vs baseline: 4.0518x; 1.0503x over previous
//
#include <hip/hip_runtime.h>
#include <hip/hip_bf16.h>
#include <math.h>

using bf16 = __hip_bfloat16;

typedef __attribute__((ext_vector_type(8))) short short8;   // 8 bf16 (4 VGPRs)
typedef __attribute__((ext_vector_type(4))) float float4v;  // MFMA acc

static constexpr int kNA  = 20000;
static constexpr int kNP  = 40000;
static constexpr int kEWB = 150000;
static constexpr int kEW  = 150000;
static constexpr int kEC  = 300000;

// ---- canonical bf16 input region ----
static constexpr int kNSeg = 21;
static constexpr int kSegN[kNSeg] = {
  150000, 150000, 300000,           // ew_wb, ew_w, ew_c
  131072, 512,                      // adW, adb
  262144, 1024,                     // kW, kb
  262144, 1024,                     // qW, qb
  262144, 1024,                     // mW, mb
  262144, 1024,                     // aW, ab
  24,                               // wpri
  98304, 98304,                     // watt, wmsg
  6, 1024, 1024,                    // skip, lng, lnb
  16384, 64                         // outW, outb
};
static constexpr size_t kOff(int s) {
  size_t o = 0;
  for (int i = 0; i < s; ++i) o += (size_t)kSegN[i];
  return o;
}
static constexpr size_t kCanonTotal = kOff(kNSeg);

struct CanonArgs {
  const void* src[kNSeg];
  int n[kNSeg];
  unsigned dstOff[kNSeg];
};
struct TransArgs {
  const bf16* src[10];
  bf16* dst[10];
};

__device__ __forceinline__ float toF(float x) { return x; }
__device__ __forceinline__ float toF(bf16 x)  { return __bfloat162float(x); }
__device__ __forceinline__ float bits2f(unsigned short b) {
  unsigned int u = ((unsigned int)b) << 16;
  return __uint_as_float(u);
}
__device__ __forceinline__ void storeOut(float* p, float v) { *p = v; }
__device__ __forceinline__ void storeOut(bf16* p, float v)  { *p = __float2bfloat16(v); }
__device__ __forceinline__ float sigmoidf_(float x) { return 1.0f / (1.0f + expf(-x)); }
__device__ __forceinline__ float gelu_exact(float x) {
  return 0.5f * x * (1.0f + erff(x * 0.70710678118654752f));
}

// -------------------------------------------------------------------------
// Input-dtype sniffer. flags: [0]=isBf16 [1]=1
// -------------------------------------------------------------------------
__global__ __launch_bounds__(256) void detect_dtype(
    const unsigned* __restrict__ x, unsigned* __restrict__ flags)
{
  __shared__ int cnt;
  if (threadIdx.x == 0) cnt = 0;
  __syncthreads();
  unsigned w = x[threadIdx.x];
  unsigned e = (w >> 7) & 0xFFu;
  if (e >= 110u && e <= 140u) atomicAdd(&cnt, 1);
  __syncthreads();
  if (threadIdx.x == 0) {
    flags[0] = (cnt >= 128) ? 1u : 0u;
    flags[1] = 1u;
  }
}

__global__ __launch_bounds__(256) void canon_kernel(
    CanonArgs a, bf16* __restrict__ dst, const unsigned* __restrict__ flags)
{
  const int s = blockIdx.y;
  const int i = blockIdx.x * 256 + threadIdx.x;
  if (i >= a.n[s]) return;
  bf16 v;
  if (flags[0]) v = ((const bf16*)a.src[s])[i];
  else          v = __float2bfloat16(((const float*)a.src[s])[i]);
  dst[a.dstOff[s] + i] = v;
}

// -------------------------------------------------------------------------
// Batched 256x256 weight transpose: dst[n][k] = src[k][n]. grid (4,4,10).
// -------------------------------------------------------------------------
__global__ __launch_bounds__(256) void transpose_w(TransArgs ta)
{
  const int m = blockIdx.z;
  const short* src = (const short*)ta.src[m];
  short* dst = (short*)ta.dst[m];
  const int k0 = blockIdx.x * 64, n0 = blockIdx.y * 64;
  __shared__ short tile[64][65];
  const int tx = threadIdx.x & 63, ty = threadIdx.x >> 6;
  for (int i = ty; i < 64; i += 4)
    tile[i][tx] = src[(size_t)(k0 + i) * 256 + n0 + tx];
  __syncthreads();
  for (int i = ty; i < 64; i += 4)
    dst[(size_t)(n0 + i) * 256 + k0 + tx] = tile[tx][i];
}

// -------------------------------------------------------------------------
// CSR build: histogram -> exclusive scan (single block) -> scatter.
// -------------------------------------------------------------------------
__global__ __launch_bounds__(256) void csr_hist(
    const int* __restrict__ dst, int E, int* __restrict__ cnt)
{
  const int i = blockIdx.x * 256 + threadIdx.x;
  if (i < E) atomicAdd(&cnt[dst[i]], 1);
}

__global__ __launch_bounds__(1024) void csr_scan(
    int* __restrict__ cur, int* __restrict__ offs, int N)
{
  __shared__ int buf[1024];
  __shared__ int carry;
  const int tid = threadIdx.x;
  if (tid == 0) carry = 0;
  __syncthreads();
  for (int base = 0; base < N; base += 1024) {
    const int idx = base + tid;
    const int v = (idx < N) ? cur[idx] : 0;
    buf[tid] = v;
    __syncthreads();
    for (int off = 1; off < 1024; off <<= 1) {
      int t = (tid >= off) ? buf[tid - off] : 0;
      __syncthreads();
      buf[tid] += t;
      __syncthreads();
    }
    const int excl = buf[tid] - v;
    const int total = buf[1023];
    if (idx < N) {
      const int o = carry + excl;
      offs[idx] = o;
      cur[idx] = o;
    }
    __syncthreads();
    if (tid == 0) carry += total;
    __syncthreads();
  }
  if (tid == 0) offs[N] = carry;
}

__global__ __launch_bounds__(256) void csr_scatter(
    const int* __restrict__ dst, int E, int* __restrict__ cur, int* __restrict__ sorted)
{
  const int i = blockIdx.x * 256 + threadIdx.x;
  if (i >= E) return;
  const int p = atomicAdd(&cur[dst[i]], 1);
  sorted[p] = i;
}

// -------------------------------------------------------------------------
// Fold per-head w_att/w_msg into K/M projections; emit fused-transposed
// KMT[l,e][512][256] bf16 (rows 0-255 = K-part cols, 256-511 = M-part via
// noff) + bias kmb[l,e][512]. grid (8 row-chunks, 24 leh blocks).
// LDS-staged, vectorized, coalesced output.
// -------------------------------------------------------------------------
__global__ __launch_bounds__(256) void combine_weights(
    const bf16* __restrict__ Wbig, const bf16* __restrict__ bbig,
    const bf16* __restrict__ wsm, bf16* __restrict__ KMT,
    bf16* __restrict__ kmb, int noff)
{
  const int blk = blockIdx.y;
  const int rc  = blockIdx.x;           // 32-row chunk of the 256 K-rows
  const int h = blk & 3;
  const int le = blk >> 2;
  const int e = le % 3;
  const int l = le / 3;
  const int st = (e == 1) ? 0 : 1;      // writes: author src; else paper src

  const short* Wsrc = (const short*)(Wbig + (size_t)(l * 2 + st) * 65536);
  const bf16*  bsrc = bbig + (size_t)(l * 2 + st) * 256;
  const short* wm   = (const short*)(wsm + ((size_t)(l * 3 + e) * 4 + h) * 4096);
  short* outT = (short*)(KMT + (size_t)(l * 3 + e) * 512 * 256);
  bf16* outb  = kmb + (size_t)(l * 3 + e) * 512;

  __shared__ short w[64][72];
  __shared__ short As[32][72];
  __shared__ short ot[64][40];

  const int t = threadIdx.x;
  {
    const int base = t * 16;
    const int r0 = base >> 6, c0 = base & 63;
    *(short8*)&w[r0][c0]     = *(const short8*)&wm[base];
    *(short8*)&w[r0][c0 + 8] = *(const short8*)&wm[base + 8];
  }
  {
    const int row = t >> 3;
    const int kc = (t & 7) * 8;
    *(short8*)&As[row][kc] =
        *(const short8*)&Wsrc[(size_t)(rc * 32 + row) * 256 + h * 64 + kc];
  }
  __syncthreads();

  const int j   = t & 63;
  const int sub = t >> 6;   // 0..3, 8 rows each
  float accv[8] = {};
  #pragma unroll
  for (int d = 0; d < 64; ++d) {
    const float wd = bits2f((unsigned short)w[d][j]);
    #pragma unroll
    for (int r8 = 0; r8 < 8; ++r8)
      accv[r8] += bits2f((unsigned short)As[sub * 8 + r8][d]) * wd;
  }
  #pragma unroll
  for (int r8 = 0; r8 < 8; ++r8) {
    union { bf16 h; short s; } cv;
    cv.h = __float2bfloat16(accv[r8]);
    ot[j][sub * 8 + r8] = cv.s;
  }

  if (rc == 0 && t < 64) {
    float acc = 0.f;
    #pragma unroll
    for (int d = 0; d < 64; ++d)
      acc += toF(bsrc[h * 64 + d]) * bits2f((unsigned short)w[d][t]);
    outb[h * 64 + t + noff] = __float2bfloat16(acc);
  }
  __syncthreads();
  {
    const int nn = t >> 2;
    const int kx = (t & 3) * 8;
    short8 v;
    #pragma unroll
    for (int x = 0; x < 8; ++x) v[x] = ot[nn][kx + x];
    *(short8*)&outT[(size_t)(h * 64 + nn + noff) * 256 + rc * 32 + kx] = v;
  }
}

// -------------------------------------------------------------------------
// MFMA GEMM: C[M, ldc] cols [by*256, by*256+255] = act( A[M,256] @ W + b ).
// WT[n][k] bf16, n indexed globally by by*256+nlocal. Block = 4 waves,
// tile 128(M) x 256(N), BK=64. A dtype runtime-selected via *aflag.
// -------------------------------------------------------------------------
template <typename OT>
__global__ __launch_bounds__(256) void mfma_gemm(
    const void* __restrict__ A, const unsigned* __restrict__ aflag,
    const bf16* __restrict__ WT, const bf16* __restrict__ bias,
    OT* __restrict__ C, int M, int act, int ldc)
{
  __shared__ short As[128][72];
  __shared__ short Bs[256][72];
  const bool abf = (*aflag != 0u);
  const int t = threadIdx.x;
  const int bm = blockIdx.x * 128;
  const int ncoff = blockIdx.y * 256;
  const int lane = t & 63;
  const int wid  = t >> 6;
  const int n0 = wid * 64;
  const int col16 = lane & 15;
  const int quad  = lane >> 4;
  const int rr = t >> 3;        // staging row 0..31
  const int kk = (t & 7) * 8;   // staging k-offset

  float4v acc[8][4];
  #pragma unroll
  for (int mi = 0; mi < 8; ++mi)
    #pragma unroll
    for (int ni = 0; ni < 4; ++ni) acc[mi][ni] = (float4v){0.f, 0.f, 0.f, 0.f};

  for (int k0 = 0; k0 < 256; k0 += 64) {
    #pragma unroll
    for (int it = 0; it < 4; ++it) {
      const int row = it * 32 + rr;
      const int grow = bm + row;
      short8 v = (short8){0, 0, 0, 0, 0, 0, 0, 0};
      if (grow < M) {
        if (abf) {
          v = *(const short8*)((const short*)A + (size_t)grow * 256 + k0 + kk);
        } else {
          const float* ap = (const float*)A + (size_t)grow * 256 + k0 + kk;
          #pragma unroll
          for (int j = 0; j < 8; ++j) {
            union { bf16 h; short s; } cv;
            cv.h = __float2bfloat16(ap[j]);
            v[j] = cv.s;
          }
        }
      }
      *(short8*)&As[row][kk] = v;
    }
    #pragma unroll
    for (int it = 0; it < 8; ++it) {
      const int n = it * 32 + rr;
      *(short8*)&Bs[n][kk] =
          *(const short8*)((const short*)WT + (size_t)(ncoff + n) * 256 + k0 + kk);
    }
    __syncthreads();

    #pragma unroll
    for (int ks = 0; ks < 64; ks += 32) {
      short8 bfr[4];
      #pragma unroll
      for (int ni = 0; ni < 4; ++ni)
        bfr[ni] = *(const short8*)&Bs[n0 + ni * 16 + col16][ks + quad * 8];
      #pragma unroll
      for (int mi = 0; mi < 8; ++mi) {
        const short8 afr = *(const short8*)&As[mi * 16 + col16][ks + quad * 8];
        #pragma unroll
        for (int ni = 0; ni < 4; ++ni)
          acc[mi][ni] = __builtin_amdgcn_mfma_f32_16x16x32_bf16(afr, bfr[ni], acc[mi][ni], 0, 0, 0);
      }
    }
    __syncthreads();
  }

  #pragma unroll
  for (int ni = 0; ni < 4; ++ni) {
    const int col = n0 + ni * 16 + col16;
    const float bc = toF(bias[ncoff + col]);
    #pragma unroll
    for (int mi = 0; mi < 8; ++mi) {
      #pragma unroll
      for (int r = 0; r < 4; ++r) {
        const int row = bm + mi * 16 + quad * 4 + r;
        if (row < M) {
          float v = acc[mi][ni][r] + bc;
          if (act == 1) v = gelu_exact(v);
          storeOut(&C[(size_t)row * ldc + ncoff + col], v);
        }
      }
    }
  }
}

// -------------------------------------------------------------------------
// CSR gather: one wave per dst node. km[src] holds K (cols 0-255) and M
// (cols 256-511) adjacent -> better cache locality. One bf16 write per node.
// -------------------------------------------------------------------------
__global__ __launch_bounds__(256) void gather_kernel(
    const bf16* __restrict__ q, const bf16* __restrict__ km,
    const int* __restrict__ src, const int* __restrict__ sorted, const int* __restrict__ offs,
    const bf16* __restrict__ ew, const bf16* __restrict__ pri,
    bf16* __restrict__ agg, int Nd, int addPrev, float finalScale)
{
  const int lane = threadIdx.x & 63;
  const int wid  = threadIdx.x >> 6;
  const int node = blockIdx.x * 4 + wid;
  if (node >= Nd) return;

  union B4 { uint2 u; unsigned short s[4]; };
  B4 qv;
  qv.u = ((const uint2*)(q + (size_t)node * 256))[lane];
  float qf[4];
  #pragma unroll
  for (int j = 0; j < 4; ++j) qf[j] = bits2f(qv.s[j]);
  const float prih = toF(pri[lane >> 4]);

  float acc[4] = {0.f, 0.f, 0.f, 0.f};
  const int beg = offs[node], end = offs[node + 1];
  for (int idx = beg; idx < end; ++idx) {
    const int e = sorted[idx];
    const int s = src[e];
    const uint2* kmrow = (const uint2*)(km + (size_t)s * 512);
    B4 kb, mb;
    kb.u = kmrow[lane];
    mb.u = kmrow[64 + lane];
    float dot = 0.f;
    #pragma unroll
    for (int j = 0; j < 4; ++j) dot += qf[j] * bits2f(kb.s[j]);
    #pragma unroll
    for (int off = 1; off < 16; off <<= 1) dot += __shfl_xor(dot, off);
    const float a = toF(ew[e]) * sigmoidf_(dot * prih * 0.125f);
    #pragma unroll
    for (int j = 0; j < 4; ++j) acc[j] += bits2f(mb.s[j]) * a;
  }

  if (addPrev) {
    B4 pb;
    pb.u = ((const uint2*)(agg + (size_t)node * 256))[lane];
    #pragma unroll
    for (int j = 0; j < 4; ++j) acc[j] += bits2f(pb.s[j]);
  }
  bf16* out = agg + (size_t)node * 256 + lane * 4;
  #pragma unroll
  for (int j = 0; j < 4; ++j) out[j] = __float2bfloat16(acc[j] * finalScale);
}

// -------------------------------------------------------------------------
// o = tr*alpha + feat*(1-alpha); feat = bf16(LN(o)*g + b). One wave per node.
// -------------------------------------------------------------------------
__global__ __launch_bounds__(256) void skip_ln(
    const float* __restrict__ tr, bf16* __restrict__ feat,
    const bf16* __restrict__ skipv, const bf16* __restrict__ g,
    const bf16* __restrict__ b, int N)
{
  const int lane = threadIdx.x & 63;
  const int wid  = threadIdx.x >> 6;
  const int node = blockIdx.x * 4 + wid;
  if (node >= N) return;
  const float alpha = sigmoidf_(toF(*skipv));
  const float4 t = ((const float4*)(tr + (size_t)node * 256))[lane];
  union B4 { uint2 u; unsigned short s[4]; };
  B4 fb;
  fb.u = ((const uint2*)(feat + (size_t)node * 256))[lane];
  float o[4];
  o[0] = t.x * alpha + bits2f(fb.s[0]) * (1.f - alpha);
  o[1] = t.y * alpha + bits2f(fb.s[1]) * (1.f - alpha);
  o[2] = t.z * alpha + bits2f(fb.s[2]) * (1.f - alpha);
  o[3] = t.w * alpha + bits2f(fb.s[3]) * (1.f - alpha);

  float sum = o[0] + o[1] + o[2] + o[3];
  #pragma unroll
  for (int off = 32; off; off >>= 1) sum += __shfl_xor(sum, off);
  const float mu = sum * (1.f / 256.f);

  float dd[4], sq = 0.f;
  #pragma unroll
  for (int j = 0; j < 4; ++j) { dd[j] = o[j] - mu; sq += dd[j] * dd[j]; }
  #pragma unroll
  for (int off = 32; off; off >>= 1) sq += __shfl_xor(sq, off);
  const float rs = rsqrtf(sq * (1.f / 256.f) + 1e-5f);

  bf16* fout = feat + (size_t)node * 256 + lane * 4;
  #pragma unroll
  for (int j = 0; j < 4; ++j) {
    float r = dd[j] * rs * toF(g[lane * 4 + j]) + toF(b[lane * 4 + j]);
    fout[j] = __float2bfloat16(r);
  }
}

// -------------------------------------------------------------------------
// out[M,64] = A[M,256] @ W[256,64] + b[64]; output dtype per *flag.
// -------------------------------------------------------------------------
__global__ __launch_bounds__(256) void out_gemm(
    const bf16* __restrict__ A, const bf16* __restrict__ W,
    const bf16* __restrict__ bias, void* __restrict__ out,
    const unsigned* __restrict__ flag, int M)
{
  __shared__ float Ws[64][64];
  const bool obf = (*flag != 0u);
  const int tid = threadIdx.x;
  const int row = blockIdx.x * 64 + (tid >> 2);
  const int c0 = (tid & 3) * 16;
  const int arow = (row < M) ? row : 0;
  const bf16* a = A + (size_t)arow * 256;
  float acc[16] = {};
  for (int k0 = 0; k0 < 256; k0 += 64) {
    for (int i = tid; i < 4096; i += 256)
      Ws[i >> 6][i & 63] = toF(W[(size_t)(k0 + (i >> 6)) * 64 + (i & 63)]);
    __syncthreads();
    for (int k = 0; k < 64; ++k) {
      const float av = toF(a[k0 + k]);
      #pragma unroll
      for (int j = 0; j < 16; ++j) acc[j] += av * Ws[k][c0 + j];
    }
    __syncthreads();
  }
  if (row < M) {
    #pragma unroll
    for (int j = 0; j < 16; ++j) {
      const float v = acc[j] + toF(bias[c0 + j]);
      const size_t idx = (size_t)row * 64 + c0 + j;
      if (obf) ((bf16*)out)[idx] = __float2bfloat16(v);
      else     ((float*)out)[idx] = v;
    }
  }
}

// -------------------------------------------------------------------------
extern "C" void kernel_launch(void* const* d_in, const int* in_sizes, int n_in,
                              void* d_out, int out_size, void* d_ws, size_t ws_size,
                              hipStream_t stream) {
  const int* src_wb  = (const int*)d_in[23];
  const int* dst_wb  = (const int*)d_in[24];
  const int* src_w   = (const int*)d_in[25];
  const int* dst_w   = (const int*)d_in[26];
  const int* src_c   = (const int*)d_in[27];
  const int* dst_c   = (const int*)d_in[28];

  // ---- workspace carve (~144 MB total) ----
  char* base = (char*)d_ws;
  unsigned* flags = (unsigned*)base;                       // 256 B
  bf16* canon = (bf16*)(base + 256);
  char* p = base + 256 + (((size_t)kCanonTotal * 2 + 511) & ~(size_t)511);
  bf16* adWT = (bf16*)p;                     // 2 x 65536
  bf16* qWT  = adWT + (size_t)2 * 65536;     // 4 x 65536
  bf16* aWT  = qWT  + (size_t)4 * 65536;     // 4 x 65536
  bf16* KMeffT = aWT + (size_t)4 * 65536;    // 6 x 512*256 (K rows 0-255, M rows 256-511)
  bf16* kmbeT  = KMeffT + (size_t)6 * 512 * 256;  // 6 x 512
  char* pc = (char*)(((size_t)(kmbeT + 6 * 512) + 511) & ~(size_t)511);
  // CSR region
  int* cur_wb  = (int*)pc;
  int* cur_w   = cur_wb + (kNA + 1);
  int* cur_c   = cur_w + (kNP + 1);
  int* offs_wb = cur_c + (kNP + 1);
  int* offs_w  = offs_wb + (kNA + 1);
  int* offs_c  = offs_w + (kNP + 1);
  int* sort_wb = offs_c + (kNP + 1);
  int* sort_w  = sort_wb + kEWB;
  int* sort_c  = sort_w + kEW;
  char* p2 = (char*)(((size_t)(sort_c + kEC) + 511) & ~(size_t)511);
  bf16* fa  = (bf16*)p2;                  // [NA,256]
  bf16* fp_ = fa + (size_t)kNA * 256;     // [NP,256]
  char* R   = (char*)(fp_ + (size_t)kNP * 256);
  bf16* qa = (bf16*)R;                    // [NA,256]
  bf16* qp = qa + (size_t)kNA * 256;      // [NP,256]
  bf16* km = qp + (size_t)kNP * 256;      // [NP,512] fused K|M (reused per relation)
  float* tr_a = (float*)R;                // fp32 view of R, disjoint lifetime
  float* tr_p = tr_a + (size_t)kNA * 256;
  char* afterR = R + (size_t)(kNA + 3 * kNP) * 256 * sizeof(bf16);
  bf16* agg_a = (bf16*)afterR;            // [NA,256]
  bf16* agg_p = agg_a + (size_t)kNA * 256;// [NP,256]

  const bf16* c_ew_wb = canon + kOff(0);
  const bf16* c_ew_w  = canon + kOff(1);
  const bf16* c_ew_c  = canon + kOff(2);
  const bf16* c_adW   = canon + kOff(3);
  const bf16* c_adb   = canon + kOff(4);
  const bf16* c_kW    = canon + kOff(5);
  const bf16* c_kb    = canon + kOff(6);
  const bf16* c_qW    = canon + kOff(7);
  const bf16* c_qb    = canon + kOff(8);
  const bf16* c_mW    = canon + kOff(9);
  const bf16* c_mb    = canon + kOff(10);
  const bf16* c_aW    = canon + kOff(11);
  const bf16* c_ab    = canon + kOff(12);
  const bf16* c_wpri  = canon + kOff(13);
  const bf16* c_watt  = canon + kOff(14);
  const bf16* c_wmsg  = canon + kOff(15);
  const bf16* c_skip  = canon + kOff(16);
  const bf16* c_lng   = canon + kOff(17);
  const bf16* c_lnb   = canon + kOff(18);
  const bf16* c_outW  = canon + kOff(19);
  const bf16* c_outb  = canon + kOff(20);

  const unsigned* fIn = flags + 0;
  const unsigned* f1  = flags + 1;

  detect_dtype<<<1, 256, 0, stream>>>((const unsigned*)d_in[0], flags);

  CanonArgs ca;
  for (int s = 0; s < kNSeg; ++s) { ca.n[s] = kSegN[s]; ca.dstOff[s] = (unsigned)kOff(s); }
  const int srcIdx[kNSeg] = {2,3,4, 5,6, 7,8, 9,10, 11,12, 13,14, 15, 16,17, 18,19,20, 21,22};
  for (int s = 0; s < kNSeg; ++s) ca.src[s] = d_in[srcIdx[s]];
  canon_kernel<<<dim3(1172, kNSeg), 256, 0, stream>>>(ca, canon, flags);

  // ---- transpose the 10 dense 256x256 weights into [n][k] layout ----
  TransArgs ta;
  ta.src[0] = c_adW;              ta.dst[0] = adWT;
  ta.src[1] = c_adW + 65536;      ta.dst[1] = adWT + 65536;
  for (int m = 0; m < 4; ++m) { ta.src[2 + m] = c_qW + (size_t)m * 65536; ta.dst[2 + m] = qWT + (size_t)m * 65536; }
  for (int m = 0; m < 4; ++m) { ta.src[6 + m] = c_aW + (size_t)m * 65536; ta.dst[6 + m] = aWT + (size_t)m * 65536; }
  transpose_w<<<dim3(4, 4, 10), 256, 0, stream>>>(ta);

  // ---- CSR build (edges static: once per launch) ----
  hipMemsetAsync(cur_wb, 0, (size_t)((kNA + 1) + 2 * (kNP + 1)) * 4, stream);
  csr_hist<<<(kEWB + 255) / 256, 256, 0, stream>>>(dst_wb, kEWB, cur_wb);
  csr_hist<<<(kEW  + 255) / 256, 256, 0, stream>>>(dst_w,  kEW,  cur_w);
  csr_hist<<<(kEC  + 255) / 256, 256, 0, stream>>>(dst_c,  kEC,  cur_c);
  csr_scan<<<1, 1024, 0, stream>>>(cur_wb, offs_wb, kNA);
  csr_scan<<<1, 1024, 0, stream>>>(cur_w,  offs_w,  kNP);
  csr_scan<<<1, 1024, 0, stream>>>(cur_c,  offs_c,  kNP);
  csr_scatter<<<(kEWB + 255) / 256, 256, 0, stream>>>(dst_wb, kEWB, cur_wb, sort_wb);
  csr_scatter<<<(kEW  + 255) / 256, 256, 0, stream>>>(dst_w,  kEW,  cur_w,  sort_w);
  csr_scatter<<<(kEC  + 255) / 256, 256, 0, stream>>>(dst_c,  kEC,  cur_c,  sort_c);

  // fused K|M effective weights (K: noff=0, M: noff=256)
  combine_weights<<<dim3(8, 24), 256, 0, stream>>>(c_kW, c_kb, c_watt, KMeffT, kmbeT, 0);
  combine_weights<<<dim3(8, 24), 256, 0, stream>>>(c_mW, c_mb, c_wmsg, KMeffT, kmbeT, 256);

  auto gM = [](int m) { return dim3((unsigned)((m + 127) / 128)); };
  auto gM2 = [](int m) { return dim3((unsigned)((m + 127) / 128), 2); };

  // adapt: feats = gelu(x @ adapt_W + adapt_b); x read dual-dtype
  mfma_gemm<bf16><<<gM(kNA), 256, 0, stream>>>(d_in[0], fIn, adWT,         c_adb,       fa,  kNA, 1, 256);
  mfma_gemm<bf16><<<gM(kNP), 256, 0, stream>>>(d_in[1], fIn, adWT + 65536, c_adb + 256, fp_, kNP, 1, 256);

  for (int l = 0; l < 2; ++l) {
    mfma_gemm<bf16><<<gM(kNA), 256, 0, stream>>>(
        fa,  f1, qWT + (size_t)(l * 2 + 0) * 65536, c_qb + (l * 2 + 0) * 256, qa, kNA, 0, 256);
    mfma_gemm<bf16><<<gM(kNP), 256, 0, stream>>>(
        fp_, f1, qWT + (size_t)(l * 2 + 1) * 65536, c_qb + (l * 2 + 1) * 256, qp, kNP, 0, 256);

    // WRITTEN_BY (e=2): paper -> author
    mfma_gemm<bf16><<<gM2(kNP), 256, 0, stream>>>(
        fp_, f1, KMeffT + (size_t)(l * 3 + 2) * 512 * 256, kmbeT + (l * 3 + 2) * 512, km, kNP, 0, 512);
    gather_kernel<<<(kNA + 3) / 4, 256, 0, stream>>>(
        qa, km, src_wb, sort_wb, offs_wb, c_ew_wb, c_wpri + (l * 3 + 2) * 4,
        agg_a, kNA, 0, 1.f);

    // WRITES (e=1): author -> paper
    mfma_gemm<bf16><<<gM2(kNA), 256, 0, stream>>>(
        fa, f1, KMeffT + (size_t)(l * 3 + 1) * 512 * 256, kmbeT + (l * 3 + 1) * 512, km, kNA, 0, 512);
    gather_kernel<<<(kNP + 3) / 4, 256, 0, stream>>>(
        qp, km, src_w, sort_w, offs_w, c_ew_w, c_wpri + (l * 3 + 1) * 4,
        agg_p, kNP, 0, 1.f);

    // CITES (e=0): paper -> paper, chained add + 0.5 mean
    mfma_gemm<bf16><<<gM2(kNP), 256, 0, stream>>>(
        fp_, f1, KMeffT + (size_t)(l * 3 + 0) * 512 * 256, kmbeT + (l * 3 + 0) * 512, km, kNP, 0, 512);
    gather_kernel<<<(kNP + 3) / 4, 256, 0, stream>>>(
        qp, km, src_c, sort_c, offs_c, c_ew_c, c_wpri + (l * 3 + 0) * 4,
        agg_p, kNP, 1, 0.5f);

    // A-projection of aggregates
    mfma_gemm<float><<<gM(kNA), 256, 0, stream>>>(
        agg_a, f1, aWT + (size_t)(l * 2 + 0) * 65536, c_ab + (l * 2 + 0) * 256, tr_a, kNA, 0, 256);
    mfma_gemm<float><<<gM(kNP), 256, 0, stream>>>(
        agg_p, f1, aWT + (size_t)(l * 2 + 1) * 65536, c_ab + (l * 2 + 1) * 256, tr_p, kNP, 0, 256);

    skip_ln<<<kNA / 4, 256, 0, stream>>>(
        tr_a, fa,  c_skip + l * 3 + 0, c_lng + (l * 2 + 0) * 256, c_lnb + (l * 2 + 0) * 256, kNA);
    skip_ln<<<kNP / 4, 256, 0, stream>>>(
        tr_p, fp_, c_skip + l * 3 + 1, c_lng + (l * 2 + 1) * 256, c_lnb + (l * 2 + 1) * 256, kNP);
  }

  out_gemm<<<kNP / 64, 256, 0, stream>>>(fp_, c_outW, c_outb, d_out, fIn, kNP);
}

// Round 7
// 1189.685 us; speedup vs baseline: 5.5123x; 1.3605x over previous
//
#include <hip/hip_runtime.h>
#include <hip/hip_bf16.h>
#include <math.h>

using bf16 = __hip_bfloat16;

typedef __attribute__((ext_vector_type(8))) short short8;   // 8 bf16 (4 VGPRs)
typedef __attribute__((ext_vector_type(4))) float float4v;  // MFMA acc

static constexpr int kNA  = 20000;
static constexpr int kNP  = 40000;
static constexpr int kEWB = 150000;
static constexpr int kEW  = 150000;
static constexpr int kEC  = 300000;

// ---- canonical bf16 input region ----
static constexpr int kNSeg = 21;
static constexpr int kSegN[kNSeg] = {
  150000, 150000, 300000,           // ew_wb, ew_w, ew_c
  131072, 512,                      // adW, adb
  262144, 1024,                     // kW, kb
  262144, 1024,                     // qW, qb
  262144, 1024,                     // mW, mb
  262144, 1024,                     // aW, ab
  24,                               // wpri
  98304, 98304,                     // watt, wmsg
  6, 1024, 1024,                    // skip, lng, lnb
  16384, 64                         // outW, outb
};
static constexpr size_t kOff(int s) {
  size_t o = 0;
  for (int i = 0; i < s; ++i) o += (size_t)kSegN[i];
  return o;
}
static constexpr size_t kCanonTotal = kOff(kNSeg);

struct CanonArgs {
  const void* src[kNSeg];
  int n[kNSeg];
  unsigned dstOff[kNSeg];
};
struct TransArgs {
  const bf16* src[10];
  bf16* dst[10];
};
// per-blockIdx.y GEMM output descriptor (slab = 128 output cols)
struct GemmDesc {
  const short* wt;   // [128][256] n-major slab
  const bf16* bias;  // 128 entries (slab-local)
  void* c;           // output base
  int ldc;           // in elements
  int coff;          // global col offset of this slab in C
  int act;           // 1 = gelu
  int otype;         // 0 = bf16, 1 = fp32
  int pad;
};
struct MultiDesc { GemmDesc d[6]; };

__device__ __forceinline__ float toF(float x) { return x; }
__device__ __forceinline__ float toF(bf16 x)  { return __bfloat162float(x); }
__device__ __forceinline__ float bits2f(unsigned short b) {
  unsigned int u = ((unsigned int)b) << 16;
  return __uint_as_float(u);
}
__device__ __forceinline__ float sigmoidf_(float x) { return 1.0f / (1.0f + expf(-x)); }
__device__ __forceinline__ float gelu_exact(float x) {
  return 0.5f * x * (1.0f + erff(x * 0.70710678118654752f));
}

// -------------------------------------------------------------------------
// Input-dtype sniffer. flags: [0]=isBf16 [1]=1
// -------------------------------------------------------------------------
__global__ __launch_bounds__(256) void detect_dtype(
    const unsigned* __restrict__ x, unsigned* __restrict__ flags)
{
  __shared__ int cnt;
  if (threadIdx.x == 0) cnt = 0;
  __syncthreads();
  unsigned w = x[threadIdx.x];
  unsigned e = (w >> 7) & 0xFFu;
  if (e >= 110u && e <= 140u) atomicAdd(&cnt, 1);
  __syncthreads();
  if (threadIdx.x == 0) {
    flags[0] = (cnt >= 128) ? 1u : 0u;
    flags[1] = 1u;
  }
}

__global__ __launch_bounds__(256) void canon_kernel(
    CanonArgs a, bf16* __restrict__ dst, const unsigned* __restrict__ flags)
{
  const int s = blockIdx.y;
  const int i = blockIdx.x * 256 + threadIdx.x;
  if (i >= a.n[s]) return;
  bf16 v;
  if (flags[0]) v = ((const bf16*)a.src[s])[i];
  else          v = __float2bfloat16(((const float*)a.src[s])[i]);
  dst[a.dstOff[s] + i] = v;
}

// -------------------------------------------------------------------------
// Batched 256x256 weight transpose: dst[n][k] = src[k][n]. grid (4,4,10).
// -------------------------------------------------------------------------
__global__ __launch_bounds__(256) void transpose_w(TransArgs ta)
{
  const int m = blockIdx.z;
  const short* src = (const short*)ta.src[m];
  short* dst = (short*)ta.dst[m];
  const int k0 = blockIdx.x * 64, n0 = blockIdx.y * 64;
  __shared__ short tile[64][65];
  const int tx = threadIdx.x & 63, ty = threadIdx.x >> 6;
  for (int i = ty; i < 64; i += 4)
    tile[i][tx] = src[(size_t)(k0 + i) * 256 + n0 + tx];
  __syncthreads();
  for (int i = ty; i < 64; i += 4)
    dst[(size_t)(n0 + i) * 256 + k0 + tx] = tile[tx][i];
}

// -------------------------------------------------------------------------
// CSR build: histogram -> exclusive scan (single block) -> scatter.
// -------------------------------------------------------------------------
__global__ __launch_bounds__(256) void csr_hist(
    const int* __restrict__ dst, int E, int* __restrict__ cnt)
{
  const int i = blockIdx.x * 256 + threadIdx.x;
  if (i < E) atomicAdd(&cnt[dst[i]], 1);
}

__global__ __launch_bounds__(1024) void csr_scan(
    int* __restrict__ cur, int* __restrict__ offs, int N)
{
  __shared__ int buf[1024];
  __shared__ int carry;
  const int tid = threadIdx.x;
  if (tid == 0) carry = 0;
  __syncthreads();
  for (int base = 0; base < N; base += 1024) {
    const int idx = base + tid;
    const int v = (idx < N) ? cur[idx] : 0;
    buf[tid] = v;
    __syncthreads();
    for (int off = 1; off < 1024; off <<= 1) {
      int t = (tid >= off) ? buf[tid - off] : 0;
      __syncthreads();
      buf[tid] += t;
      __syncthreads();
    }
    const int excl = buf[tid] - v;
    const int total = buf[1023];
    if (idx < N) {
      const int o = carry + excl;
      offs[idx] = o;
      cur[idx] = o;
    }
    __syncthreads();
    if (tid == 0) carry += total;
    __syncthreads();
  }
  if (tid == 0) offs[N] = carry;
}

__global__ __launch_bounds__(256) void csr_scatter(
    const int* __restrict__ dst, int E, int* __restrict__ cur, int* __restrict__ sorted)
{
  const int i = blockIdx.x * 256 + threadIdx.x;
  if (i >= E) return;
  const int p = atomicAdd(&cur[dst[i]], 1);
  sorted[p] = i;
}

// -------------------------------------------------------------------------
// Fold per-head w_att/w_msg into K/M projections; emit fused-transposed
// KMT[l,e][512][256] bf16 + bias kmb[l,e][512]. grid (8, 24).
// -------------------------------------------------------------------------
__global__ __launch_bounds__(256) void combine_weights(
    const bf16* __restrict__ Wbig, const bf16* __restrict__ bbig,
    const bf16* __restrict__ wsm, bf16* __restrict__ KMT,
    bf16* __restrict__ kmb, int noff)
{
  const int blk = blockIdx.y;
  const int rc  = blockIdx.x;           // 32-row chunk of the 256 K-rows
  const int h = blk & 3;
  const int le = blk >> 2;
  const int e = le % 3;
  const int l = le / 3;
  const int st = (e == 1) ? 0 : 1;      // writes: author src; else paper src

  const short* Wsrc = (const short*)(Wbig + (size_t)(l * 2 + st) * 65536);
  const bf16*  bsrc = bbig + (size_t)(l * 2 + st) * 256;
  const short* wm   = (const short*)(wsm + ((size_t)(l * 3 + e) * 4 + h) * 4096);
  short* outT = (short*)(KMT + (size_t)(l * 3 + e) * 512 * 256);
  bf16* outb  = kmb + (size_t)(l * 3 + e) * 512;

  __shared__ short w[64][72];
  __shared__ short As[32][72];
  __shared__ short ot[64][40];

  const int t = threadIdx.x;
  {
    const int base = t * 16;
    const int r0 = base >> 6, c0 = base & 63;
    *(short8*)&w[r0][c0]     = *(const short8*)&wm[base];
    *(short8*)&w[r0][c0 + 8] = *(const short8*)&wm[base + 8];
  }
  {
    const int row = t >> 3;
    const int kc = (t & 7) * 8;
    *(short8*)&As[row][kc] =
        *(const short8*)&Wsrc[(size_t)(rc * 32 + row) * 256 + h * 64 + kc];
  }
  __syncthreads();

  const int j   = t & 63;
  const int sub = t >> 6;   // 0..3, 8 rows each
  float accv[8] = {};
  #pragma unroll
  for (int d = 0; d < 64; ++d) {
    const float wd = bits2f((unsigned short)w[d][j]);
    #pragma unroll
    for (int r8 = 0; r8 < 8; ++r8)
      accv[r8] += bits2f((unsigned short)As[sub * 8 + r8][d]) * wd;
  }
  #pragma unroll
  for (int r8 = 0; r8 < 8; ++r8) {
    union { bf16 h; short s; } cv;
    cv.h = __float2bfloat16(accv[r8]);
    ot[j][sub * 8 + r8] = cv.s;
  }

  if (rc == 0 && t < 64) {
    float acc = 0.f;
    #pragma unroll
    for (int d = 0; d < 64; ++d)
      acc += toF(bsrc[h * 64 + d]) * bits2f((unsigned short)w[d][t]);
    outb[h * 64 + t + noff] = __float2bfloat16(acc);
  }
  __syncthreads();
  {
    const int nn = t >> 2;
    const int kx = (t & 3) * 8;
    short8 v;
    #pragma unroll
    for (int x = 0; x < 8; ++x) v[x] = ot[nn][kx + x];
    *(short8*)&outT[(size_t)(h * 64 + nn + noff) * 256 + rc * 32 + kx] = v;
  }
}

// -------------------------------------------------------------------------
// Multi-output MFMA GEMM. Tile 128(M) x 128(N), BK=64, 4 waves in 2x2.
// blockIdx.y selects a GemmDesc (weight slab + output target). LDS 36.9 KB
// -> 4 blocks/CU; __launch_bounds__(256,4) caps VGPR for 16 waves/CU.
// -------------------------------------------------------------------------
__global__ __launch_bounds__(256, 4) void mfma_gemm128(
    const void* __restrict__ A, const unsigned* __restrict__ aflag,
    MultiDesc md, int M)
{
  __shared__ short As[128][72];
  __shared__ short Bs[128][72];
  const GemmDesc d = md.d[blockIdx.y];
  const bool abf = (*aflag != 0u);
  const int t = threadIdx.x;
  const int bm = blockIdx.x * 128;
  const int lane = t & 63;
  const int wid  = t >> 6;
  const int wm = (wid >> 1) * 64;
  const int wn = (wid & 1) * 64;
  const int col16 = lane & 15;
  const int quad  = lane >> 4;
  const int rr = t >> 3;        // staging row 0..31
  const int kk = (t & 7) * 8;   // staging k-offset

  float4v acc[4][4];
  #pragma unroll
  for (int mi = 0; mi < 4; ++mi)
    #pragma unroll
    for (int ni = 0; ni < 4; ++ni) acc[mi][ni] = (float4v){0.f, 0.f, 0.f, 0.f};

  for (int k0 = 0; k0 < 256; k0 += 64) {
    #pragma unroll
    for (int it = 0; it < 4; ++it) {
      const int row = it * 32 + rr;
      const int grow = bm + row;
      short8 v = (short8){0, 0, 0, 0, 0, 0, 0, 0};
      if (grow < M) {
        if (abf) {
          v = *(const short8*)((const short*)A + (size_t)grow * 256 + k0 + kk);
        } else {
          const float* ap = (const float*)A + (size_t)grow * 256 + k0 + kk;
          #pragma unroll
          for (int j = 0; j < 8; ++j) {
            union { bf16 h; short s; } cv;
            cv.h = __float2bfloat16(ap[j]);
            v[j] = cv.s;
          }
        }
      }
      *(short8*)&As[row][kk] = v;
    }
    #pragma unroll
    for (int it = 0; it < 4; ++it) {
      const int n = it * 32 + rr;
      *(short8*)&Bs[n][kk] = *(const short8*)&d.wt[(size_t)n * 256 + k0 + kk];
    }
    __syncthreads();

    #pragma unroll
    for (int ks = 0; ks < 64; ks += 32) {
      short8 bfr[4];
      #pragma unroll
      for (int ni = 0; ni < 4; ++ni)
        bfr[ni] = *(const short8*)&Bs[wn + ni * 16 + col16][ks + quad * 8];
      #pragma unroll
      for (int mi = 0; mi < 4; ++mi) {
        const short8 afr = *(const short8*)&As[wm + mi * 16 + col16][ks + quad * 8];
        #pragma unroll
        for (int ni = 0; ni < 4; ++ni)
          acc[mi][ni] = __builtin_amdgcn_mfma_f32_16x16x32_bf16(afr, bfr[ni], acc[mi][ni], 0, 0, 0);
      }
    }
    __syncthreads();
  }

  #pragma unroll
  for (int ni = 0; ni < 4; ++ni) {
    const int col = wn + ni * 16 + col16;        // 0..127 slab-local
    const float bc = toF(d.bias[col]);
    const int gcol = d.coff + col;
    #pragma unroll
    for (int mi = 0; mi < 4; ++mi) {
      #pragma unroll
      for (int r = 0; r < 4; ++r) {
        const int row = bm + wm + mi * 16 + quad * 4 + r;
        if (row < M) {
          float v = acc[mi][ni][r] + bc;
          if (d.act == 1) v = gelu_exact(v);
          const size_t idx = (size_t)row * d.ldc + gcol;
          if (d.otype == 0) ((bf16*)d.c)[idx] = __float2bfloat16(v);
          else              ((float*)d.c)[idx] = v;
        }
      }
    }
  }
}

// -------------------------------------------------------------------------
// CSR gather: one wave per dst node; km[src] holds K (0-255) | M (256-511).
// -------------------------------------------------------------------------
__global__ __launch_bounds__(256) void gather_kernel(
    const bf16* __restrict__ q, const bf16* __restrict__ km,
    const int* __restrict__ src, const int* __restrict__ sorted, const int* __restrict__ offs,
    const bf16* __restrict__ ew, const bf16* __restrict__ pri,
    bf16* __restrict__ agg, int Nd, int addPrev, float finalScale)
{
  const int lane = threadIdx.x & 63;
  const int wid  = threadIdx.x >> 6;
  const int node = blockIdx.x * 4 + wid;
  if (node >= Nd) return;

  union B4 { uint2 u; unsigned short s[4]; };
  B4 qv;
  qv.u = ((const uint2*)(q + (size_t)node * 256))[lane];
  float qf[4];
  #pragma unroll
  for (int j = 0; j < 4; ++j) qf[j] = bits2f(qv.s[j]);
  const float prih = toF(pri[lane >> 4]);

  float acc[4] = {0.f, 0.f, 0.f, 0.f};
  const int beg = offs[node], end = offs[node + 1];
  for (int idx = beg; idx < end; ++idx) {
    const int e = sorted[idx];
    const int s = src[e];
    const uint2* kmrow = (const uint2*)(km + (size_t)s * 512);
    B4 kb, mb;
    kb.u = kmrow[lane];
    mb.u = kmrow[64 + lane];
    float dot = 0.f;
    #pragma unroll
    for (int j = 0; j < 4; ++j) dot += qf[j] * bits2f(kb.s[j]);
    #pragma unroll
    for (int off = 1; off < 16; off <<= 1) dot += __shfl_xor(dot, off);
    const float a = toF(ew[e]) * sigmoidf_(dot * prih * 0.125f);
    #pragma unroll
    for (int j = 0; j < 4; ++j) acc[j] += bits2f(mb.s[j]) * a;
  }

  if (addPrev) {
    B4 pb;
    pb.u = ((const uint2*)(agg + (size_t)node * 256))[lane];
    #pragma unroll
    for (int j = 0; j < 4; ++j) acc[j] += bits2f(pb.s[j]);
  }
  bf16* out = agg + (size_t)node * 256 + lane * 4;
  #pragma unroll
  for (int j = 0; j < 4; ++j) out[j] = __float2bfloat16(acc[j] * finalScale);
}

// -------------------------------------------------------------------------
// o = tr*alpha + feat*(1-alpha); feat = bf16(LN(o)*g + b). One wave per node.
// -------------------------------------------------------------------------
__global__ __launch_bounds__(256) void skip_ln(
    const float* __restrict__ tr, bf16* __restrict__ feat,
    const bf16* __restrict__ skipv, const bf16* __restrict__ g,
    const bf16* __restrict__ b, int N)
{
  const int lane = threadIdx.x & 63;
  const int wid  = threadIdx.x >> 6;
  const int node = blockIdx.x * 4 + wid;
  if (node >= N) return;
  const float alpha = sigmoidf_(toF(*skipv));
  const float4 t = ((const float4*)(tr + (size_t)node * 256))[lane];
  union B4 { uint2 u; unsigned short s[4]; };
  B4 fb;
  fb.u = ((const uint2*)(feat + (size_t)node * 256))[lane];
  float o[4];
  o[0] = t.x * alpha + bits2f(fb.s[0]) * (1.f - alpha);
  o[1] = t.y * alpha + bits2f(fb.s[1]) * (1.f - alpha);
  o[2] = t.z * alpha + bits2f(fb.s[2]) * (1.f - alpha);
  o[3] = t.w * alpha + bits2f(fb.s[3]) * (1.f - alpha);

  float sum = o[0] + o[1] + o[2] + o[3];
  #pragma unroll
  for (int off = 32; off; off >>= 1) sum += __shfl_xor(sum, off);
  const float mu = sum * (1.f / 256.f);

  float dd[4], sq = 0.f;
  #pragma unroll
  for (int j = 0; j < 4; ++j) { dd[j] = o[j] - mu; sq += dd[j] * dd[j]; }
  #pragma unroll
  for (int off = 32; off; off >>= 1) sq += __shfl_xor(sq, off);
  const float rs = rsqrtf(sq * (1.f / 256.f) + 1e-5f);

  bf16* fout = feat + (size_t)node * 256 + lane * 4;
  #pragma unroll
  for (int j = 0; j < 4; ++j) {
    float r = dd[j] * rs * toF(g[lane * 4 + j]) + toF(b[lane * 4 + j]);
    fout[j] = __float2bfloat16(r);
  }
}

// -------------------------------------------------------------------------
// out[M,64] = A[M,256] @ W[256,64] + b[64]; output dtype per *flag.
// -------------------------------------------------------------------------
__global__ __launch_bounds__(256) void out_gemm(
    const bf16* __restrict__ A, const bf16* __restrict__ W,
    const bf16* __restrict__ bias, void* __restrict__ out,
    const unsigned* __restrict__ flag, int M)
{
  __shared__ float Ws[64][64];
  const bool obf = (*flag != 0u);
  const int tid = threadIdx.x;
  const int row = blockIdx.x * 64 + (tid >> 2);
  const int c0 = (tid & 3) * 16;
  const int arow = (row < M) ? row : 0;
  const bf16* a = A + (size_t)arow * 256;
  float acc[16] = {};
  for (int k0 = 0; k0 < 256; k0 += 64) {
    for (int i = tid; i < 4096; i += 256)
      Ws[i >> 6][i & 63] = toF(W[(size_t)(k0 + (i >> 6)) * 64 + (i & 63)]);
    __syncthreads();
    for (int k = 0; k < 64; ++k) {
      const float av = toF(a[k0 + k]);
      #pragma unroll
      for (int j = 0; j < 16; ++j) acc[j] += av * Ws[k][c0 + j];
    }
    __syncthreads();
  }
  if (row < M) {
    #pragma unroll
    for (int j = 0; j < 16; ++j) {
      const float v = acc[j] + toF(bias[c0 + j]);
      const size_t idx = (size_t)row * 64 + c0 + j;
      if (obf) ((bf16*)out)[idx] = __float2bfloat16(v);
      else     ((float*)out)[idx] = v;
    }
  }
}

// -------------------------------------------------------------------------
extern "C" void kernel_launch(void* const* d_in, const int* in_sizes, int n_in,
                              void* d_out, int out_size, void* d_ws, size_t ws_size,
                              hipStream_t stream) {
  const int* src_wb  = (const int*)d_in[23];
  const int* dst_wb  = (const int*)d_in[24];
  const int* src_w   = (const int*)d_in[25];
  const int* dst_w   = (const int*)d_in[26];
  const int* src_c   = (const int*)d_in[27];
  const int* dst_c   = (const int*)d_in[28];

  // ---- workspace carve (~164 MB total) ----
  char* base = (char*)d_ws;
  unsigned* flags = (unsigned*)base;                       // 256 B
  bf16* canon = (bf16*)(base + 256);
  char* p = base + 256 + (((size_t)kCanonTotal * 2 + 511) & ~(size_t)511);
  bf16* adWT = (bf16*)p;                     // 2 x 65536
  bf16* qWT  = adWT + (size_t)2 * 65536;     // 4 x 65536
  bf16* aWT  = qWT  + (size_t)4 * 65536;     // 4 x 65536
  bf16* KMeffT = aWT + (size_t)4 * 65536;    // 6 x 512*256
  bf16* kmbeT  = KMeffT + (size_t)6 * 512 * 256;  // 6 x 512
  char* pc = (char*)(((size_t)(kmbeT + 6 * 512) + 511) & ~(size_t)511);
  // CSR region
  int* cur_wb  = (int*)pc;
  int* cur_w   = cur_wb + (kNA + 1);
  int* cur_c   = cur_w + (kNP + 1);
  int* offs_wb = cur_c + (kNP + 1);
  int* offs_w  = offs_wb + (kNA + 1);
  int* offs_c  = offs_w + (kNP + 1);
  int* sort_wb = offs_c + (kNP + 1);
  int* sort_w  = sort_wb + kEWB;
  int* sort_c  = sort_w + kEW;
  char* p2 = (char*)(((size_t)(sort_c + kEC) + 511) & ~(size_t)511);
  bf16* fa  = (bf16*)p2;                  // [NA,256]
  bf16* fp_ = fa + (size_t)kNA * 256;     // [NP,256]
  char* R   = (char*)(fp_ + (size_t)kNP * 256);
  bf16* qa   = (bf16*)R;                  // [NA,256]
  bf16* qp   = qa + (size_t)kNA * 256;    // [NP,256]
  bf16* km_a = qp + (size_t)kNP * 256;    // [NA,512] authors KM (writes rel)
  bf16* km_p = km_a + (size_t)kNA * 512;  // [NP,512] papers KM (wb, then cites)
  float* tr_a = (float*)R;                // fp32 view of R, disjoint lifetime
  float* tr_p = tr_a + (size_t)kNA * 256;
  char* afterR = R + ((size_t)(kNA + kNP) * 256 + (size_t)(kNA + kNP) * 512) * sizeof(bf16);
  bf16* agg_a = (bf16*)afterR;            // [NA,256]
  bf16* agg_p = agg_a + (size_t)kNA * 256;// [NP,256]

  const bf16* c_ew_wb = canon + kOff(0);
  const bf16* c_ew_w  = canon + kOff(1);
  const bf16* c_ew_c  = canon + kOff(2);
  const bf16* c_adW   = canon + kOff(3);
  const bf16* c_adb   = canon + kOff(4);
  const bf16* c_kW    = canon + kOff(5);
  const bf16* c_kb    = canon + kOff(6);
  const bf16* c_qW    = canon + kOff(7);
  const bf16* c_qb    = canon + kOff(8);
  const bf16* c_mW    = canon + kOff(9);
  const bf16* c_mb    = canon + kOff(10);
  const bf16* c_aW    = canon + kOff(11);
  const bf16* c_ab    = canon + kOff(12);
  const bf16* c_wpri  = canon + kOff(13);
  const bf16* c_watt  = canon + kOff(14);
  const bf16* c_wmsg  = canon + kOff(15);
  const bf16* c_skip  = canon + kOff(16);
  const bf16* c_lng   = canon + kOff(17);
  const bf16* c_lnb   = canon + kOff(18);
  const bf16* c_outW  = canon + kOff(19);
  const bf16* c_outb  = canon + kOff(20);

  const unsigned* fIn = flags + 0;
  const unsigned* f1  = flags + 1;

  detect_dtype<<<1, 256, 0, stream>>>((const unsigned*)d_in[0], flags);

  CanonArgs ca;
  for (int s = 0; s < kNSeg; ++s) { ca.n[s] = kSegN[s]; ca.dstOff[s] = (unsigned)kOff(s); }
  const int srcIdx[kNSeg] = {2,3,4, 5,6, 7,8, 9,10, 11,12, 13,14, 15, 16,17, 18,19,20, 21,22};
  for (int s = 0; s < kNSeg; ++s) ca.src[s] = d_in[srcIdx[s]];
  canon_kernel<<<dim3(1172, kNSeg), 256, 0, stream>>>(ca, canon, flags);

  // ---- transpose the 10 dense 256x256 weights into [n][k] layout ----
  TransArgs ta;
  ta.src[0] = c_adW;              ta.dst[0] = adWT;
  ta.src[1] = c_adW + 65536;      ta.dst[1] = adWT + 65536;
  for (int m = 0; m < 4; ++m) { ta.src[2 + m] = c_qW + (size_t)m * 65536; ta.dst[2 + m] = qWT + (size_t)m * 65536; }
  for (int m = 0; m < 4; ++m) { ta.src[6 + m] = c_aW + (size_t)m * 65536; ta.dst[6 + m] = aWT + (size_t)m * 65536; }
  transpose_w<<<dim3(4, 4, 10), 256, 0, stream>>>(ta);

  // ---- CSR build ----
  hipMemsetAsync(cur_wb, 0, (size_t)((kNA + 1) + 2 * (kNP + 1)) * 4, stream);
  csr_hist<<<(kEWB + 255) / 256, 256, 0, stream>>>(dst_wb, kEWB, cur_wb);
  csr_hist<<<(kEW  + 255) / 256, 256, 0, stream>>>(dst_w,  kEW,  cur_w);
  csr_hist<<<(kEC  + 255) / 256, 256, 0, stream>>>(dst_c,  kEC,  cur_c);
  csr_scan<<<1, 1024, 0, stream>>>(cur_wb, offs_wb, kNA);
  csr_scan<<<1, 1024, 0, stream>>>(cur_w,  offs_w,  kNP);
  csr_scan<<<1, 1024, 0, stream>>>(cur_c,  offs_c,  kNP);
  csr_scatter<<<(kEWB + 255) / 256, 256, 0, stream>>>(dst_wb, kEWB, cur_wb, sort_wb);
  csr_scatter<<<(kEW  + 255) / 256, 256, 0, stream>>>(dst_w,  kEW,  cur_w,  sort_w);
  csr_scatter<<<(kEC  + 255) / 256, 256, 0, stream>>>(dst_c,  kEC,  cur_c,  sort_c);

  // fused K|M effective weights (K: noff=0, M: noff=256)
  combine_weights<<<dim3(8, 24), 256, 0, stream>>>(c_kW, c_kb, c_watt, KMeffT, kmbeT, 0);
  combine_weights<<<dim3(8, 24), 256, 0, stream>>>(c_mW, c_mb, c_wmsg, KMeffT, kmbeT, 256);

  auto grid = [](int m, int ny) { return dim3((unsigned)((m + 127) / 128), (unsigned)ny); };
  auto mkd = [](const bf16* wt, const bf16* bias, void* c, int ldc, int coff,
                int act, int otype) {
    GemmDesc g;
    g.wt = (const short*)wt; g.bias = bias; g.c = c; g.ldc = ldc;
    g.coff = coff; g.act = act; g.otype = otype; g.pad = 0;
    return g;
  };

  // adapt: feats = gelu(x @ adapt_W + adapt_b)
  {
    MultiDesc md{};
    md.d[0] = mkd(adWT,                c_adb,        fa, 256, 0,   1, 0);
    md.d[1] = mkd(adWT + 128 * 256,    c_adb + 128,  fa, 256, 128, 1, 0);
    mfma_gemm128<<<grid(kNA, 2), 256, 0, stream>>>(d_in[0], fIn, md, kNA);
    md.d[0] = mkd(adWT + 65536,        c_adb + 256,  fp_, 256, 0,   1, 0);
    md.d[1] = mkd(adWT + 65536 + 128 * 256, c_adb + 384, fp_, 256, 128, 1, 0);
    mfma_gemm128<<<grid(kNP, 2), 256, 0, stream>>>(d_in[1], fIn, md, kNP);
  }

  for (int l = 0; l < 2; ++l) {
    const bf16* qW_a = qWT + (size_t)(l * 2 + 0) * 65536;
    const bf16* qW_p = qWT + (size_t)(l * 2 + 1) * 65536;
    const bf16* qb_a = c_qb + (l * 2 + 0) * 256;
    const bf16* qb_p = c_qb + (l * 2 + 1) * 256;
    const bf16* KM_c  = KMeffT + (size_t)(l * 3 + 0) * 512 * 256;
    const bf16* KM_w  = KMeffT + (size_t)(l * 3 + 1) * 512 * 256;
    const bf16* KM_wb = KMeffT + (size_t)(l * 3 + 2) * 512 * 256;
    const bf16* kb_c  = kmbeT + (l * 3 + 0) * 512;
    const bf16* kb_w  = kmbeT + (l * 3 + 1) * 512;
    const bf16* kb_wb = kmbeT + (l * 3 + 2) * 512;

    // authors-proj: Q_a (2 slabs) + KM_w (4 slabs) from fa
    {
      MultiDesc md{};
      md.d[0] = mkd(qW_a,             qb_a,        qa,   256, 0,   0, 0);
      md.d[1] = mkd(qW_a + 128 * 256, qb_a + 128,  qa,   256, 128, 0, 0);
      for (int s = 0; s < 4; ++s)
        md.d[2 + s] = mkd(KM_w + (size_t)s * 128 * 256, kb_w + s * 128, km_a, 512, s * 128, 0, 0);
      mfma_gemm128<<<grid(kNA, 6), 256, 0, stream>>>(fa, f1, md, kNA);
    }
    // papers-proj: Q_p (2 slabs) + KM_wb (4 slabs) from fp_
    {
      MultiDesc md{};
      md.d[0] = mkd(qW_p,             qb_p,        qp,   256, 0,   0, 0);
      md.d[1] = mkd(qW_p + 128 * 256, qb_p + 128,  qp,   256, 128, 0, 0);
      for (int s = 0; s < 4; ++s)
        md.d[2 + s] = mkd(KM_wb + (size_t)s * 128 * 256, kb_wb + s * 128, km_p, 512, s * 128, 0, 0);
      mfma_gemm128<<<grid(kNP, 6), 256, 0, stream>>>(fp_, f1, md, kNP);
    }

    // WRITTEN_BY: paper -> author
    gather_kernel<<<(kNA + 3) / 4, 256, 0, stream>>>(
        qa, km_p, src_wb, sort_wb, offs_wb, c_ew_wb, c_wpri + (l * 3 + 2) * 4,
        agg_a, kNA, 0, 1.f);
    // WRITES: author -> paper
    gather_kernel<<<(kNP + 3) / 4, 256, 0, stream>>>(
        qp, km_a, src_w, sort_w, offs_w, c_ew_w, c_wpri + (l * 3 + 1) * 4,
        agg_p, kNP, 0, 1.f);

    // cites-KM: reuse km_p (wb gather already done in stream order)
    {
      MultiDesc md{};
      for (int s = 0; s < 4; ++s)
        md.d[s] = mkd(KM_c + (size_t)s * 128 * 256, kb_c + s * 128, km_p, 512, s * 128, 0, 0);
      mfma_gemm128<<<grid(kNP, 4), 256, 0, stream>>>(fp_, f1, md, kNP);
    }
    // CITES: paper -> paper, chained add + 0.5 mean
    gather_kernel<<<(kNP + 3) / 4, 256, 0, stream>>>(
        qp, km_p, src_c, sort_c, offs_c, c_ew_c, c_wpri + (l * 3 + 0) * 4,
        agg_p, kNP, 1, 0.5f);

    // A-projection of aggregates -> fp32 tr (aliases R; gathers are done)
    {
      const bf16* aW_a = aWT + (size_t)(l * 2 + 0) * 65536;
      const bf16* aW_p = aWT + (size_t)(l * 2 + 1) * 65536;
      MultiDesc md{};
      md.d[0] = mkd(aW_a,             c_ab + (l * 2 + 0) * 256,       tr_a, 256, 0,   0, 1);
      md.d[1] = mkd(aW_a + 128 * 256, c_ab + (l * 2 + 0) * 256 + 128, tr_a, 256, 128, 0, 1);
      mfma_gemm128<<<grid(kNA, 2), 256, 0, stream>>>(agg_a, f1, md, kNA);
      md.d[0] = mkd(aW_p,             c_ab + (l * 2 + 1) * 256,       tr_p, 256, 0,   0, 1);
      md.d[1] = mkd(aW_p + 128 * 256, c_ab + (l * 2 + 1) * 256 + 128, tr_p, 256, 128, 0, 1);
      mfma_gemm128<<<grid(kNP, 2), 256, 0, stream>>>(agg_p, f1, md, kNP);
    }

    skip_ln<<<kNA / 4, 256, 0, stream>>>(
        tr_a, fa,  c_skip + l * 3 + 0, c_lng + (l * 2 + 0) * 256, c_lnb + (l * 2 + 0) * 256, kNA);
    skip_ln<<<kNP / 4, 256, 0, stream>>>(
        tr_p, fp_, c_skip + l * 3 + 1, c_lng + (l * 2 + 1) * 256, c_lnb + (l * 2 + 1) * 256, kNP);
  }

  out_gemm<<<kNP / 64, 256, 0, stream>>>(fp_, c_outW, c_outb, d_out, fIn, kNP);
}

// Round 8
// 1082.422 us; speedup vs baseline: 6.0586x; 1.0991x over previous
//
#include <hip/hip_runtime.h>
#include <hip/hip_bf16.h>
#include <math.h>

using bf16 = __hip_bfloat16;

typedef __attribute__((ext_vector_type(8))) short short8;   // 8 bf16 (4 VGPRs)
typedef __attribute__((ext_vector_type(4))) float float4v;  // MFMA acc

static constexpr int kNA  = 20000;
static constexpr int kNP  = 40000;
static constexpr int kEWB = 150000;
static constexpr int kEW  = 150000;
static constexpr int kEC  = 300000;

// ---- canonical bf16 input region ----
static constexpr int kNSeg = 21;
static constexpr int kSegN[kNSeg] = {
  150000, 150000, 300000,           // ew_wb, ew_w, ew_c
  131072, 512,                      // adW, adb
  262144, 1024,                     // kW, kb
  262144, 1024,                     // qW, qb
  262144, 1024,                     // mW, mb
  262144, 1024,                     // aW, ab
  24,                               // wpri
  98304, 98304,                     // watt, wmsg
  6, 1024, 1024,                    // skip, lng, lnb
  16384, 64                         // outW, outb
};
static constexpr size_t kOff(int s) {
  size_t o = 0;
  for (int i = 0; i < s; ++i) o += (size_t)kSegN[i];
  return o;
}
static constexpr size_t kCanonTotal = kOff(kNSeg);

struct CanonArgs {
  const void* src[kNSeg];
  int n[kNSeg];
  unsigned dstOff[kNSeg];
};
struct TransArgs {
  const bf16* src[10];
  bf16* dst[10];
};
// per-blockIdx.y GEMM output descriptor (slab = 128 output cols)
struct GemmDesc {
  const short* wt;   // [128][256] n-major slab
  const bf16* bias;  // 128 entries (slab-local)
  void* c;           // output base
  int ldc;           // in elements
  int coff;          // global col offset of this slab in C
  int act;           // 1 = gelu
  int otype;         // 0 = bf16, 1 = fp32
  int pad;
};
struct MultiDesc { GemmDesc d[6]; };

__device__ __forceinline__ float toF(float x) { return x; }
__device__ __forceinline__ float toF(bf16 x)  { return __bfloat162float(x); }
__device__ __forceinline__ float bits2f(unsigned short b) {
  unsigned int u = ((unsigned int)b) << 16;
  return __uint_as_float(u);
}
__device__ __forceinline__ float sigmoidf_(float x) { return 1.0f / (1.0f + expf(-x)); }
__device__ __forceinline__ float gelu_exact(float x) {
  return 0.5f * x * (1.0f + erff(x * 0.70710678118654752f));
}

// -------------------------------------------------------------------------
// Input-dtype sniffer. flags: [0]=isBf16 [1]=1
// -------------------------------------------------------------------------
__global__ __launch_bounds__(256) void detect_dtype(
    const unsigned* __restrict__ x, unsigned* __restrict__ flags)
{
  __shared__ int cnt;
  if (threadIdx.x == 0) cnt = 0;
  __syncthreads();
  unsigned w = x[threadIdx.x];
  unsigned e = (w >> 7) & 0xFFu;
  if (e >= 110u && e <= 140u) atomicAdd(&cnt, 1);
  __syncthreads();
  if (threadIdx.x == 0) {
    flags[0] = (cnt >= 128) ? 1u : 0u;
    flags[1] = 1u;
  }
}

__global__ __launch_bounds__(256) void canon_kernel(
    CanonArgs a, bf16* __restrict__ dst, const unsigned* __restrict__ flags)
{
  const int s = blockIdx.y;
  const int i = blockIdx.x * 256 + threadIdx.x;
  if (i >= a.n[s]) return;
  bf16 v;
  if (flags[0]) v = ((const bf16*)a.src[s])[i];
  else          v = __float2bfloat16(((const float*)a.src[s])[i]);
  dst[a.dstOff[s] + i] = v;
}

// -------------------------------------------------------------------------
// Batched 256x256 weight transpose: dst[n][k] = src[k][n]. grid (4,4,10).
// -------------------------------------------------------------------------
__global__ __launch_bounds__(256) void transpose_w(TransArgs ta)
{
  const int m = blockIdx.z;
  const short* src = (const short*)ta.src[m];
  short* dst = (short*)ta.dst[m];
  const int k0 = blockIdx.x * 64, n0 = blockIdx.y * 64;
  __shared__ short tile[64][65];
  const int tx = threadIdx.x & 63, ty = threadIdx.x >> 6;
  for (int i = ty; i < 64; i += 4)
    tile[i][tx] = src[(size_t)(k0 + i) * 256 + n0 + tx];
  __syncthreads();
  for (int i = ty; i < 64; i += 4)
    dst[(size_t)(n0 + i) * 256 + k0 + tx] = tile[tx][i];
}

// -------------------------------------------------------------------------
// CSR build: histogram -> exclusive scan (single block) -> scatter.
// Scatter pre-gathers src id and edge weight into idx-order arrays
// (removes one dependent-load level from the gather hot loop).
// -------------------------------------------------------------------------
__global__ __launch_bounds__(256) void csr_hist(
    const int* __restrict__ dst, int E, int* __restrict__ cnt)
{
  const int i = blockIdx.x * 256 + threadIdx.x;
  if (i < E) atomicAdd(&cnt[dst[i]], 1);
}

__global__ __launch_bounds__(1024) void csr_scan(
    int* __restrict__ cur, int* __restrict__ offs, int N)
{
  __shared__ int buf[1024];
  __shared__ int carry;
  const int tid = threadIdx.x;
  if (tid == 0) carry = 0;
  __syncthreads();
  for (int base = 0; base < N; base += 1024) {
    const int idx = base + tid;
    const int v = (idx < N) ? cur[idx] : 0;
    buf[tid] = v;
    __syncthreads();
    for (int off = 1; off < 1024; off <<= 1) {
      int t = (tid >= off) ? buf[tid - off] : 0;
      __syncthreads();
      buf[tid] += t;
      __syncthreads();
    }
    const int excl = buf[tid] - v;
    const int total = buf[1023];
    if (idx < N) {
      const int o = carry + excl;
      offs[idx] = o;
      cur[idx] = o;
    }
    __syncthreads();
    if (tid == 0) carry += total;
    __syncthreads();
  }
  if (tid == 0) offs[N] = carry;
}

__global__ __launch_bounds__(256) void csr_scatter(
    const int* __restrict__ dst, const int* __restrict__ src,
    const bf16* __restrict__ ew, int E, int* __restrict__ cur,
    int* __restrict__ srcs, bf16* __restrict__ ews)
{
  const int i = blockIdx.x * 256 + threadIdx.x;
  if (i >= E) return;
  const int p = atomicAdd(&cur[dst[i]], 1);
  srcs[p] = src[i];
  ews[p]  = ew[i];
}

// -------------------------------------------------------------------------
// Fold per-head w_att/w_msg into K/M projections; emit fused-transposed
// KMT[l,e][512][256] bf16 + bias kmb[l,e][512]. grid (8, 24).
// -------------------------------------------------------------------------
__global__ __launch_bounds__(256) void combine_weights(
    const bf16* __restrict__ Wbig, const bf16* __restrict__ bbig,
    const bf16* __restrict__ wsm, bf16* __restrict__ KMT,
    bf16* __restrict__ kmb, int noff)
{
  const int blk = blockIdx.y;
  const int rc  = blockIdx.x;           // 32-row chunk of the 256 K-rows
  const int h = blk & 3;
  const int le = blk >> 2;
  const int e = le % 3;
  const int l = le / 3;
  const int st = (e == 1) ? 0 : 1;      // writes: author src; else paper src

  const short* Wsrc = (const short*)(Wbig + (size_t)(l * 2 + st) * 65536);
  const bf16*  bsrc = bbig + (size_t)(l * 2 + st) * 256;
  const short* wm   = (const short*)(wsm + ((size_t)(l * 3 + e) * 4 + h) * 4096);
  short* outT = (short*)(KMT + (size_t)(l * 3 + e) * 512 * 256);
  bf16* outb  = kmb + (size_t)(l * 3 + e) * 512;

  __shared__ short w[64][72];
  __shared__ short As[32][72];
  __shared__ short ot[64][40];

  const int t = threadIdx.x;
  {
    const int base = t * 16;
    const int r0 = base >> 6, c0 = base & 63;
    *(short8*)&w[r0][c0]     = *(const short8*)&wm[base];
    *(short8*)&w[r0][c0 + 8] = *(const short8*)&wm[base + 8];
  }
  {
    const int row = t >> 3;
    const int kc = (t & 7) * 8;
    *(short8*)&As[row][kc] =
        *(const short8*)&Wsrc[(size_t)(rc * 32 + row) * 256 + h * 64 + kc];
  }
  __syncthreads();

  const int j   = t & 63;
  const int sub = t >> 6;   // 0..3, 8 rows each
  float accv[8] = {};
  #pragma unroll
  for (int d = 0; d < 64; ++d) {
    const float wd = bits2f((unsigned short)w[d][j]);
    #pragma unroll
    for (int r8 = 0; r8 < 8; ++r8)
      accv[r8] += bits2f((unsigned short)As[sub * 8 + r8][d]) * wd;
  }
  #pragma unroll
  for (int r8 = 0; r8 < 8; ++r8) {
    union { bf16 h; short s; } cv;
    cv.h = __float2bfloat16(accv[r8]);
    ot[j][sub * 8 + r8] = cv.s;
  }

  if (rc == 0 && t < 64) {
    float acc = 0.f;
    #pragma unroll
    for (int d = 0; d < 64; ++d)
      acc += toF(bsrc[h * 64 + d]) * bits2f((unsigned short)w[d][t]);
    outb[h * 64 + t + noff] = __float2bfloat16(acc);
  }
  __syncthreads();
  {
    const int nn = t >> 2;
    const int kx = (t & 3) * 8;
    short8 v;
    #pragma unroll
    for (int x = 0; x < 8; ++x) v[x] = ot[nn][kx + x];
    *(short8*)&outT[(size_t)(h * 64 + nn + noff) * 256 + rc * 32 + kx] = v;
  }
}

// -------------------------------------------------------------------------
// Multi-output MFMA GEMM. Tile 128(M) x 128(N), BK=64, 4 waves in 2x2.
// blockIdx.y selects a GemmDesc. LDS 36.9 KB -> 4 blocks/CU.
// -------------------------------------------------------------------------
__global__ __launch_bounds__(256, 4) void mfma_gemm128(
    const void* __restrict__ A, const unsigned* __restrict__ aflag,
    MultiDesc md, int M)
{
  __shared__ short As[128][72];
  __shared__ short Bs[128][72];
  const GemmDesc d = md.d[blockIdx.y];
  const bool abf = (*aflag != 0u);
  const int t = threadIdx.x;
  const int bm = blockIdx.x * 128;
  const int lane = t & 63;
  const int wid  = t >> 6;
  const int wm = (wid >> 1) * 64;
  const int wn = (wid & 1) * 64;
  const int col16 = lane & 15;
  const int quad  = lane >> 4;
  const int rr = t >> 3;        // staging row 0..31
  const int kk = (t & 7) * 8;   // staging k-offset

  float4v acc[4][4];
  #pragma unroll
  for (int mi = 0; mi < 4; ++mi)
    #pragma unroll
    for (int ni = 0; ni < 4; ++ni) acc[mi][ni] = (float4v){0.f, 0.f, 0.f, 0.f};

  for (int k0 = 0; k0 < 256; k0 += 64) {
    #pragma unroll
    for (int it = 0; it < 4; ++it) {
      const int row = it * 32 + rr;
      const int grow = bm + row;
      short8 v = (short8){0, 0, 0, 0, 0, 0, 0, 0};
      if (grow < M) {
        if (abf) {
          v = *(const short8*)((const short*)A + (size_t)grow * 256 + k0 + kk);
        } else {
          const float* ap = (const float*)A + (size_t)grow * 256 + k0 + kk;
          #pragma unroll
          for (int j = 0; j < 8; ++j) {
            union { bf16 h; short s; } cv;
            cv.h = __float2bfloat16(ap[j]);
            v[j] = cv.s;
          }
        }
      }
      *(short8*)&As[row][kk] = v;
    }
    #pragma unroll
    for (int it = 0; it < 4; ++it) {
      const int n = it * 32 + rr;
      *(short8*)&Bs[n][kk] = *(const short8*)&d.wt[(size_t)n * 256 + k0 + kk];
    }
    __syncthreads();

    #pragma unroll
    for (int ks = 0; ks < 64; ks += 32) {
      short8 bfr[4];
      #pragma unroll
      for (int ni = 0; ni < 4; ++ni)
        bfr[ni] = *(const short8*)&Bs[wn + ni * 16 + col16][ks + quad * 8];
      #pragma unroll
      for (int mi = 0; mi < 4; ++mi) {
        const short8 afr = *(const short8*)&As[wm + mi * 16 + col16][ks + quad * 8];
        #pragma unroll
        for (int ni = 0; ni < 4; ++ni)
          acc[mi][ni] = __builtin_amdgcn_mfma_f32_16x16x32_bf16(afr, bfr[ni], acc[mi][ni], 0, 0, 0);
      }
    }
    __syncthreads();
  }

  #pragma unroll
  for (int ni = 0; ni < 4; ++ni) {
    const int col = wn + ni * 16 + col16;        // 0..127 slab-local
    const float bc = toF(d.bias[col]);
    const int gcol = d.coff + col;
    #pragma unroll
    for (int mi = 0; mi < 4; ++mi) {
      #pragma unroll
      for (int r = 0; r < 4; ++r) {
        const int row = bm + wm + mi * 16 + quad * 4 + r;
        if (row < M) {
          float v = acc[mi][ni][r] + bc;
          if (d.act == 1) v = gelu_exact(v);
          const size_t idx = (size_t)row * d.ldc + gcol;
          if (d.otype == 0) ((bf16*)d.c)[idx] = __float2bfloat16(v);
          else              ((float*)d.c)[idx] = v;
        }
      }
    }
  }
}

// -------------------------------------------------------------------------
// CSR gather v2: one wave per dst node, SPLIT into two 32-lane halves that
// process alternate edges (2x edge ILP, halved dependent-chain length).
// Each lane covers 8 contiguous elems (uint4 16B loads); head-dot reduces
// in 3 shuffle rounds over 8-lane groups. Halves merged via shfl_xor(32).
// srcs/ews are idx-ordered (no sorted->src indirection).
// -------------------------------------------------------------------------
__global__ __launch_bounds__(256) void gather_kernel(
    const bf16* __restrict__ q, const bf16* __restrict__ km,
    const int* __restrict__ srcs, const bf16* __restrict__ ews,
    const int* __restrict__ offs, const bf16* __restrict__ pri,
    bf16* __restrict__ agg, int Nd, int addPrev, float finalScale)
{
  const int lane = threadIdx.x & 63;
  const int wid  = threadIdx.x >> 6;
  const int node = blockIdx.x * 4 + wid;
  if (node >= Nd) return;
  const int h  = lane >> 5;   // half 0/1
  const int sl = lane & 31;   // sublane: covers elems sl*8..sl*8+7, head sl>>3
  const float prih = toF(pri[sl >> 3]);

  union B8 { uint4 u; unsigned short s[8]; };
  B8 qv;
  qv.u = ((const uint4*)(q + (size_t)node * 256))[sl];
  float qf[8];
  #pragma unroll
  for (int j = 0; j < 8; ++j) qf[j] = bits2f(qv.s[j]);

  float acc[8] = {};
  const int beg = offs[node], end = offs[node + 1];
  for (int idx = beg + h; idx < end; idx += 2) {
    const int s = srcs[idx];
    const float w = toF(ews[idx]);
    B8 kb;
    kb.u = ((const uint4*)(km + (size_t)s * 512))[sl];
    float dot = 0.f;
    #pragma unroll
    for (int j = 0; j < 8; ++j) dot += qf[j] * bits2f(kb.s[j]);
    dot += __shfl_xor(dot, 1);
    dot += __shfl_xor(dot, 2);
    dot += __shfl_xor(dot, 4);
    const float a = w * sigmoidf_(dot * prih * 0.125f);
    B8 mb;
    mb.u = ((const uint4*)(km + (size_t)s * 512 + 256))[sl];
    #pragma unroll
    for (int j = 0; j < 8; ++j) acc[j] += bits2f(mb.s[j]) * a;
  }

  // merge the two halves
  #pragma unroll
  for (int j = 0; j < 8; ++j) acc[j] += __shfl_xor(acc[j], 32);

  if (h == 0) {
    bf16* out = agg + (size_t)node * 256 + sl * 8;
    if (addPrev) {
      B8 pb;
      pb.u = *(const uint4*)out;
      #pragma unroll
      for (int j = 0; j < 8; ++j) acc[j] += bits2f(pb.s[j]);
    }
    B8 ov;
    #pragma unroll
    for (int j = 0; j < 8; ++j) {
      union { bf16 h; unsigned short u; } cv;
      cv.h = __float2bfloat16(acc[j] * finalScale);
      ov.s[j] = cv.u;
    }
    *(uint4*)out = ov.u;
  }
}

// -------------------------------------------------------------------------
// o = tr*alpha + feat*(1-alpha); feat = bf16(LN(o)*g + b). One wave per node.
// -------------------------------------------------------------------------
__global__ __launch_bounds__(256) void skip_ln(
    const float* __restrict__ tr, bf16* __restrict__ feat,
    const bf16* __restrict__ skipv, const bf16* __restrict__ g,
    const bf16* __restrict__ b, int N)
{
  const int lane = threadIdx.x & 63;
  const int wid  = threadIdx.x >> 6;
  const int node = blockIdx.x * 4 + wid;
  if (node >= N) return;
  const float alpha = sigmoidf_(toF(*skipv));
  const float4 t = ((const float4*)(tr + (size_t)node * 256))[lane];
  union B4 { uint2 u; unsigned short s[4]; };
  B4 fb;
  fb.u = ((const uint2*)(feat + (size_t)node * 256))[lane];
  float o[4];
  o[0] = t.x * alpha + bits2f(fb.s[0]) * (1.f - alpha);
  o[1] = t.y * alpha + bits2f(fb.s[1]) * (1.f - alpha);
  o[2] = t.z * alpha + bits2f(fb.s[2]) * (1.f - alpha);
  o[3] = t.w * alpha + bits2f(fb.s[3]) * (1.f - alpha);

  float sum = o[0] + o[1] + o[2] + o[3];
  #pragma unroll
  for (int off = 32; off; off >>= 1) sum += __shfl_xor(sum, off);
  const float mu = sum * (1.f / 256.f);

  float dd[4], sq = 0.f;
  #pragma unroll
  for (int j = 0; j < 4; ++j) { dd[j] = o[j] - mu; sq += dd[j] * dd[j]; }
  #pragma unroll
  for (int off = 32; off; off >>= 1) sq += __shfl_xor(sq, off);
  const float rs = rsqrtf(sq * (1.f / 256.f) + 1e-5f);

  bf16* fout = feat + (size_t)node * 256 + lane * 4;
  #pragma unroll
  for (int j = 0; j < 4; ++j) {
    float r = dd[j] * rs * toF(g[lane * 4 + j]) + toF(b[lane * 4 + j]);
    fout[j] = __float2bfloat16(r);
  }
}

// -------------------------------------------------------------------------
// out[M,64] = A[M,256] @ W[256,64] + b[64]; output dtype per *flag.
// -------------------------------------------------------------------------
__global__ __launch_bounds__(256) void out_gemm(
    const bf16* __restrict__ A, const bf16* __restrict__ W,
    const bf16* __restrict__ bias, void* __restrict__ out,
    const unsigned* __restrict__ flag, int M)
{
  __shared__ float Ws[64][64];
  const bool obf = (*flag != 0u);
  const int tid = threadIdx.x;
  const int row = blockIdx.x * 64 + (tid >> 2);
  const int c0 = (tid & 3) * 16;
  const int arow = (row < M) ? row : 0;
  const bf16* a = A + (size_t)arow * 256;
  float acc[16] = {};
  for (int k0 = 0; k0 < 256; k0 += 64) {
    for (int i = tid; i < 4096; i += 256)
      Ws[i >> 6][i & 63] = toF(W[(size_t)(k0 + (i >> 6)) * 64 + (i & 63)]);
    __syncthreads();
    for (int k = 0; k < 64; ++k) {
      const float av = toF(a[k0 + k]);
      #pragma unroll
      for (int j = 0; j < 16; ++j) acc[j] += av * Ws[k][c0 + j];
    }
    __syncthreads();
  }
  if (row < M) {
    #pragma unroll
    for (int j = 0; j < 16; ++j) {
      const float v = acc[j] + toF(bias[c0 + j]);
      const size_t idx = (size_t)row * 64 + c0 + j;
      if (obf) ((bf16*)out)[idx] = __float2bfloat16(v);
      else     ((float*)out)[idx] = v;
    }
  }
}

// -------------------------------------------------------------------------
extern "C" void kernel_launch(void* const* d_in, const int* in_sizes, int n_in,
                              void* d_out, int out_size, void* d_ws, size_t ws_size,
                              hipStream_t stream) {
  const int* src_wb  = (const int*)d_in[23];
  const int* dst_wb  = (const int*)d_in[24];
  const int* src_w   = (const int*)d_in[25];
  const int* dst_w   = (const int*)d_in[26];
  const int* src_c   = (const int*)d_in[27];
  const int* dst_c   = (const int*)d_in[28];

  // ---- workspace carve (~166 MB total) ----
  char* base = (char*)d_ws;
  unsigned* flags = (unsigned*)base;                       // 256 B
  bf16* canon = (bf16*)(base + 256);
  char* p = base + 256 + (((size_t)kCanonTotal * 2 + 511) & ~(size_t)511);
  bf16* adWT = (bf16*)p;                     // 2 x 65536
  bf16* qWT  = adWT + (size_t)2 * 65536;     // 4 x 65536
  bf16* aWT  = qWT  + (size_t)4 * 65536;     // 4 x 65536
  bf16* KMeffT = aWT + (size_t)4 * 65536;    // 6 x 512*256
  bf16* kmbeT  = KMeffT + (size_t)6 * 512 * 256;  // 6 x 512
  char* pc = (char*)(((size_t)(kmbeT + 6 * 512) + 511) & ~(size_t)511);
  // CSR region
  int* cur_wb  = (int*)pc;
  int* cur_w   = cur_wb + (kNA + 1);
  int* cur_c   = cur_w + (kNP + 1);
  int* offs_wb = cur_c + (kNP + 1);
  int* offs_w  = offs_wb + (kNA + 1);
  int* offs_c  = offs_w + (kNP + 1);
  int* srcs_wb = offs_c + (kNP + 1);
  int* srcs_w  = srcs_wb + kEWB;
  int* srcs_c  = srcs_w + kEW;
  bf16* ews_wb = (bf16*)(srcs_c + kEC);
  bf16* ews_w  = ews_wb + kEWB;
  bf16* ews_c  = ews_w + kEW;
  char* p2 = (char*)(((size_t)(ews_c + kEC) + 511) & ~(size_t)511);
  bf16* fa  = (bf16*)p2;                  // [NA,256]
  bf16* fp_ = fa + (size_t)kNA * 256;     // [NP,256]
  char* R   = (char*)(fp_ + (size_t)kNP * 256);
  bf16* qa   = (bf16*)R;                  // [NA,256]
  bf16* qp   = qa + (size_t)kNA * 256;    // [NP,256]
  bf16* km_a = qp + (size_t)kNP * 256;    // [NA,512] authors KM (writes rel)
  bf16* km_p = km_a + (size_t)kNA * 512;  // [NP,512] papers KM (wb, then cites)
  float* tr_a = (float*)R;                // fp32 view of R, disjoint lifetime
  float* tr_p = tr_a + (size_t)kNA * 256;
  char* afterR = R + ((size_t)(kNA + kNP) * 256 + (size_t)(kNA + kNP) * 512) * sizeof(bf16);
  bf16* agg_a = (bf16*)afterR;            // [NA,256]
  bf16* agg_p = agg_a + (size_t)kNA * 256;// [NP,256]

  const bf16* c_ew_wb = canon + kOff(0);
  const bf16* c_ew_w  = canon + kOff(1);
  const bf16* c_ew_c  = canon + kOff(2);
  const bf16* c_adW   = canon + kOff(3);
  const bf16* c_adb   = canon + kOff(4);
  const bf16* c_kW    = canon + kOff(5);
  const bf16* c_kb    = canon + kOff(6);
  const bf16* c_qW    = canon + kOff(7);
  const bf16* c_qb    = canon + kOff(8);
  const bf16* c_mW    = canon + kOff(9);
  const bf16* c_mb    = canon + kOff(10);
  const bf16* c_aW    = canon + kOff(11);
  const bf16* c_ab    = canon + kOff(12);
  const bf16* c_wpri  = canon + kOff(13);
  const bf16* c_watt  = canon + kOff(14);
  const bf16* c_wmsg  = canon + kOff(15);
  const bf16* c_skip  = canon + kOff(16);
  const bf16* c_lng   = canon + kOff(17);
  const bf16* c_lnb   = canon + kOff(18);
  const bf16* c_outW  = canon + kOff(19);
  const bf16* c_outb  = canon + kOff(20);

  const unsigned* fIn = flags + 0;
  const unsigned* f1  = flags + 1;

  detect_dtype<<<1, 256, 0, stream>>>((const unsigned*)d_in[0], flags);

  CanonArgs ca;
  for (int s = 0; s < kNSeg; ++s) { ca.n[s] = kSegN[s]; ca.dstOff[s] = (unsigned)kOff(s); }
  const int srcIdx[kNSeg] = {2,3,4, 5,6, 7,8, 9,10, 11,12, 13,14, 15, 16,17, 18,19,20, 21,22};
  for (int s = 0; s < kNSeg; ++s) ca.src[s] = d_in[srcIdx[s]];
  canon_kernel<<<dim3(1172, kNSeg), 256, 0, stream>>>(ca, canon, flags);

  // ---- transpose the 10 dense 256x256 weights into [n][k] layout ----
  TransArgs ta;
  ta.src[0] = c_adW;              ta.dst[0] = adWT;
  ta.src[1] = c_adW + 65536;      ta.dst[1] = adWT + 65536;
  for (int m = 0; m < 4; ++m) { ta.src[2 + m] = c_qW + (size_t)m * 65536; ta.dst[2 + m] = qWT + (size_t)m * 65536; }
  for (int m = 0; m < 4; ++m) { ta.src[6 + m] = c_aW + (size_t)m * 65536; ta.dst[6 + m] = aWT + (size_t)m * 65536; }
  transpose_w<<<dim3(4, 4, 10), 256, 0, stream>>>(ta);

  // ---- CSR build (canon must precede scatter: ews gathers canon'd ew) ----
  hipMemsetAsync(cur_wb, 0, (size_t)((kNA + 1) + 2 * (kNP + 1)) * 4, stream);
  csr_hist<<<(kEWB + 255) / 256, 256, 0, stream>>>(dst_wb, kEWB, cur_wb);
  csr_hist<<<(kEW  + 255) / 256, 256, 0, stream>>>(dst_w,  kEW,  cur_w);
  csr_hist<<<(kEC  + 255) / 256, 256, 0, stream>>>(dst_c,  kEC,  cur_c);
  csr_scan<<<1, 1024, 0, stream>>>(cur_wb, offs_wb, kNA);
  csr_scan<<<1, 1024, 0, stream>>>(cur_w,  offs_w,  kNP);
  csr_scan<<<1, 1024, 0, stream>>>(cur_c,  offs_c,  kNP);
  csr_scatter<<<(kEWB + 255) / 256, 256, 0, stream>>>(dst_wb, src_wb, c_ew_wb, kEWB, cur_wb, srcs_wb, ews_wb);
  csr_scatter<<<(kEW  + 255) / 256, 256, 0, stream>>>(dst_w,  src_w,  c_ew_w,  kEW,  cur_w,  srcs_w,  ews_w);
  csr_scatter<<<(kEC  + 255) / 256, 256, 0, stream>>>(dst_c,  src_c,  c_ew_c,  kEC,  cur_c,  srcs_c,  ews_c);

  // fused K|M effective weights (K: noff=0, M: noff=256)
  combine_weights<<<dim3(8, 24), 256, 0, stream>>>(c_kW, c_kb, c_watt, KMeffT, kmbeT, 0);
  combine_weights<<<dim3(8, 24), 256, 0, stream>>>(c_mW, c_mb, c_wmsg, KMeffT, kmbeT, 256);

  auto grid = [](int m, int ny) { return dim3((unsigned)((m + 127) / 128), (unsigned)ny); };
  auto mkd = [](const bf16* wt, const bf16* bias, void* c, int ldc, int coff,
                int act, int otype) {
    GemmDesc g;
    g.wt = (const short*)wt; g.bias = bias; g.c = c; g.ldc = ldc;
    g.coff = coff; g.act = act; g.otype = otype; g.pad = 0;
    return g;
  };

  // adapt: feats = gelu(x @ adapt_W + adapt_b)
  {
    MultiDesc md{};
    md.d[0] = mkd(adWT,                c_adb,        fa, 256, 0,   1, 0);
    md.d[1] = mkd(adWT + 128 * 256,    c_adb + 128,  fa, 256, 128, 1, 0);
    mfma_gemm128<<<grid(kNA, 2), 256, 0, stream>>>(d_in[0], fIn, md, kNA);
    md.d[0] = mkd(adWT + 65536,        c_adb + 256,  fp_, 256, 0,   1, 0);
    md.d[1] = mkd(adWT + 65536 + 128 * 256, c_adb + 384, fp_, 256, 128, 1, 0);
    mfma_gemm128<<<grid(kNP, 2), 256, 0, stream>>>(d_in[1], fIn, md, kNP);
  }

  for (int l = 0; l < 2; ++l) {
    const bf16* qW_a = qWT + (size_t)(l * 2 + 0) * 65536;
    const bf16* qW_p = qWT + (size_t)(l * 2 + 1) * 65536;
    const bf16* qb_a = c_qb + (l * 2 + 0) * 256;
    const bf16* qb_p = c_qb + (l * 2 + 1) * 256;
    const bf16* KM_c  = KMeffT + (size_t)(l * 3 + 0) * 512 * 256;
    const bf16* KM_w  = KMeffT + (size_t)(l * 3 + 1) * 512 * 256;
    const bf16* KM_wb = KMeffT + (size_t)(l * 3 + 2) * 512 * 256;
    const bf16* kb_c  = kmbeT + (l * 3 + 0) * 512;
    const bf16* kb_w  = kmbeT + (l * 3 + 1) * 512;
    const bf16* kb_wb = kmbeT + (l * 3 + 2) * 512;

    // authors-proj: Q_a (2 slabs) + KM_w (4 slabs) from fa
    {
      MultiDesc md{};
      md.d[0] = mkd(qW_a,             qb_a,        qa,   256, 0,   0, 0);
      md.d[1] = mkd(qW_a + 128 * 256, qb_a + 128,  qa,   256, 128, 0, 0);
      for (int s = 0; s < 4; ++s)
        md.d[2 + s] = mkd(KM_w + (size_t)s * 128 * 256, kb_w + s * 128, km_a, 512, s * 128, 0, 0);
      mfma_gemm128<<<grid(kNA, 6), 256, 0, stream>>>(fa, f1, md, kNA);
    }
    // papers-proj: Q_p (2 slabs) + KM_wb (4 slabs) from fp_
    {
      MultiDesc md{};
      md.d[0] = mkd(qW_p,             qb_p,        qp,   256, 0,   0, 0);
      md.d[1] = mkd(qW_p + 128 * 256, qb_p + 128,  qp,   256, 128, 0, 0);
      for (int s = 0; s < 4; ++s)
        md.d[2 + s] = mkd(KM_wb + (size_t)s * 128 * 256, kb_wb + s * 128, km_p, 512, s * 128, 0, 0);
      mfma_gemm128<<<grid(kNP, 6), 256, 0, stream>>>(fp_, f1, md, kNP);
    }

    // WRITTEN_BY: paper -> author
    gather_kernel<<<(kNA + 3) / 4, 256, 0, stream>>>(
        qa, km_p, srcs_wb, ews_wb, offs_wb, c_wpri + (l * 3 + 2) * 4,
        agg_a, kNA, 0, 1.f);
    // WRITES: author -> paper
    gather_kernel<<<(kNP + 3) / 4, 256, 0, stream>>>(
        qp, km_a, srcs_w, ews_w, offs_w, c_wpri + (l * 3 + 1) * 4,
        agg_p, kNP, 0, 1.f);

    // cites-KM: reuse km_p (wb gather already done in stream order)
    {
      MultiDesc md{};
      for (int s = 0; s < 4; ++s)
        md.d[s] = mkd(KM_c + (size_t)s * 128 * 256, kb_c + s * 128, km_p, 512, s * 128, 0, 0);
      mfma_gemm128<<<grid(kNP, 4), 256, 0, stream>>>(fp_, f1, md, kNP);
    }
    // CITES: paper -> paper, chained add + 0.5 mean
    gather_kernel<<<(kNP + 3) / 4, 256, 0, stream>>>(
        qp, km_p, srcs_c, ews_c, offs_c, c_wpri + (l * 3 + 0) * 4,
        agg_p, kNP, 1, 0.5f);

    // A-projection of aggregates -> fp32 tr (aliases R; gathers are done)
    {
      const bf16* aW_a = aWT + (size_t)(l * 2 + 0) * 65536;
      const bf16* aW_p = aWT + (size_t)(l * 2 + 1) * 65536;
      MultiDesc md{};
      md.d[0] = mkd(aW_a,             c_ab + (l * 2 + 0) * 256,       tr_a, 256, 0,   0, 1);
      md.d[1] = mkd(aW_a + 128 * 256, c_ab + (l * 2 + 0) * 256 + 128, tr_a, 256, 128, 0, 1);
      mfma_gemm128<<<grid(kNA, 2), 256, 0, stream>>>(agg_a, f1, md, kNA);
      md.d[0] = mkd(aW_p,             c_ab + (l * 2 + 1) * 256,       tr_p, 256, 0,   0, 1);
      md.d[1] = mkd(aW_p + 128 * 256, c_ab + (l * 2 + 1) * 256 + 128, tr_p, 256, 128, 0, 1);
      mfma_gemm128<<<grid(kNP, 2), 256, 0, stream>>>(agg_p, f1, md, kNP);
    }

    skip_ln<<<kNA / 4, 256, 0, stream>>>(
        tr_a, fa,  c_skip + l * 3 + 0, c_lng + (l * 2 + 0) * 256, c_lnb + (l * 2 + 0) * 256, kNA);
    skip_ln<<<kNP / 4, 256, 0, stream>>>(
        tr_p, fp_, c_skip + l * 3 + 1, c_lng + (l * 2 + 1) * 256, c_lnb + (l * 2 + 1) * 256, kNP);
  }

  out_gemm<<<kNP / 64, 256, 0, stream>>>(fp_, c_outW, c_outb, d_out, fIn, kNP);
}

// Round 9
// 911.952 us; speedup vs baseline: 7.1911x; 1.1869x over previous
//
#include <hip/hip_runtime.h>
#include <hip/hip_bf16.h>
#include <math.h>

using bf16 = __hip_bfloat16;

typedef __attribute__((ext_vector_type(8))) short short8;   // 8 bf16 (4 VGPRs)
typedef __attribute__((ext_vector_type(4))) float float4v;  // MFMA acc

static constexpr int kNA  = 20000;
static constexpr int kNP  = 40000;
static constexpr int kEWB = 150000;
static constexpr int kEW  = 150000;
static constexpr int kEC  = 300000;

// ---- canonical bf16 input region ----
static constexpr int kNSeg = 21;
static constexpr int kSegN[kNSeg] = {
  150000, 150000, 300000,           // ew_wb, ew_w, ew_c
  131072, 512,                      // adW, adb
  262144, 1024,                     // kW, kb
  262144, 1024,                     // qW, qb
  262144, 1024,                     // mW, mb
  262144, 1024,                     // aW, ab
  24,                               // wpri
  98304, 98304,                     // watt, wmsg
  6, 1024, 1024,                    // skip, lng, lnb
  16384, 64                         // outW, outb
};
static constexpr size_t kOff(int s) {
  size_t o = 0;
  for (int i = 0; i < s; ++i) o += (size_t)kSegN[i];
  return o;
}
static constexpr size_t kCanonTotal = kOff(kNSeg);

struct CanonArgs {
  const void* src[kNSeg];
  int n[kNSeg];
  unsigned dstOff[kNSeg];
};
struct TransArgs {
  const bf16* src[10];
  bf16* dst[10];
};
// per-blockIdx.y GEMM output descriptor (slab = 128 output cols)
struct GemmDesc {
  const short* wt;   // [128][256] n-major slab
  const bf16* bias;  // 128 entries (slab-local)
  void* c;           // output base
  int ldc;           // in elements
  int coff;          // global col offset of this slab in C
  int act;           // 1 = gelu
  int otype;         // 0 = bf16, 1 = fp32
  int pad;
};
struct MultiDesc { GemmDesc d[6]; };
// three-relation scan descriptor
struct ScanArgs {
  int* deg[3];   // degree arrays (also cursor output)
  int* offs[3];  // offsets (N+1)
  int* bsums;    // [3][32] block sums
  int N[3];
};

__device__ __forceinline__ float toF(float x) { return x; }
__device__ __forceinline__ float toF(bf16 x)  { return __bfloat162float(x); }
__device__ __forceinline__ float bits2f(unsigned short b) {
  unsigned int u = ((unsigned int)b) << 16;
  return __uint_as_float(u);
}
__device__ __forceinline__ float sigmoidf_(float x) { return 1.0f / (1.0f + expf(-x)); }
__device__ __forceinline__ float gelu_exact(float x) {
  return 0.5f * x * (1.0f + erff(x * 0.70710678118654752f));
}

// -------------------------------------------------------------------------
// Input-dtype sniffer. flags: [0]=isBf16 [1]=1
// -------------------------------------------------------------------------
__global__ __launch_bounds__(256) void detect_dtype(
    const unsigned* __restrict__ x, unsigned* __restrict__ flags)
{
  __shared__ int cnt;
  if (threadIdx.x == 0) cnt = 0;
  __syncthreads();
  unsigned w = x[threadIdx.x];
  unsigned e = (w >> 7) & 0xFFu;
  if (e >= 110u && e <= 140u) atomicAdd(&cnt, 1);
  __syncthreads();
  if (threadIdx.x == 0) {
    flags[0] = (cnt >= 128) ? 1u : 0u;
    flags[1] = 1u;
  }
}

__global__ __launch_bounds__(256) void canon_kernel(
    CanonArgs a, bf16* __restrict__ dst, const unsigned* __restrict__ flags)
{
  const int s = blockIdx.y;
  const int i = blockIdx.x * 256 + threadIdx.x;
  if (i >= a.n[s]) return;
  bf16 v;
  if (flags[0]) v = ((const bf16*)a.src[s])[i];
  else          v = __float2bfloat16(((const float*)a.src[s])[i]);
  dst[a.dstOff[s] + i] = v;
}

// -------------------------------------------------------------------------
// Batched 256x256 weight transpose: dst[n][k] = src[k][n]. grid (4,4,10).
// -------------------------------------------------------------------------
__global__ __launch_bounds__(256) void transpose_w(TransArgs ta)
{
  const int m = blockIdx.z;
  const short* src = (const short*)ta.src[m];
  short* dst = (short*)ta.dst[m];
  const int k0 = blockIdx.x * 64, n0 = blockIdx.y * 64;
  __shared__ short tile[64][65];
  const int tx = threadIdx.x & 63, ty = threadIdx.x >> 6;
  for (int i = ty; i < 64; i += 4)
    tile[i][tx] = src[(size_t)(k0 + i) * 256 + n0 + tx];
  __syncthreads();
  for (int i = ty; i < 64; i += 4)
    dst[(size_t)(n0 + i) * 256 + k0 + tx] = tile[tx][i];
}

// -------------------------------------------------------------------------
// CSR build: histogram -> 3-level parallel scan -> gather-scatter.
// -------------------------------------------------------------------------
__global__ __launch_bounds__(256) void csr_hist(
    const int* __restrict__ dst, int E, int* __restrict__ cnt)
{
  const int i = blockIdx.x * 256 + threadIdx.x;
  if (i < E) atomicAdd(&cnt[dst[i]], 1);
}

// level 1: per-block (2048-elem chunk) local exclusive scan + block sums.
// grid (32, 3) so all bsums entries get written.
__global__ __launch_bounds__(256) void scan_l1(ScanArgs a)
{
  const int rel = blockIdx.y;
  const int N = a.N[rel];
  const int t = threadIdx.x;
  const int lane = t & 63;
  const int wid = t >> 6;
  const int i0 = blockIdx.x * 2048 + t * 8;
  const int* deg = a.deg[rel];
  int v[8];
  int T = 0;
  #pragma unroll
  for (int j = 0; j < 8; ++j) {
    v[j] = (i0 + j < N) ? deg[i0 + j] : 0;
    T += v[j];
  }
  int incl = T;
  #pragma unroll
  for (int off = 1; off < 64; off <<= 1) {
    const int u = __shfl_up(incl, off);
    if (lane >= off) incl += u;
  }
  __shared__ int wsum[4];
  if (lane == 63) wsum[wid] = incl;
  __syncthreads();
  int woff = 0;
  #pragma unroll
  for (int wp = 0; wp < 4; ++wp) if (wp < wid) woff += wsum[wp];
  int run = woff + incl - T;
  int* offs = a.offs[rel];
  #pragma unroll
  for (int j = 0; j < 8; ++j) {
    if (i0 + j < N) offs[i0 + j] = run;
    run += v[j];
  }
  if (t == 0)
    a.bsums[rel * 32 + blockIdx.x] = wsum[0] + wsum[1] + wsum[2] + wsum[3];
}

// level 2: scan the 32 block sums per relation (one wave each). grid (3).
__global__ __launch_bounds__(64) void scan_l2(int* __restrict__ bsums,
                                              int* __restrict__ totals)
{
  const int rel = blockIdx.x;
  const int lane = threadIdx.x;
  const int v = (lane < 32) ? bsums[rel * 32 + lane] : 0;
  int incl = v;
  #pragma unroll
  for (int off = 1; off < 64; off <<= 1) {
    const int u = __shfl_up(incl, off);
    if (lane >= off) incl += u;
  }
  if (lane < 32) bsums[rel * 32 + lane] = incl - v;
  if (lane == 63) totals[rel] = incl;
}

// level 3: add block offsets; write final offs + cursor copy (deg array
// becomes the scatter cursor); offs[N] = total. grid (20, 3).
__global__ __launch_bounds__(256) void scan_l3(ScanArgs a,
                                               const int* __restrict__ totals)
{
  const int rel = blockIdx.y;
  const int N = a.N[rel];
  const int i0 = blockIdx.x * 2048 + threadIdx.x * 8;
  const int boff = a.bsums[rel * 32 + blockIdx.x];
  int* offs = a.offs[rel];
  int* cur = a.deg[rel];
  #pragma unroll
  for (int j = 0; j < 8; ++j) {
    const int idx = i0 + j;
    if (idx < N) {
      const int o = offs[idx] + boff;
      offs[idx] = o;
      cur[idx] = o;
    }
  }
  if (blockIdx.x == 0 && threadIdx.x == 0) offs[N] = totals[rel];
}

__global__ __launch_bounds__(256) void csr_scatter(
    const int* __restrict__ dst, const int* __restrict__ src,
    const bf16* __restrict__ ew, int E, int* __restrict__ cur,
    int* __restrict__ srcs, bf16* __restrict__ ews)
{
  const int i = blockIdx.x * 256 + threadIdx.x;
  if (i >= E) return;
  const int p = atomicAdd(&cur[dst[i]], 1);
  srcs[p] = src[i];
  ews[p]  = ew[i];
}

// -------------------------------------------------------------------------
// Fold per-head w_att/w_msg into K/M projections; emit fused-transposed
// KMT[l,e][512][256] bf16 + bias kmb[l,e][512]. grid (8, 24).
// -------------------------------------------------------------------------
__global__ __launch_bounds__(256) void combine_weights(
    const bf16* __restrict__ Wbig, const bf16* __restrict__ bbig,
    const bf16* __restrict__ wsm, bf16* __restrict__ KMT,
    bf16* __restrict__ kmb, int noff)
{
  const int blk = blockIdx.y;
  const int rc  = blockIdx.x;           // 32-row chunk of the 256 K-rows
  const int h = blk & 3;
  const int le = blk >> 2;
  const int e = le % 3;
  const int l = le / 3;
  const int st = (e == 1) ? 0 : 1;      // writes: author src; else paper src

  const short* Wsrc = (const short*)(Wbig + (size_t)(l * 2 + st) * 65536);
  const bf16*  bsrc = bbig + (size_t)(l * 2 + st) * 256;
  const short* wm   = (const short*)(wsm + ((size_t)(l * 3 + e) * 4 + h) * 4096);
  short* outT = (short*)(KMT + (size_t)(l * 3 + e) * 512 * 256);
  bf16* outb  = kmb + (size_t)(l * 3 + e) * 512;

  __shared__ short w[64][72];
  __shared__ short As[32][72];
  __shared__ short ot[64][40];

  const int t = threadIdx.x;
  {
    const int base = t * 16;
    const int r0 = base >> 6, c0 = base & 63;
    *(short8*)&w[r0][c0]     = *(const short8*)&wm[base];
    *(short8*)&w[r0][c0 + 8] = *(const short8*)&wm[base + 8];
  }
  {
    const int row = t >> 3;
    const int kc = (t & 7) * 8;
    *(short8*)&As[row][kc] =
        *(const short8*)&Wsrc[(size_t)(rc * 32 + row) * 256 + h * 64 + kc];
  }
  __syncthreads();

  const int j   = t & 63;
  const int sub = t >> 6;   // 0..3, 8 rows each
  float accv[8] = {};
  #pragma unroll
  for (int d = 0; d < 64; ++d) {
    const float wd = bits2f((unsigned short)w[d][j]);
    #pragma unroll
    for (int r8 = 0; r8 < 8; ++r8)
      accv[r8] += bits2f((unsigned short)As[sub * 8 + r8][d]) * wd;
  }
  #pragma unroll
  for (int r8 = 0; r8 < 8; ++r8) {
    union { bf16 h; short s; } cv;
    cv.h = __float2bfloat16(accv[r8]);
    ot[j][sub * 8 + r8] = cv.s;
  }

  if (rc == 0 && t < 64) {
    float acc = 0.f;
    #pragma unroll
    for (int d = 0; d < 64; ++d)
      acc += toF(bsrc[h * 64 + d]) * bits2f((unsigned short)w[d][t]);
    outb[h * 64 + t + noff] = __float2bfloat16(acc);
  }
  __syncthreads();
  {
    const int nn = t >> 2;
    const int kx = (t & 3) * 8;
    short8 v;
    #pragma unroll
    for (int x = 0; x < 8; ++x) v[x] = ot[nn][kx + x];
    *(short8*)&outT[(size_t)(h * 64 + nn + noff) * 256 + rc * 32 + kx] = v;
  }
}

// -------------------------------------------------------------------------
// Multi-output MFMA GEMM. Tile 128(M) x 128(N), BK=64, 4 waves in 2x2.
// blockIdx.y selects a GemmDesc. LDS 36.9 KB -> 4 blocks/CU.
// -------------------------------------------------------------------------
__global__ __launch_bounds__(256, 4) void mfma_gemm128(
    const void* __restrict__ A, const unsigned* __restrict__ aflag,
    MultiDesc md, int M)
{
  __shared__ short As[128][72];
  __shared__ short Bs[128][72];
  const GemmDesc d = md.d[blockIdx.y];
  const bool abf = (*aflag != 0u);
  const int t = threadIdx.x;
  const int bm = blockIdx.x * 128;
  const int lane = t & 63;
  const int wid  = t >> 6;
  const int wm = (wid >> 1) * 64;
  const int wn = (wid & 1) * 64;
  const int col16 = lane & 15;
  const int quad  = lane >> 4;
  const int rr = t >> 3;        // staging row 0..31
  const int kk = (t & 7) * 8;   // staging k-offset

  float4v acc[4][4];
  #pragma unroll
  for (int mi = 0; mi < 4; ++mi)
    #pragma unroll
    for (int ni = 0; ni < 4; ++ni) acc[mi][ni] = (float4v){0.f, 0.f, 0.f, 0.f};

  for (int k0 = 0; k0 < 256; k0 += 64) {
    #pragma unroll
    for (int it = 0; it < 4; ++it) {
      const int row = it * 32 + rr;
      const int grow = bm + row;
      short8 v = (short8){0, 0, 0, 0, 0, 0, 0, 0};
      if (grow < M) {
        if (abf) {
          v = *(const short8*)((const short*)A + (size_t)grow * 256 + k0 + kk);
        } else {
          const float* ap = (const float*)A + (size_t)grow * 256 + k0 + kk;
          #pragma unroll
          for (int j = 0; j < 8; ++j) {
            union { bf16 h; short s; } cv;
            cv.h = __float2bfloat16(ap[j]);
            v[j] = cv.s;
          }
        }
      }
      *(short8*)&As[row][kk] = v;
    }
    #pragma unroll
    for (int it = 0; it < 4; ++it) {
      const int n = it * 32 + rr;
      *(short8*)&Bs[n][kk] = *(const short8*)&d.wt[(size_t)n * 256 + k0 + kk];
    }
    __syncthreads();

    #pragma unroll
    for (int ks = 0; ks < 64; ks += 32) {
      short8 bfr[4];
      #pragma unroll
      for (int ni = 0; ni < 4; ++ni)
        bfr[ni] = *(const short8*)&Bs[wn + ni * 16 + col16][ks + quad * 8];
      #pragma unroll
      for (int mi = 0; mi < 4; ++mi) {
        const short8 afr = *(const short8*)&As[wm + mi * 16 + col16][ks + quad * 8];
        #pragma unroll
        for (int ni = 0; ni < 4; ++ni)
          acc[mi][ni] = __builtin_amdgcn_mfma_f32_16x16x32_bf16(afr, bfr[ni], acc[mi][ni], 0, 0, 0);
      }
    }
    __syncthreads();
  }

  #pragma unroll
  for (int ni = 0; ni < 4; ++ni) {
    const int col = wn + ni * 16 + col16;        // 0..127 slab-local
    const float bc = toF(d.bias[col]);
    const int gcol = d.coff + col;
    #pragma unroll
    for (int mi = 0; mi < 4; ++mi) {
      #pragma unroll
      for (int r = 0; r < 4; ++r) {
        const int row = bm + wm + mi * 16 + quad * 4 + r;
        if (row < M) {
          float v = acc[mi][ni][r] + bc;
          if (d.act == 1) v = gelu_exact(v);
          const size_t idx = (size_t)row * d.ldc + gcol;
          if (d.otype == 0) ((bf16*)d.c)[idx] = __float2bfloat16(v);
          else              ((float*)d.c)[idx] = v;
        }
      }
    }
  }
}

// -------------------------------------------------------------------------
// CSR gather v2: one wave per dst node, split into two 32-lane halves over
// alternate edges; 16B loads; 3-round 8-lane head reduction.
// -------------------------------------------------------------------------
__global__ __launch_bounds__(256) void gather_kernel(
    const bf16* __restrict__ q, const bf16* __restrict__ km,
    const int* __restrict__ srcs, const bf16* __restrict__ ews,
    const int* __restrict__ offs, const bf16* __restrict__ pri,
    bf16* __restrict__ agg, int Nd, int addPrev, float finalScale)
{
  const int lane = threadIdx.x & 63;
  const int wid  = threadIdx.x >> 6;
  const int node = blockIdx.x * 4 + wid;
  if (node >= Nd) return;
  const int h  = lane >> 5;   // half 0/1
  const int sl = lane & 31;   // sublane: covers elems sl*8..sl*8+7, head sl>>3
  const float prih = toF(pri[sl >> 3]);

  union B8 { uint4 u; unsigned short s[8]; };
  B8 qv;
  qv.u = ((const uint4*)(q + (size_t)node * 256))[sl];
  float qf[8];
  #pragma unroll
  for (int j = 0; j < 8; ++j) qf[j] = bits2f(qv.s[j]);

  float acc[8] = {};
  const int beg = offs[node], end = offs[node + 1];
  for (int idx = beg + h; idx < end; idx += 2) {
    const int s = srcs[idx];
    const float w = toF(ews[idx]);
    B8 kb;
    kb.u = ((const uint4*)(km + (size_t)s * 512))[sl];
    float dot = 0.f;
    #pragma unroll
    for (int j = 0; j < 8; ++j) dot += qf[j] * bits2f(kb.s[j]);
    dot += __shfl_xor(dot, 1);
    dot += __shfl_xor(dot, 2);
    dot += __shfl_xor(dot, 4);
    const float a = w * sigmoidf_(dot * prih * 0.125f);
    B8 mb;
    mb.u = ((const uint4*)(km + (size_t)s * 512 + 256))[sl];
    #pragma unroll
    for (int j = 0; j < 8; ++j) acc[j] += bits2f(mb.s[j]) * a;
  }

  #pragma unroll
  for (int j = 0; j < 8; ++j) acc[j] += __shfl_xor(acc[j], 32);

  if (h == 0) {
    bf16* out = agg + (size_t)node * 256 + sl * 8;
    if (addPrev) {
      B8 pb;
      pb.u = *(const uint4*)out;
      #pragma unroll
      for (int j = 0; j < 8; ++j) acc[j] += bits2f(pb.s[j]);
    }
    B8 ov;
    #pragma unroll
    for (int j = 0; j < 8; ++j) {
      union { bf16 h; unsigned short u; } cv;
      cv.h = __float2bfloat16(acc[j] * finalScale);
      ov.s[j] = cv.u;
    }
    *(uint4*)out = ov.u;
  }
}

// -------------------------------------------------------------------------
// o = tr*alpha + feat*(1-alpha); feat = bf16(LN(o)*g + b). One wave per node.
// -------------------------------------------------------------------------
__global__ __launch_bounds__(256) void skip_ln(
    const float* __restrict__ tr, bf16* __restrict__ feat,
    const bf16* __restrict__ skipv, const bf16* __restrict__ g,
    const bf16* __restrict__ b, int N)
{
  const int lane = threadIdx.x & 63;
  const int wid  = threadIdx.x >> 6;
  const int node = blockIdx.x * 4 + wid;
  if (node >= N) return;
  const float alpha = sigmoidf_(toF(*skipv));
  const float4 t = ((const float4*)(tr + (size_t)node * 256))[lane];
  union B4 { uint2 u; unsigned short s[4]; };
  B4 fb;
  fb.u = ((const uint2*)(feat + (size_t)node * 256))[lane];
  float o[4];
  o[0] = t.x * alpha + bits2f(fb.s[0]) * (1.f - alpha);
  o[1] = t.y * alpha + bits2f(fb.s[1]) * (1.f - alpha);
  o[2] = t.z * alpha + bits2f(fb.s[2]) * (1.f - alpha);
  o[3] = t.w * alpha + bits2f(fb.s[3]) * (1.f - alpha);

  float sum = o[0] + o[1] + o[2] + o[3];
  #pragma unroll
  for (int off = 32; off; off >>= 1) sum += __shfl_xor(sum, off);
  const float mu = sum * (1.f / 256.f);

  float dd[4], sq = 0.f;
  #pragma unroll
  for (int j = 0; j < 4; ++j) { dd[j] = o[j] - mu; sq += dd[j] * dd[j]; }
  #pragma unroll
  for (int off = 32; off; off >>= 1) sq += __shfl_xor(sq, off);
  const float rs = rsqrtf(sq * (1.f / 256.f) + 1e-5f);

  bf16* fout = feat + (size_t)node * 256 + lane * 4;
  #pragma unroll
  for (int j = 0; j < 4; ++j) {
    float r = dd[j] * rs * toF(g[lane * 4 + j]) + toF(b[lane * 4 + j]);
    fout[j] = __float2bfloat16(r);
  }
}

// -------------------------------------------------------------------------
// out[M,64] = A[M,256] @ W[256,64] + b[64]; output dtype per *flag.
// -------------------------------------------------------------------------
__global__ __launch_bounds__(256) void out_gemm(
    const bf16* __restrict__ A, const bf16* __restrict__ W,
    const bf16* __restrict__ bias, void* __restrict__ out,
    const unsigned* __restrict__ flag, int M)
{
  __shared__ float Ws[64][64];
  const bool obf = (*flag != 0u);
  const int tid = threadIdx.x;
  const int row = blockIdx.x * 64 + (tid >> 2);
  const int c0 = (tid & 3) * 16;
  const int arow = (row < M) ? row : 0;
  const bf16* a = A + (size_t)arow * 256;
  float acc[16] = {};
  for (int k0 = 0; k0 < 256; k0 += 64) {
    for (int i = tid; i < 4096; i += 256)
      Ws[i >> 6][i & 63] = toF(W[(size_t)(k0 + (i >> 6)) * 64 + (i & 63)]);
    __syncthreads();
    for (int k = 0; k < 64; ++k) {
      const float av = toF(a[k0 + k]);
      #pragma unroll
      for (int j = 0; j < 16; ++j) acc[j] += av * Ws[k][c0 + j];
    }
    __syncthreads();
  }
  if (row < M) {
    #pragma unroll
    for (int j = 0; j < 16; ++j) {
      const float v = acc[j] + toF(bias[c0 + j]);
      const size_t idx = (size_t)row * 64 + c0 + j;
      if (obf) ((bf16*)out)[idx] = __float2bfloat16(v);
      else     ((float*)out)[idx] = v;
    }
  }
}

// -------------------------------------------------------------------------
extern "C" void kernel_launch(void* const* d_in, const int* in_sizes, int n_in,
                              void* d_out, int out_size, void* d_ws, size_t ws_size,
                              hipStream_t stream) {
  const int* src_wb  = (const int*)d_in[23];
  const int* dst_wb  = (const int*)d_in[24];
  const int* src_w   = (const int*)d_in[25];
  const int* dst_w   = (const int*)d_in[26];
  const int* src_c   = (const int*)d_in[27];
  const int* dst_c   = (const int*)d_in[28];

  // ---- workspace carve (~166 MB total) ----
  char* base = (char*)d_ws;
  unsigned* flags = (unsigned*)base;                       // 256 B
  bf16* canon = (bf16*)(base + 256);
  char* p = base + 256 + (((size_t)kCanonTotal * 2 + 511) & ~(size_t)511);
  bf16* adWT = (bf16*)p;                     // 2 x 65536
  bf16* qWT  = adWT + (size_t)2 * 65536;     // 4 x 65536
  bf16* aWT  = qWT  + (size_t)4 * 65536;     // 4 x 65536
  bf16* KMeffT = aWT + (size_t)4 * 65536;    // 6 x 512*256
  bf16* kmbeT  = KMeffT + (size_t)6 * 512 * 256;  // 6 x 512
  char* pc = (char*)(((size_t)(kmbeT + 6 * 512) + 511) & ~(size_t)511);
  // CSR region
  int* cur_wb  = (int*)pc;
  int* cur_w   = cur_wb + (kNA + 1);
  int* cur_c   = cur_w + (kNP + 1);
  int* offs_wb = cur_c + (kNP + 1);
  int* offs_w  = offs_wb + (kNA + 1);
  int* offs_c  = offs_w + (kNP + 1);
  int* srcs_wb = offs_c + (kNP + 1);
  int* srcs_w  = srcs_wb + kEWB;
  int* srcs_c  = srcs_w + kEW;
  bf16* ews_wb = (bf16*)(srcs_c + kEC);
  bf16* ews_w  = ews_wb + kEWB;
  bf16* ews_c  = ews_w + kEW;
  int* bsums   = (int*)(ews_c + kEC);     // [3][32]
  int* totals  = bsums + 96;              // [3]
  char* p2 = (char*)(((size_t)(totals + 3) + 511) & ~(size_t)511);
  bf16* fa  = (bf16*)p2;                  // [NA,256]
  bf16* fp_ = fa + (size_t)kNA * 256;     // [NP,256]
  char* R   = (char*)(fp_ + (size_t)kNP * 256);
  bf16* qa   = (bf16*)R;                  // [NA,256]
  bf16* qp   = qa + (size_t)kNA * 256;    // [NP,256]
  bf16* km_a = qp + (size_t)kNP * 256;    // [NA,512] authors KM (writes rel)
  bf16* km_p = km_a + (size_t)kNA * 512;  // [NP,512] papers KM (wb, then cites)
  float* tr_a = (float*)R;                // fp32 view of R, disjoint lifetime
  float* tr_p = tr_a + (size_t)kNA * 256;
  char* afterR = R + ((size_t)(kNA + kNP) * 256 + (size_t)(kNA + kNP) * 512) * sizeof(bf16);
  bf16* agg_a = (bf16*)afterR;            // [NA,256]
  bf16* agg_p = agg_a + (size_t)kNA * 256;// [NP,256]

  const bf16* c_ew_wb = canon + kOff(0);
  const bf16* c_ew_w  = canon + kOff(1);
  const bf16* c_ew_c  = canon + kOff(2);
  const bf16* c_adW   = canon + kOff(3);
  const bf16* c_adb   = canon + kOff(4);
  const bf16* c_kW    = canon + kOff(5);
  const bf16* c_kb    = canon + kOff(6);
  const bf16* c_qW    = canon + kOff(7);
  const bf16* c_qb    = canon + kOff(8);
  const bf16* c_mW    = canon + kOff(9);
  const bf16* c_mb    = canon + kOff(10);
  const bf16* c_aW    = canon + kOff(11);
  const bf16* c_ab    = canon + kOff(12);
  const bf16* c_wpri  = canon + kOff(13);
  const bf16* c_watt  = canon + kOff(14);
  const bf16* c_wmsg  = canon + kOff(15);
  const bf16* c_skip  = canon + kOff(16);
  const bf16* c_lng   = canon + kOff(17);
  const bf16* c_lnb   = canon + kOff(18);
  const bf16* c_outW  = canon + kOff(19);
  const bf16* c_outb  = canon + kOff(20);

  const unsigned* fIn = flags + 0;
  const unsigned* f1  = flags + 1;

  detect_dtype<<<1, 256, 0, stream>>>((const unsigned*)d_in[0], flags);

  CanonArgs ca;
  for (int s = 0; s < kNSeg; ++s) { ca.n[s] = kSegN[s]; ca.dstOff[s] = (unsigned)kOff(s); }
  const int srcIdx[kNSeg] = {2,3,4, 5,6, 7,8, 9,10, 11,12, 13,14, 15, 16,17, 18,19,20, 21,22};
  for (int s = 0; s < kNSeg; ++s) ca.src[s] = d_in[srcIdx[s]];
  canon_kernel<<<dim3(1172, kNSeg), 256, 0, stream>>>(ca, canon, flags);

  // ---- transpose the 10 dense 256x256 weights into [n][k] layout ----
  TransArgs ta;
  ta.src[0] = c_adW;              ta.dst[0] = adWT;
  ta.src[1] = c_adW + 65536;      ta.dst[1] = adWT + 65536;
  for (int m = 0; m < 4; ++m) { ta.src[2 + m] = c_qW + (size_t)m * 65536; ta.dst[2 + m] = qWT + (size_t)m * 65536; }
  for (int m = 0; m < 4; ++m) { ta.src[6 + m] = c_aW + (size_t)m * 65536; ta.dst[6 + m] = aWT + (size_t)m * 65536; }
  transpose_w<<<dim3(4, 4, 10), 256, 0, stream>>>(ta);

  // ---- CSR build (canon precedes scatter: ews gathers canon'd ew) ----
  hipMemsetAsync(cur_wb, 0, (size_t)((kNA + 1) + 2 * (kNP + 1)) * 4, stream);
  csr_hist<<<(kEWB + 255) / 256, 256, 0, stream>>>(dst_wb, kEWB, cur_wb);
  csr_hist<<<(kEW  + 255) / 256, 256, 0, stream>>>(dst_w,  kEW,  cur_w);
  csr_hist<<<(kEC  + 255) / 256, 256, 0, stream>>>(dst_c,  kEC,  cur_c);
  ScanArgs sa;
  sa.deg[0] = cur_wb;  sa.offs[0] = offs_wb; sa.N[0] = kNA;
  sa.deg[1] = cur_w;   sa.offs[1] = offs_w;  sa.N[1] = kNP;
  sa.deg[2] = cur_c;   sa.offs[2] = offs_c;  sa.N[2] = kNP;
  sa.bsums = bsums;
  scan_l1<<<dim3(32, 3), 256, 0, stream>>>(sa);
  scan_l2<<<3, 64, 0, stream>>>(bsums, totals);
  scan_l3<<<dim3(20, 3), 256, 0, stream>>>(sa, totals);
  csr_scatter<<<(kEWB + 255) / 256, 256, 0, stream>>>(dst_wb, src_wb, c_ew_wb, kEWB, cur_wb, srcs_wb, ews_wb);
  csr_scatter<<<(kEW  + 255) / 256, 256, 0, stream>>>(dst_w,  src_w,  c_ew_w,  kEW,  cur_w,  srcs_w,  ews_w);
  csr_scatter<<<(kEC  + 255) / 256, 256, 0, stream>>>(dst_c,  src_c,  c_ew_c,  kEC,  cur_c,  srcs_c,  ews_c);

  // fused K|M effective weights (K: noff=0, M: noff=256)
  combine_weights<<<dim3(8, 24), 256, 0, stream>>>(c_kW, c_kb, c_watt, KMeffT, kmbeT, 0);
  combine_weights<<<dim3(8, 24), 256, 0, stream>>>(c_mW, c_mb, c_wmsg, KMeffT, kmbeT, 256);

  auto grid = [](int m, int ny) { return dim3((unsigned)((m + 127) / 128), (unsigned)ny); };
  auto mkd = [](const bf16* wt, const bf16* bias, void* c, int ldc, int coff,
                int act, int otype) {
    GemmDesc g;
    g.wt = (const short*)wt; g.bias = bias; g.c = c; g.ldc = ldc;
    g.coff = coff; g.act = act; g.otype = otype; g.pad = 0;
    return g;
  };

  // adapt: feats = gelu(x @ adapt_W + adapt_b)
  {
    MultiDesc md{};
    md.d[0] = mkd(adWT,                c_adb,        fa, 256, 0,   1, 0);
    md.d[1] = mkd(adWT + 128 * 256,    c_adb + 128,  fa, 256, 128, 1, 0);
    mfma_gemm128<<<grid(kNA, 2), 256, 0, stream>>>(d_in[0], fIn, md, kNA);
    md.d[0] = mkd(adWT + 65536,        c_adb + 256,  fp_, 256, 0,   1, 0);
    md.d[1] = mkd(adWT + 65536 + 128 * 256, c_adb + 384, fp_, 256, 128, 1, 0);
    mfma_gemm128<<<grid(kNP, 2), 256, 0, stream>>>(d_in[1], fIn, md, kNP);
  }

  for (int l = 0; l < 2; ++l) {
    const bf16* qW_a = qWT + (size_t)(l * 2 + 0) * 65536;
    const bf16* qW_p = qWT + (size_t)(l * 2 + 1) * 65536;
    const bf16* qb_a = c_qb + (l * 2 + 0) * 256;
    const bf16* qb_p = c_qb + (l * 2 + 1) * 256;
    const bf16* KM_c  = KMeffT + (size_t)(l * 3 + 0) * 512 * 256;
    const bf16* KM_w  = KMeffT + (size_t)(l * 3 + 1) * 512 * 256;
    const bf16* KM_wb = KMeffT + (size_t)(l * 3 + 2) * 512 * 256;
    const bf16* kb_c  = kmbeT + (l * 3 + 0) * 512;
    const bf16* kb_w  = kmbeT + (l * 3 + 1) * 512;
    const bf16* kb_wb = kmbeT + (l * 3 + 2) * 512;

    // authors-proj: Q_a (2 slabs) + KM_w (4 slabs) from fa
    {
      MultiDesc md{};
      md.d[0] = mkd(qW_a,             qb_a,        qa,   256, 0,   0, 0);
      md.d[1] = mkd(qW_a + 128 * 256, qb_a + 128,  qa,   256, 128, 0, 0);
      for (int s = 0; s < 4; ++s)
        md.d[2 + s] = mkd(KM_w + (size_t)s * 128 * 256, kb_w + s * 128, km_a, 512, s * 128, 0, 0);
      mfma_gemm128<<<grid(kNA, 6), 256, 0, stream>>>(fa, f1, md, kNA);
    }
    // papers-proj: Q_p (2 slabs) + KM_wb (4 slabs) from fp_
    {
      MultiDesc md{};
      md.d[0] = mkd(qW_p,             qb_p,        qp,   256, 0,   0, 0);
      md.d[1] = mkd(qW_p + 128 * 256, qb_p + 128,  qp,   256, 128, 0, 0);
      for (int s = 0; s < 4; ++s)
        md.d[2 + s] = mkd(KM_wb + (size_t)s * 128 * 256, kb_wb + s * 128, km_p, 512, s * 128, 0, 0);
      mfma_gemm128<<<grid(kNP, 6), 256, 0, stream>>>(fp_, f1, md, kNP);
    }

    // WRITTEN_BY: paper -> author
    gather_kernel<<<(kNA + 3) / 4, 256, 0, stream>>>(
        qa, km_p, srcs_wb, ews_wb, offs_wb, c_wpri + (l * 3 + 2) * 4,
        agg_a, kNA, 0, 1.f);
    // WRITES: author -> paper
    gather_kernel<<<(kNP + 3) / 4, 256, 0, stream>>>(
        qp, km_a, srcs_w, ews_w, offs_w, c_wpri + (l * 3 + 1) * 4,
        agg_p, kNP, 0, 1.f);

    // cites-KM: reuse km_p (wb gather already done in stream order)
    {
      MultiDesc md{};
      for (int s = 0; s < 4; ++s)
        md.d[s] = mkd(KM_c + (size_t)s * 128 * 256, kb_c + s * 128, km_p, 512, s * 128, 0, 0);
      mfma_gemm128<<<grid(kNP, 4), 256, 0, stream>>>(fp_, f1, md, kNP);
    }
    // CITES: paper -> paper, chained add + 0.5 mean
    gather_kernel<<<(kNP + 3) / 4, 256, 0, stream>>>(
        qp, km_p, srcs_c, ews_c, offs_c, c_wpri + (l * 3 + 0) * 4,
        agg_p, kNP, 1, 0.5f);

    // A-projection of aggregates -> fp32 tr (aliases R; gathers are done)
    {
      const bf16* aW_a = aWT + (size_t)(l * 2 + 0) * 65536;
      const bf16* aW_p = aWT + (size_t)(l * 2 + 1) * 65536;
      MultiDesc md{};
      md.d[0] = mkd(aW_a,             c_ab + (l * 2 + 0) * 256,       tr_a, 256, 0,   0, 1);
      md.d[1] = mkd(aW_a + 128 * 256, c_ab + (l * 2 + 0) * 256 + 128, tr_a, 256, 128, 0, 1);
      mfma_gemm128<<<grid(kNA, 2), 256, 0, stream>>>(agg_a, f1, md, kNA);
      md.d[0] = mkd(aW_p,             c_ab + (l * 2 + 1) * 256,       tr_p, 256, 0,   0, 1);
      md.d[1] = mkd(aW_p + 128 * 256, c_ab + (l * 2 + 1) * 256 + 128, tr_p, 256, 128, 0, 1);
      mfma_gemm128<<<grid(kNP, 2), 256, 0, stream>>>(agg_p, f1, md, kNP);
    }

    skip_ln<<<kNA / 4, 256, 0, stream>>>(
        tr_a, fa,  c_skip + l * 3 + 0, c_lng + (l * 2 + 0) * 256, c_lnb + (l * 2 + 0) * 256, kNA);
    skip_ln<<<kNP / 4, 256, 0, stream>>>(
        tr_p, fp_, c_skip + l * 3 + 1, c_lng + (l * 2 + 1) * 256, c_lnb + (l * 2 + 1) * 256, kNP);
  }

  out_gemm<<<kNP / 64, 256, 0, stream>>>(fp_, c_outW, c_outb, d_out, fIn, kNP);
}